// Round 10
// baseline (227.087 us; speedup 1.0000x reference)
//
#include <hip/hip_runtime.h>
#include <math.h>

// Retention (B=4, S=4096, D=256): chunkwise, split-bf16 MFMA, packed k8-slab
// operands.
// R1-R7: see history. Best verified: R7 = 198us.
// R8: FAILED (asm barriers -> scratch). R9: FAILED net (-18us from scattered
//     per-lane fp32 VT32 loads in lmat/out; bf16 slab direct loads are
//     fragment-contiguous and fine).
// R10: direct-global ONLY for coalesced bf16-slab operands:
//     scores fully direct (no k-loop LDS/barriers); out-inter direct,
//     out-intra keeps B(VT32) LDS dbuf w/ A=Sg direct (LDS 51->18KB, 4/CU);
//     lmat back to R7; proj R7 form at 4 blocks/CU.
#define BB 4
#define SS 4096
#define DD 256
#define LL 256
#define NCH 16
#define GAMMA 0.9865f
#define LOG2G (-0.019609034f)   // log2(0.9865)
#define INV1MG 74.07407407f     // 1/(1-gamma)
#define SLAB 1032               // padded LDS slab stride (u16)
#define SLABB 520               // padded LDS slab stride (u16), 64-row panels

typedef __attribute__((ext_vector_type(8))) short short8;
typedef __attribute__((ext_vector_type(4))) float f32x4;
typedef unsigned short u16;
typedef unsigned int u32;

__device__ __forceinline__ u16 f2bf(float f) {
  union { float f; unsigned u; } v; v.f = f;
  unsigned r = v.u + 0x7FFFu + ((v.u >> 16) & 1u);
  return (u16)(r >> 16);
}
__device__ __forceinline__ float bf2f(u16 h) {
  union { unsigned u; float f; } v; v.u = ((unsigned)h) << 16; return v.f;
}

// 128x128 tile, A from LDS, B from regs (proj), split-bf16 3-product
__device__ __forceinline__ void mfma_step_regB(
    const u16* Ah, const u16* Al, const short8 bh[4], const short8 bl[4],
    int wm0, int fm, int fq, f32x4 acc[4][4])
{
  const int ka = fq * SLAB;
  short8 ah[4], al[4];
#pragma unroll
  for (int i = 0; i < 4; ++i) {
    ah[i] = *(const short8*)&Ah[ka + (wm0 + i * 16 + fm) * 8];
    al[i] = *(const short8*)&Al[ka + (wm0 + i * 16 + fm) * 8];
  }
#pragma unroll
  for (int j = 0; j < 4; ++j)
#pragma unroll
    for (int i = 0; i < 4; ++i) {
      acc[i][j] = __builtin_amdgcn_mfma_f32_16x16x32_bf16(al[i], bh[j], acc[i][j], 0, 0, 0);
      acc[i][j] = __builtin_amdgcn_mfma_f32_16x16x32_bf16(ah[i], bl[j], acc[i][j], 0, 0, 0);
      acc[i][j] = __builtin_amdgcn_mfma_f32_16x16x32_bf16(ah[i], bh[j], acc[i][j], 0, 0, 0);
    }
}

// all-register 128x64 MFMA step (4 waves, 64x32 each), split-bf16 3-product
__device__ __forceinline__ void mfma_regs_ab(
    const short8 ah[4], const short8 al[4],
    const short8 bh[2], const short8 bl[2], f32x4 acc[4][2])
{
#pragma unroll
  for (int j = 0; j < 2; ++j)
#pragma unroll
    for (int i = 0; i < 4; ++i) {
      acc[i][j] = __builtin_amdgcn_mfma_f32_16x16x32_bf16(al[i], bh[j], acc[i][j], 0, 0, 0);
      acc[i][j] = __builtin_amdgcn_mfma_f32_16x16x32_bf16(ah[i], bl[j], acc[i][j], 0, 0, 0);
      acc[i][j] = __builtin_amdgcn_mfma_f32_16x16x32_bf16(ah[i], bh[j], acc[i][j], 0, 0, 0);
    }
}

// load a wave's A-fragments (4 row-groups, hi+lo) from packed global panel
__device__ __forceinline__ void loadA4(short8 ah[4], short8 al[4],
    const u16* AhP, const u16* AlP, int ks, int wm0, int fm, int fq)
{
  const int base = ks * 4096 + fq * 1024;
#pragma unroll
  for (int i = 0; i < 4; ++i) {
    int o = base + (wm0 + i * 16 + fm) * 8;
    ah[i] = *(const short8*)&AhP[o];
    al[i] = *(const short8*)&AlP[o];
  }
}
// load a wave's W^T B-fragments (4 col-groups, hi+lo) straight from global.
__device__ __forceinline__ void loadBW(short8 bh[4], short8 bl[4],
    const u16* WhP, const u16* WlP, int ks, int wn0, int fm, int fq)
{
  const int base = ks * 4096 + fq * 1024;
#pragma unroll
  for (int j = 0; j < 4; ++j) {
    int o = base + (wn0 + j * 16 + fm) * 8;
    bh[j] = *(const short8*)&WhP[o];
    bl[j] = *(const short8*)&WlP[o];
  }
}
// load a wave's 64-row-panel B-fragments (2 col-groups, hi+lo) from global.
__device__ __forceinline__ void loadB2(short8 bh[2], short8 bl[2],
    const u16* BhP, const u16* BlP, int ks, int wn0, int fm, int fq)
{
  const int base = ks * 4096 + fq * 1024;
#pragma unroll
  for (int j = 0; j < 2; ++j) {
    int o = base + (wn0 + j * 16 + fm) * 8;
    bh[j] = *(const short8*)&BhP[o];
    bl[j] = *(const short8*)&BlP[o];
  }
}

// 128x64 tile: A from regs, B from LDS (out-intra)
__device__ __forceinline__ void mfma_regA_ldsB(
    const short8 ah[4], const short8 al[4], const u16* Bh, const u16* Bl,
    int wn0, int fm, int fq, f32x4 acc[4][2])
{
  const int kb = fq * SLABB;
#pragma unroll
  for (int j = 0; j < 2; ++j) {
    short8 bh = *(const short8*)&Bh[kb + (wn0 + j * 16 + fm) * 8];
    short8 bl = *(const short8*)&Bl[kb + (wn0 + j * 16 + fm) * 8];
#pragma unroll
    for (int i = 0; i < 4; ++i) {
      acc[i][j] = __builtin_amdgcn_mfma_f32_16x16x32_bf16(al[i], bh, acc[i][j], 0, 0, 0);
      acc[i][j] = __builtin_amdgcn_mfma_f32_16x16x32_bf16(ah[i], bl, acc[i][j], 0, 0, 0);
      acc[i][j] = __builtin_amdgcn_mfma_f32_16x16x32_bf16(ah[i], bh, acc[i][j], 0, 0, 0);
    }
  }
}

// 128x64 tile, A from LDS, B from regs (lmat)
__device__ __forceinline__ void mfma_ldsA_regB(
    const u16* Ah, const u16* Al, const short8 bh[2], const short8 bl[2],
    int wm0, int fm, int fq, f32x4 acc[4][2])
{
  const int ka = fq * SLAB;
  short8 ah[4], al[4];
#pragma unroll
  for (int i = 0; i < 4; ++i) {
    ah[i] = *(const short8*)&Ah[ka + (wm0 + i * 16 + fm) * 8];
    al[i] = *(const short8*)&Al[ka + (wm0 + i * 16 + fm) * 8];
  }
  mfma_regs_ab(ah, al, bh, bl, acc);
}

// write this pass's column-half of a 128x128 acc into fp32 bounce tile [128][65]
__device__ __forceinline__ void bounce_write(
    float* fb, const f32x4 acc[4][4], int wm0, int wn0, int fm, int fq, int p)
{
  if (wn0 == p * 64) {
#pragma unroll
    for (int i = 0; i < 4; ++i)
#pragma unroll
      for (int j = 0; j < 4; ++j)
#pragma unroll
        for (int r = 0; r < 4; ++r)
          fb[(wm0 + i * 16 + fq * 4 + r) * 65 + j * 16 + fm] = acc[i][j][r];
  }
}

// ---------------------------------------------------------------------------
// 0) pack W^T slabs (hi/lo) + zero rsP/lVec accumulators. grid (3, 16).
__global__ __launch_bounds__(256) void init_pack_kernel(
    const float* __restrict__ Wq, const float* __restrict__ Wk, const float* __restrict__ Wv,
    u16* __restrict__ Wth, u16* __restrict__ Wtl,
    float* __restrict__ rsP, float* __restrict__ lVec)
{
  const int which = blockIdx.x;
  const int it = blockIdx.y;
  const int t = threadIdx.x;
  if (which == 0) {
    *(float4*)&rsP[(size_t)(it * 256 + t) * 4] = (float4){0.f, 0.f, 0.f, 0.f};
  } else if (which == 1) {
    *(float4*)&lVec[(size_t)(it * 256 + t) * 4] = (float4){0.f, 0.f, 0.f, 0.f};
  }
  const float* W = which == 0 ? Wq : (which == 1 ? Wk : Wv);
  for (int pn = 0; pn < 2; ++pn) {
    int pos = it * 256 + t;
    int k8 = pos >> 7, r = pos & 127;
    u16 hs[8], ls[8];
#pragma unroll
    for (int u = 0; u < 8; ++u) {
      float x = W[(size_t)(k8 * 8 + u) * DD + pn * 128 + r];
      u16 h = f2bf(x); hs[u] = h; ls[u] = f2bf(x - bf2f(h));
    }
    size_t o = ((size_t)((which * 2 + pn) * 32 + k8)) * 1024 + (size_t)r * 8;
    *(short8*)&Wth[o] = *(short8*)hs;
    *(short8*)&Wtl[o] = *(short8*)ls;
  }
}

// ---------------------------------------------------------------------------
// proj helpers: fp32 X tile load to regs / split-write to a slab buffer
__device__ __forceinline__ void loadX(float xs[2][8], const float* XP, int ks,
                                      int arow, int ak8) {
#pragma unroll
  for (int t = 0; t < 2; ++t) {
    const float* src = XP + (size_t)(t * 64 + arow) * DD + ks * 32 + ak8 * 8;
    *(float4*)&xs[t][0] = *(const float4*)src;
    *(float4*)&xs[t][4] = *(const float4*)(src + 4);
  }
}
__device__ __forceinline__ void writeAsplit(u16* Ab, const float xs[2][8],
                                            int arow, int ak8) {
#pragma unroll
  for (int t = 0; t < 2; ++t) {
    int row = t * 64 + arow;
    u16 hs[8], ls[8];
#pragma unroll
    for (int u = 0; u < 8; ++u) {
      u16 h = f2bf(xs[t][u]); hs[u] = h; ls[u] = f2bf(xs[t][u] - bf2f(h));
    }
    *(short8*)&Ab[ak8 * SLAB + row * 8] = *(short8*)hs;
    *(short8*)&Ab[4 * SLAB + ak8 * SLAB + row * 8] = *(short8*)ls;
  }
}

// ---------------------------------------------------------------------------
// 1) projections: Q~=(xWq+b)/16, K~=(xWk+b)/sqrt(c), V. Bounce epilogue.
//    (R7 form) A: fp32 X reg-prefetched, split into LDS dbuf. B: W^T regs.
//    4 blocks/CU.
__global__ __launch_bounds__(256, 4) void proj_kernel(
    const float* __restrict__ xq, const float* __restrict__ xk, const float* __restrict__ xv,
    const u16* __restrict__ Wth, const u16* __restrict__ Wtl,
    const float* __restrict__ bq, const float* __restrict__ bk_, const float* __restrict__ bv,
    u16* __restrict__ Qh, u16* __restrict__ Ql,
    u16* __restrict__ Kh, u16* __restrict__ Kl,
    u16* __restrict__ KTh, u16* __restrict__ KTl, float* __restrict__ VT32,
    float* __restrict__ lVec)
{
  const int which = blockIdx.z;
  const float* bias = which == 0 ? bq : (which == 1 ? bk_ : bv);
  const int m0 = blockIdx.x * 128;
  const int pn = blockIdx.y;
  __shared__ u16 SM[16 * SLAB + 128];    // A dbuf (2x8 slabs) + pad; fb overlays
  __shared__ float rsc[128];
  __shared__ float wlut[128];
  __shared__ float kacc[64];
  float* fb = (float*)SM;                 // 128x65 fp32 bounce (epilogue only)
  const int tid = threadIdx.x, lane = tid & 63, wave = tid >> 6;
  const int wm0 = (wave >> 1) * 64, wn0 = (wave & 1) * 64;
  const int fm = lane & 15, fq = lane >> 4;
  if (which == 1) {
    if (tid < 128) {
      int sb = (m0 & (SS - 1)) + tid;
      rsc[tid] = rsqrtf((1.0f - exp2f((float)(sb + 1) * LOG2G)) * INV1MG);
      wlut[tid] = exp2f((float)(255 - ((m0 & (LL - 1)) + tid)) * LOG2G);
    }
    if (tid < 64) kacc[tid] = 0.f;
  }
  const float* XP = (which == 0 ? xq : (which == 1 ? xk : xv)) + (size_t)m0 * DD;
  const u16* WhP = Wth + (size_t)((which * 2 + pn) * 32) * 1024;
  const u16* WlP = Wtl + (size_t)((which * 2 + pn) * 32) * 1024;
  const int arow = tid >> 2, ak8 = tid & 3;  // A split-stage assignment
  f32x4 acc[4][4];
#pragma unroll
  for (int i = 0; i < 4; ++i)
#pragma unroll
    for (int j = 0; j < 4; ++j) acc[i][j] = (f32x4){0.f, 0.f, 0.f, 0.f};
  float xs[2][8];
  short8 bh[4], bl[4];
  // prologue: B(0) into regs, X(0) into buffer 0
  loadBW(bh, bl, WhP, WlP, 0, wn0, fm, fq);
  loadX(xs, XP, 0, arow, ak8);
  writeAsplit(SM, xs, arow, ak8);
  int cur = 0;
  for (int ks = 0; ks < 8; ++ks) {
    __syncthreads();                       // buf[cur] ready
    u16* Ac = SM + cur * 8 * SLAB;
    u16* An = SM + (cur ^ 1) * 8 * SLAB;
    if (ks < 7) loadX(xs, XP, ks + 1, arow, ak8);
    mfma_step_regB(Ac, Ac + 4 * SLAB, bh, bl, wm0, fm, fq, acc);
    if (ks < 7) {
      loadBW(bh, bl, WhP, WlP, ks + 1, wn0, fm, fq);  // prefetch next B
      writeAsplit(An, xs, arow, ak8);
    }
    cur ^= 1;
  }
  const int b = m0 >> 12, sbb = m0 & (SS - 1);
  for (int p = 0; p < 2; ++p) {
    __syncthreads();
    bounce_write(fb, acc, wm0, wn0, fm, fq, p);
    __syncthreads();
    if (which == 0) {
#pragma unroll
      for (int it = 0; it < 4; ++it) {
        int unit = it * 256 + tid;
        int k8l = unit >> 7, row = unit & 127;
        int gcol0 = pn * 128 + p * 64 + k8l * 8;
        u16 hs[8], ls[8];
#pragma unroll
        for (int u = 0; u < 8; ++u) {
          float v = (fb[row * 65 + k8l * 8 + u] + bias[gcol0 + u]) * (1.f / 16.f);
          u16 h = f2bf(v); hs[u] = h; ls[u] = f2bf(v - bf2f(h));
        }
        size_t o = (size_t)(m0 >> 7) * 32768 + (size_t)(pn * 16 + p * 8 + k8l) * 1024 + row * 8;
        *(short8*)&Qh[o] = *(short8*)hs;
        *(short8*)&Ql[o] = *(short8*)ls;
      }
    } else if (which == 1) {
#pragma unroll
      for (int it = 0; it < 4; ++it) {
        int unit = it * 256 + tid;
        int k8l = unit >> 7, row = unit & 127;
        int gcol0 = pn * 128 + p * 64 + k8l * 8;
        u16 hs[8], ls[8];
#pragma unroll
        for (int u = 0; u < 8; ++u) {
          float v = (fb[row * 65 + k8l * 8 + u] + bias[gcol0 + u]) * rsc[row];
          u16 h = f2bf(v); hs[u] = h; ls[u] = f2bf(v - bf2f(h));
        }
        size_t o = (size_t)(m0 >> 7) * 32768 + (size_t)(pn * 16 + p * 8 + k8l) * 1024 + row * 8;
        *(short8*)&Kh[o] = *(short8*)hs;
        *(short8*)&Kl[o] = *(short8*)ls;
      }
      float kpart = 0.f;
#pragma unroll
      for (int it = 0; it < 4; ++it) {
        int unit = it * 256 + tid;
        int dl = unit & 63, s8l = unit >> 6;
        int gcolg = pn * 128 + p * 64 + dl;
        float bs = bias[gcolg];
        u16 hs[8], ls[8];
#pragma unroll
        for (int u = 0; u < 8; ++u) {
          int row = s8l * 8 + u;
          float v = (fb[row * 65 + dl] + bs) * rsc[row];
          kpart = fmaf(v, wlut[row], kpart);
          u16 h = f2bf(v); hs[u] = h; ls[u] = f2bf(v - bf2f(h));
        }
        int sb0 = sbb + s8l * 8;
        size_t o = ((size_t)(b * 2 + (gcolg >> 7)) * 512 + (sb0 >> 3)) * 1024 + (size_t)(gcolg & 127) * 8;
        *(short8*)&KTh[o] = *(short8*)hs;
        *(short8*)&KTl[o] = *(short8*)ls;
      }
      atomicAdd(&kacc[tid & 63], kpart);
      __syncthreads();
      if (tid < 64) {
        int c = sbb >> 8;
        atomicAdd(&lVec[(size_t)(b * NCH + c) * DD + pn * 128 + p * 64 + tid], kacc[tid]);
        kacc[tid] = 0.f;
      }
    } else {
#pragma unroll
      for (int it = 0; it < 4; ++it) {
        int unit = it * 256 + tid;
        int dl = unit & 63, s8l = unit >> 6;
        int gcolg = pn * 128 + p * 64 + dl;
        float bs = bias[gcolg];
        float vv[8];
#pragma unroll
        for (int u = 0; u < 8; ++u) vv[u] = fb[(s8l * 8 + u) * 65 + dl] + bs;
        float* dst = &VT32[(size_t)b * DD * SS + (size_t)gcolg * SS + sbb + s8l * 8];
        *(float4*)dst = (float4){vv[0], vv[1], vv[2], vv[3]};
        *(float4*)(dst + 4) = (float4){vv[4], vv[5], vv[6], vv[7]};
      }
    }
  }
}

// ---------------------------------------------------------------------------
// 3) Sg = mask*(Q~.K~)*g^(il-jl); fused rowsum + Q.cVec dot -> rsP atomics.
//    Fully direct (coalesced bf16-slab operands); no k-loop LDS/barriers.
__global__ __launch_bounds__(256, 4) void scores_kernel(
    const u16* __restrict__ Qh, const u16* __restrict__ Ql,
    const u16* __restrict__ Kh, const u16* __restrict__ Kl,
    const float* __restrict__ lVec, u16* __restrict__ Sgh, u16* __restrict__ Sgl,
    float* __restrict__ rsP)
{
  const int chunk = blockIdx.x, b = chunk >> 4, c = chunk & 15;
  const int y = blockIdx.y;
  const int m0 = (y < 2) ? 0 : 128;
  const int jn0 = (y < 2) ? y * 64 : (y - 2) * 64;
  __shared__ float fb[64 * 65];
  __shared__ float cv[256], lut[256], rowAcc[128], qd2[2][128];
  const int tid = threadIdx.x, lane = tid & 63, wave = tid >> 6;
  const int wm0 = (wave >> 1) * 64, wn0 = (wave & 1) * 32;
  const int fm = lane & 15, fq = lane >> 4;
  if (jn0 == 0) {  // inline prefix scan: cv = sum_{cp<c} gL^(c-1-cp) lVec[cp]
    const float gL = exp2f((float)LL * LOG2G);
    float s = 0.f;
    for (int cp = 0; cp < c; ++cp)
      s = fmaf(gL, s, lVec[(size_t)(b * NCH + cp) * DD + tid]);
    cv[tid] = s;
  }
  lut[tid] = exp2f((float)tid * LOG2G);
  if (tid < 128) rowAcc[tid] = 0.f;
  const int growA = b * SS + c * LL + m0;
  const int growB = b * SS + c * LL + jn0;
  const u16* QhP = Qh + (size_t)(growA >> 7) * 32768;
  const u16* QlP = Ql + (size_t)(growA >> 7) * 32768;
  const u16* KhP = Kh + (size_t)(growB >> 7) * 32768 + (size_t)(growB & 127) * 8;
  const u16* KlP = Kl + (size_t)(growB >> 7) * 32768 + (size_t)(growB & 127) * 8;
  f32x4 acc[4][2];
#pragma unroll
  for (int i = 0; i < 4; ++i)
#pragma unroll
    for (int j = 0; j < 2; ++j) acc[i][j] = (f32x4){0.f, 0.f, 0.f, 0.f};
  float qdreg = 0.f;
  const int qrow = tid & 127, qk8b = tid >> 7;
  __syncthreads();                         // cv/lut ready
  for (int ks = 0; ks < 8; ++ks) {
    short8 ah[4], al[4], bh[2], bl[2];
    loadA4(ah, al, QhP, QlP, ks, wm0, fm, fq);
    loadB2(bh, bl, KhP, KlP, ks, wn0, fm, fq);
    mfma_regs_ab(ah, al, bh, bl, acc);
    if (jn0 == 0) {
#pragma unroll
      for (int h2 = 0; h2 < 2; ++h2) {
        int k8l = qk8b + 2 * h2;
        short8 hv = *(const short8*)&QhP[ks * 4096 + k8l * 1024 + qrow * 8];
        short8 lv = *(const short8*)&QlP[ks * 4096 + k8l * 1024 + qrow * 8];
#pragma unroll
        for (int u = 0; u < 8; ++u)
          qdreg = fmaf(bf2f((u16)hv[u]) + bf2f((u16)lv[u]),
                       cv[ks * 32 + k8l * 8 + u], qdreg);
      }
    }
  }
  qd2[qk8b][qrow] = qdreg;
  const int ps = chunk * 2 + (m0 >> 7);
  for (int rh = 0; rh < 2; ++rh) {
    __syncthreads();
    if (wm0 == rh * 64) {
#pragma unroll
      for (int i = 0; i < 4; ++i)
#pragma unroll
        for (int j = 0; j < 2; ++j)
#pragma unroll
          for (int r = 0; r < 4; ++r)
            fb[(i * 16 + fq * 4 + r) * 65 + wn0 + j * 16 + fm] = acc[i][j][r];
    }
    __syncthreads();
#pragma unroll
    for (int it = 0; it < 2; ++it) {
      int unit = it * 256 + tid;          // 8 k8-cols x 64 rows
      int k8l = unit >> 6, rowl = unit & 63;
      int il = m0 + rh * 64 + rowl;
      int jlb = jn0 + k8l * 8;
      float part = 0.f;
      u16 hs[8], ls[8];
#pragma unroll
      for (int u = 0; u < 8; ++u) {
        int jl = jlb + u;
        float v = (jl <= il) ? fb[rowl * 65 + k8l * 8 + u] * lut[il - jl] : 0.f;
        part += v;
        u16 h = f2bf(v); hs[u] = h; ls[u] = f2bf(v - bf2f(h));
      }
      atomicAdd(&rowAcc[rh * 64 + rowl], part);
      size_t o = (size_t)(ps * 32 + (jn0 >> 3) + k8l) * 1024 + (size_t)(rh * 64 + rowl) * 8;
      *(short8*)&Sgh[o] = *(short8*)hs;
      *(short8*)&Sgl[o] = *(short8*)ls;
    }
  }
  __syncthreads();
  if (tid < 128) {
    float rs = rowAcc[tid];
    if (jn0 == 0)
      rs += exp2f((float)(m0 + tid + 1) * LOG2G) * (qd2[0][tid] + qd2[1][tid]);
    atomicAdd(&rsP[(size_t)b * SS + c * LL + m0 + tid], rs);
  }
}

// ---------------------------------------------------------------------------
// 5) lMatT[e][d] = sum_jl Vw[jl,e] K~[jl,d] ; 128x64 tiles (grid 64x8)
//    (R7 form) A = V^T fp32 coalesced reg-stage -> LDS dbuf with (wtl/denom)
//    fused into the split; B = KT global->regs.
__global__ __launch_bounds__(256, 4) void lmat_kernel(
    const float* __restrict__ VT32, const float* __restrict__ rsP,
    const u16* __restrict__ KTh, const u16* __restrict__ KTl,
    float* __restrict__ lMatT)
{
  const int chunk = blockIdx.x, b = chunk >> 4, c = chunk & 15;
  const int ty = blockIdx.y;
  const int m0 = (ty >> 2) * 128, n0 = (ty & 3) * 64;
  __shared__ u16 SA[2 * 8 * SLAB];
  __shared__ float swl[256];
  const int tid = threadIdx.x, lane = tid & 63, wave = tid >> 6;
  const int wm0 = (wave >> 1) * 64, wn0 = (wave & 1) * 32;
  const int fm = lane & 15, fq = lane >> 4;
  // per-jl scale = gamma^(255-jl) / max(|rsP|,1)
  swl[tid] = exp2f((float)(255 - tid) * LOG2G) /
             fmaxf(fabsf(rsP[(size_t)b * SS + c * LL + tid]), 1.0f);
  const float* AP = VT32 + (size_t)b * DD * SS + (size_t)m0 * SS + c * LL;
  const u16* BhP = KTh + ((size_t)(b * 2 + (n0 >> 7)) * 512 + c * 32) * 1024 + (size_t)(n0 & 127) * 8;
  const u16* BlP = KTl + ((size_t)(b * 2 + (n0 >> 7)) * 512 + c * 32) * 1024 + (size_t)(n0 & 127) * 8;
  const int arow = tid >> 1;               // 128 rows, 2 threads/row
  f32x4 acc[4][2];
#pragma unroll
  for (int i = 0; i < 4; ++i)
#pragma unroll
    for (int j = 0; j < 2; ++j) acc[i][j] = (f32x4){0.f, 0.f, 0.f, 0.f};
  float as[2][8];
  short8 bh[2], bl[2];
  loadB2(bh, bl, BhP, BlP, 0, wn0, fm, fq);
#pragma unroll
  for (int t = 0; t < 2; ++t) {            // prologue loads ks=0
    int ak8 = (tid & 1) * 2 + t;
    const float* src = AP + (size_t)arow * SS + ak8 * 8;
    *(float4*)&as[t][0] = *(const float4*)src;
    *(float4*)&as[t][4] = *(const float4*)(src + 4);
  }
  __syncthreads();                         // swl ready
#pragma unroll
  for (int t = 0; t < 2; ++t) {
    int ak8 = (tid & 1) * 2 + t;
    u16 hs[8], ls[8];
#pragma unroll
    for (int u = 0; u < 8; ++u) {
      float v = as[t][u] * swl[ak8 * 8 + u];
      u16 h = f2bf(v); hs[u] = h; ls[u] = f2bf(v - bf2f(h));
    }
    *(short8*)&SA[ak8 * SLAB + arow * 8] = *(short8*)hs;
    *(short8*)&SA[4 * SLAB + ak8 * SLAB + arow * 8] = *(short8*)ls;
  }
  int cur = 0;
  for (int ks = 0; ks < 8; ++ks) {
    __syncthreads();
    u16* Ac = cur ? SA + 8 * SLAB : SA;
    u16* An = cur ? SA : SA + 8 * SLAB;
    if (ks < 7) {
#pragma unroll
      for (int t = 0; t < 2; ++t) {
        int ak8 = (tid & 1) * 2 + t;
        const float* src = AP + (size_t)arow * SS + (ks + 1) * 32 + ak8 * 8;
        *(float4*)&as[t][0] = *(const float4*)src;
        *(float4*)&as[t][4] = *(const float4*)(src + 4);
      }
    }
    mfma_ldsA_regB(Ac, Ac + 4 * SLAB, bh, bl, wm0, fm, fq, acc);
    if (ks < 7) {
      loadB2(bh, bl, BhP, BlP, ks + 1, wn0, fm, fq);
#pragma unroll
      for (int t = 0; t < 2; ++t) {
        int ak8 = (tid & 1) * 2 + t;
        u16 hs[8], ls[8];
#pragma unroll
        for (int u = 0; u < 8; ++u) {
          float v = as[t][u] * swl[(ks + 1) * 32 + ak8 * 8 + u];
          u16 h = f2bf(v); hs[u] = h; ls[u] = f2bf(v - bf2f(h));
        }
        *(short8*)&An[ak8 * SLAB + arow * 8] = *(short8*)hs;
        *(short8*)&An[4 * SLAB + ak8 * SLAB + arow * 8] = *(short8*)ls;
      }
    }
    cur ^= 1;
  }
#pragma unroll
  for (int i = 0; i < 4; ++i)
#pragma unroll
    for (int j = 0; j < 2; ++j)
#pragma unroll
      for (int r = 0; r < 4; ++r) {
        int e = m0 + wm0 + i * 16 + fq * 4 + r;
        int d = n0 + wn0 + j * 16 + fm;
        lMatT[(size_t)chunk * 65536 + (size_t)e * 256 + d] = acc[i][j][r];
      }
}

// 6) carry scan -> cM packed split
__global__ __launch_bounds__(256) void combine_mat_kernel(
    const float* __restrict__ lMatT, u16* __restrict__ cMh, u16* __restrict__ cMl)
{
  const int t = blockIdx.x * 256 + threadIdx.x;
  const int b = t >> 13, rem = t & 8191;
  const int k8 = rem >> 8, e = rem & 255;
  const float gL = powf(GAMMA, (float)LL);
  float s[8] = {0.f, 0.f, 0.f, 0.f, 0.f, 0.f, 0.f, 0.f};
  for (int ch = 0; ch < 16; ++ch) {
    size_t ro = (size_t)(b * 16 + ch) * 65536 + (size_t)e * 256 + k8 * 8;
    float4 a0 = *(const float4*)&lMatT[ro];
    float4 a1 = *(const float4*)&lMatT[ro + 4];
    float vals[8] = {a0.x, a0.y, a0.z, a0.w, a1.x, a1.y, a1.z, a1.w};
    u16 hh[8], ll[8];
#pragma unroll
    for (int u = 0; u < 8; ++u) {
      u16 h = f2bf(s[u]); hh[u] = h; ll[u] = f2bf(s[u] - bf2f(h));
    }
    size_t wo = ((size_t)(((b * 16 + ch) * 2 + (e >> 7)) * 32 + k8)) * 1024 + (size_t)(e & 127) * 8;
    *(short8*)&cMh[wo] = *(short8*)hh;
    *(short8*)&cMl[wo] = *(short8*)ll;
#pragma unroll
    for (int u = 0; u < 8; ++u) s[u] = gL * s[u] + vals[u];
  }
}

// ---------------------------------------------------------------------------
// 7) out = g^(il+1) * Q~ @ cM^T + Sg @ Vd ; 128x64 tiles (grid 64x8)
//    inter: A=Q, B=cM both direct (no LDS/barriers). intra: A=Sg direct,
//    B=VT32 coalesced reg-stage -> LDS dbuf with 1/denom fused.
__global__ __launch_bounds__(256, 4) void out_kernel(
    const u16* __restrict__ Qh, const u16* __restrict__ Ql,
    const u16* __restrict__ cMh, const u16* __restrict__ cMl,
    const u16* __restrict__ Sgh, const u16* __restrict__ Sgl,
    const float* __restrict__ VT32, const float* __restrict__ rsP,
    float* __restrict__ out)
{
  const int chunk = blockIdx.x, b = chunk >> 4, c = chunk & 15;
  const int ty = blockIdx.y;
  const int m0 = (ty >> 2) * 128, n0 = (ty & 3) * 64;
  __shared__ u16 SB[2 * 8 * SLABB];
  __shared__ float olut[128];
  __shared__ float sdn[256];
  const int tid = threadIdx.x, lane = tid & 63, wave = tid >> 6;
  const int wm0 = (wave >> 1) * 64, wn0 = (wave & 1) * 32;
  const int fm = lane & 15, fq = lane >> 4;
  if (tid < 128) olut[tid] = exp2f((float)(m0 + tid + 1) * LOG2G);
  sdn[tid] = 1.0f / fmaxf(fabsf(rsP[(size_t)b * SS + c * LL + tid]), 1.0f);
  f32x4 acc[4][2];
#pragma unroll
  for (int i = 0; i < 4; ++i)
#pragma unroll
    for (int j = 0; j < 2; ++j) acc[i][j] = (f32x4){0.f, 0.f, 0.f, 0.f};
  __syncthreads();                         // olut/sdn ready
  {  // inter: A = Q panel, B = cM rows n0..n0+64, both direct
    const u16* AhP = Qh + (size_t)(b * 32 + c * 2 + (m0 >> 7)) * 32768;
    const u16* AlP = Ql + (size_t)(b * 32 + c * 2 + (m0 >> 7)) * 32768;
    const u16* BhP = cMh + (size_t)(chunk * 2 + (n0 >> 7)) * 32768 + (size_t)(n0 & 127) * 8;
    const u16* BlP = cMl + (size_t)(chunk * 2 + (n0 >> 7)) * 32768 + (size_t)(n0 & 127) * 8;
    for (int ks = 0; ks < 8; ++ks) {
      short8 ah[4], al[4], bh[2], bl[2];
      loadA4(ah, al, AhP, AlP, ks, wm0, fm, fq);
      loadB2(bh, bl, BhP, BlP, ks, wn0, fm, fq);
      mfma_regs_ab(ah, al, bh, bl, acc);
    }
  }
#pragma unroll
  for (int i = 0; i < 4; ++i)
#pragma unroll
    for (int r = 0; r < 4; ++r) {
      int rl = wm0 + i * 16 + fq * 4 + r;
      float sc = olut[rl];
#pragma unroll
      for (int j = 0; j < 2; ++j) acc[i][j][r] *= sc;
    }
  {  // intra: A = Sg direct; B = VT32 reg-staged -> LDS dbuf (1/denom fused)
    const u16* AhP = Sgh + (size_t)(chunk * 2 + (m0 >> 7)) * 32768;
    const u16* AlP = Sgl + (size_t)(chunk * 2 + (m0 >> 7)) * 32768;
    const float* BP = VT32 + (size_t)b * DD * SS + (size_t)n0 * SS + c * LL;
    const int ber = tid >> 2, bk8 = tid & 3;  // 64 rows x 4 k8, 1 unit/thread
    const int nks = (m0 >> 5) + 4;
    float bs[8];
    {  // prologue: B(0) -> buf0 (first SB use; no hazard)
      const float* src = BP + (size_t)ber * SS + bk8 * 8;
      *(float4*)&bs[0] = *(const float4*)src;
      *(float4*)&bs[4] = *(const float4*)(src + 4);
      u16 hs[8], ls[8];
#pragma unroll
      for (int u = 0; u < 8; ++u) {
        float v = bs[u] * sdn[bk8 * 8 + u];
        u16 h = f2bf(v); hs[u] = h; ls[u] = f2bf(v - bf2f(h));
      }
      *(short8*)&SB[bk8 * SLABB + ber * 8] = *(short8*)hs;
      *(short8*)&SB[4 * SLABB + bk8 * SLABB + ber * 8] = *(short8*)ls;
    }
    int cur = 0;
    for (int ks = 0; ks < nks; ++ks) {
      __syncthreads();
      u16* Bc = cur ? SB + 8 * SLABB : SB;
      u16* Bn = cur ? SB : SB + 8 * SLABB;
      if (ks + 1 < nks) {
        const float* src = BP + (size_t)ber * SS + (ks + 1) * 32 + bk8 * 8;
        *(float4*)&bs[0] = *(const float4*)src;
        *(float4*)&bs[4] = *(const float4*)(src + 4);
      }
      short8 ah[4], al[4];
      loadA4(ah, al, AhP, AlP, ks, wm0, fm, fq);
      mfma_regA_ldsB(ah, al, Bc, Bc + 4 * SLABB, wn0, fm, fq, acc);
      if (ks + 1 < nks) {
        u16 hs[8], ls[8];
#pragma unroll
        for (int u = 0; u < 8; ++u) {
          float v = bs[u] * sdn[(ks + 1) * 32 + bk8 * 8 + u];
          u16 h = f2bf(v); hs[u] = h; ls[u] = f2bf(v - bf2f(h));
        }
        *(short8*)&Bn[bk8 * SLABB + ber * 8] = *(short8*)hs;
        *(short8*)&Bn[4 * SLABB + bk8 * SLABB + ber * 8] = *(short8*)ls;
      }
      cur ^= 1;
    }
  }
#pragma unroll
  for (int i = 0; i < 4; ++i)
#pragma unroll
    for (int j = 0; j < 2; ++j)
#pragma unroll
      for (int r = 0; r < 4; ++r) {
        int il = m0 + wm0 + i * 16 + fq * 4 + r;
        int e = n0 + wn0 + j * 16 + fm;
        out[(size_t)(b * SS + c * LL + il) * DD + e] = acc[i][j][r];
      }
}

// ---------------------------------------------------------------------------
extern "C" void kernel_launch(void* const* d_in, const int* in_sizes, int n_in,
                              void* d_out, int out_size, void* d_ws, size_t ws_size,
                              hipStream_t stream) {
  const float* xq = (const float*)d_in[0];
  const float* xk = (const float*)d_in[1];
  const float* xv = (const float*)d_in[2];
  const float* Wq = (const float*)d_in[3];
  const float* bq = (const float*)d_in[4];
  const float* Wk = (const float*)d_in[5];
  const float* bk = (const float*)d_in[6];
  const float* Wv = (const float*)d_in[7];
  const float* bv = (const float*)d_in[8];
  float* out = (float*)d_out;

  char* p = (char*)d_ws;
  const size_t H16 = (size_t)BB * SS * DD * 2;  // 8 MB
  u16* Qh   = (u16*)(p + 0 * H16);  u16* Ql   = (u16*)(p + 1 * H16);
  u16* Kh   = (u16*)(p + 2 * H16);  u16* Kl   = (u16*)(p + 3 * H16);
  u16* KTh  = (u16*)(p + 4 * H16);  u16* KTl  = (u16*)(p + 5 * H16);
  u16* Sgh  = (u16*)(p + 10 * H16); u16* Sgl  = (u16*)(p + 11 * H16);
  u16* cMh  = (u16*)(p + 12 * H16); u16* cMl  = (u16*)(p + 13 * H16);
  float* lMatT = (float*)(p + 14 * H16);
  float* VT32  = (float*)(p + 16 * H16);
  u16* Wth = (u16*)(p + 18 * H16);
  u16* Wtl = (u16*)(p + 18 * H16 + 3 * DD * DD * 2);
  float* rsP  = (float*)(p + 18 * H16 + 6 * DD * DD * 2);
  float* lVec = rsP + (size_t)BB * SS;

  init_pack_kernel<<<dim3(3, 16), 256, 0, stream>>>(Wq, Wk, Wv, Wth, Wtl, rsP, lVec);
  proj_kernel<<<dim3(BB * SS / 128, 2, 3), 256, 0, stream>>>(
      xq, xk, xv, Wth, Wtl, bq, bk, bv, Qh, Ql, Kh, Kl, KTh, KTl, VT32, lVec);
  scores_kernel<<<dim3(BB * NCH, 6), 256, 0, stream>>>(
      Qh, Ql, Kh, Kl, lVec, Sgh, Sgl, rsP);
  lmat_kernel<<<dim3(BB * NCH, 8), 256, 0, stream>>>(VT32, rsP, KTh, KTl, lMatT);
  combine_mat_kernel<<<128, 256, 0, stream>>>(lMatT, cMh, cMl);
  out_kernel<<<dim3(BB * NCH, 8), 256, 0, stream>>>(
      Qh, Ql, cMh, cMl, Sgh, Sgl, VT32, rsP, out);
}

// Round 11
// 206.167 us; speedup vs baseline: 1.1015x; 1.1015x over previous
//
#include <hip/hip_runtime.h>
#include <math.h>

// Retention (B=4, S=4096, D=256): chunkwise, split-bf16 MFMA, packed k8-slab
// operands.
// R1-R7: see history. R7 = 198us.
// R8: FAILED (asm barriers -> scratch). R9: FAILED net (scattered fp32 loads).
// R10: FAILED via proj (256,4) VGPR spill (84->64, +73MB scratch traffic);
//      non-proj changes (scores fully direct, out-inter direct, out-intra
//      LDS@4/CU, lmat R7@4/CU) were net -4us vs R7.
// R11: R10 with proj reverted to __launch_bounds__(256,3) (verified 42us).
#define BB 4
#define SS 4096
#define DD 256
#define LL 256
#define NCH 16
#define GAMMA 0.9865f
#define LOG2G (-0.019609034f)   // log2(0.9865)
#define INV1MG 74.07407407f     // 1/(1-gamma)
#define SLAB 1032               // padded LDS slab stride (u16)
#define SLABB 520               // padded LDS slab stride (u16), 64-row panels

typedef __attribute__((ext_vector_type(8))) short short8;
typedef __attribute__((ext_vector_type(4))) float f32x4;
typedef unsigned short u16;
typedef unsigned int u32;

__device__ __forceinline__ u16 f2bf(float f) {
  union { float f; unsigned u; } v; v.f = f;
  unsigned r = v.u + 0x7FFFu + ((v.u >> 16) & 1u);
  return (u16)(r >> 16);
}
__device__ __forceinline__ float bf2f(u16 h) {
  union { unsigned u; float f; } v; v.u = ((unsigned)h) << 16; return v.f;
}

// 128x128 tile, A from LDS, B from regs (proj), split-bf16 3-product
__device__ __forceinline__ void mfma_step_regB(
    const u16* Ah, const u16* Al, const short8 bh[4], const short8 bl[4],
    int wm0, int fm, int fq, f32x4 acc[4][4])
{
  const int ka = fq * SLAB;
  short8 ah[4], al[4];
#pragma unroll
  for (int i = 0; i < 4; ++i) {
    ah[i] = *(const short8*)&Ah[ka + (wm0 + i * 16 + fm) * 8];
    al[i] = *(const short8*)&Al[ka + (wm0 + i * 16 + fm) * 8];
  }
#pragma unroll
  for (int j = 0; j < 4; ++j)
#pragma unroll
    for (int i = 0; i < 4; ++i) {
      acc[i][j] = __builtin_amdgcn_mfma_f32_16x16x32_bf16(al[i], bh[j], acc[i][j], 0, 0, 0);
      acc[i][j] = __builtin_amdgcn_mfma_f32_16x16x32_bf16(ah[i], bl[j], acc[i][j], 0, 0, 0);
      acc[i][j] = __builtin_amdgcn_mfma_f32_16x16x32_bf16(ah[i], bh[j], acc[i][j], 0, 0, 0);
    }
}

// all-register 128x64 MFMA step (4 waves, 64x32 each), split-bf16 3-product
__device__ __forceinline__ void mfma_regs_ab(
    const short8 ah[4], const short8 al[4],
    const short8 bh[2], const short8 bl[2], f32x4 acc[4][2])
{
#pragma unroll
  for (int j = 0; j < 2; ++j)
#pragma unroll
    for (int i = 0; i < 4; ++i) {
      acc[i][j] = __builtin_amdgcn_mfma_f32_16x16x32_bf16(al[i], bh[j], acc[i][j], 0, 0, 0);
      acc[i][j] = __builtin_amdgcn_mfma_f32_16x16x32_bf16(ah[i], bl[j], acc[i][j], 0, 0, 0);
      acc[i][j] = __builtin_amdgcn_mfma_f32_16x16x32_bf16(ah[i], bh[j], acc[i][j], 0, 0, 0);
    }
}

// load a wave's A-fragments (4 row-groups, hi+lo) from packed global panel
__device__ __forceinline__ void loadA4(short8 ah[4], short8 al[4],
    const u16* AhP, const u16* AlP, int ks, int wm0, int fm, int fq)
{
  const int base = ks * 4096 + fq * 1024;
#pragma unroll
  for (int i = 0; i < 4; ++i) {
    int o = base + (wm0 + i * 16 + fm) * 8;
    ah[i] = *(const short8*)&AhP[o];
    al[i] = *(const short8*)&AlP[o];
  }
}
// load a wave's W^T B-fragments (4 col-groups, hi+lo) straight from global.
__device__ __forceinline__ void loadBW(short8 bh[4], short8 bl[4],
    const u16* WhP, const u16* WlP, int ks, int wn0, int fm, int fq)
{
  const int base = ks * 4096 + fq * 1024;
#pragma unroll
  for (int j = 0; j < 4; ++j) {
    int o = base + (wn0 + j * 16 + fm) * 8;
    bh[j] = *(const short8*)&WhP[o];
    bl[j] = *(const short8*)&WlP[o];
  }
}
// load a wave's 64-row-panel B-fragments (2 col-groups, hi+lo) from global.
__device__ __forceinline__ void loadB2(short8 bh[2], short8 bl[2],
    const u16* BhP, const u16* BlP, int ks, int wn0, int fm, int fq)
{
  const int base = ks * 4096 + fq * 1024;
#pragma unroll
  for (int j = 0; j < 2; ++j) {
    int o = base + (wn0 + j * 16 + fm) * 8;
    bh[j] = *(const short8*)&BhP[o];
    bl[j] = *(const short8*)&BlP[o];
  }
}

// 128x64 tile: A from regs, B from LDS (out-intra)
__device__ __forceinline__ void mfma_regA_ldsB(
    const short8 ah[4], const short8 al[4], const u16* Bh, const u16* Bl,
    int wn0, int fm, int fq, f32x4 acc[4][2])
{
  const int kb = fq * SLABB;
#pragma unroll
  for (int j = 0; j < 2; ++j) {
    short8 bh = *(const short8*)&Bh[kb + (wn0 + j * 16 + fm) * 8];
    short8 bl = *(const short8*)&Bl[kb + (wn0 + j * 16 + fm) * 8];
#pragma unroll
    for (int i = 0; i < 4; ++i) {
      acc[i][j] = __builtin_amdgcn_mfma_f32_16x16x32_bf16(al[i], bh, acc[i][j], 0, 0, 0);
      acc[i][j] = __builtin_amdgcn_mfma_f32_16x16x32_bf16(ah[i], bl, acc[i][j], 0, 0, 0);
      acc[i][j] = __builtin_amdgcn_mfma_f32_16x16x32_bf16(ah[i], bh, acc[i][j], 0, 0, 0);
    }
  }
}

// 128x64 tile, A from LDS, B from regs (lmat)
__device__ __forceinline__ void mfma_ldsA_regB(
    const u16* Ah, const u16* Al, const short8 bh[2], const short8 bl[2],
    int wm0, int fm, int fq, f32x4 acc[4][2])
{
  const int ka = fq * SLAB;
  short8 ah[4], al[4];
#pragma unroll
  for (int i = 0; i < 4; ++i) {
    ah[i] = *(const short8*)&Ah[ka + (wm0 + i * 16 + fm) * 8];
    al[i] = *(const short8*)&Al[ka + (wm0 + i * 16 + fm) * 8];
  }
  mfma_regs_ab(ah, al, bh, bl, acc);
}

// write this pass's column-half of a 128x128 acc into fp32 bounce tile [128][65]
__device__ __forceinline__ void bounce_write(
    float* fb, const f32x4 acc[4][4], int wm0, int wn0, int fm, int fq, int p)
{
  if (wn0 == p * 64) {
#pragma unroll
    for (int i = 0; i < 4; ++i)
#pragma unroll
      for (int j = 0; j < 4; ++j)
#pragma unroll
        for (int r = 0; r < 4; ++r)
          fb[(wm0 + i * 16 + fq * 4 + r) * 65 + j * 16 + fm] = acc[i][j][r];
  }
}

// ---------------------------------------------------------------------------
// 0) pack W^T slabs (hi/lo) + zero rsP/lVec accumulators. grid (3, 16).
__global__ __launch_bounds__(256) void init_pack_kernel(
    const float* __restrict__ Wq, const float* __restrict__ Wk, const float* __restrict__ Wv,
    u16* __restrict__ Wth, u16* __restrict__ Wtl,
    float* __restrict__ rsP, float* __restrict__ lVec)
{
  const int which = blockIdx.x;
  const int it = blockIdx.y;
  const int t = threadIdx.x;
  if (which == 0) {
    *(float4*)&rsP[(size_t)(it * 256 + t) * 4] = (float4){0.f, 0.f, 0.f, 0.f};
  } else if (which == 1) {
    *(float4*)&lVec[(size_t)(it * 256 + t) * 4] = (float4){0.f, 0.f, 0.f, 0.f};
  }
  const float* W = which == 0 ? Wq : (which == 1 ? Wk : Wv);
  for (int pn = 0; pn < 2; ++pn) {
    int pos = it * 256 + t;
    int k8 = pos >> 7, r = pos & 127;
    u16 hs[8], ls[8];
#pragma unroll
    for (int u = 0; u < 8; ++u) {
      float x = W[(size_t)(k8 * 8 + u) * DD + pn * 128 + r];
      u16 h = f2bf(x); hs[u] = h; ls[u] = f2bf(x - bf2f(h));
    }
    size_t o = ((size_t)((which * 2 + pn) * 32 + k8)) * 1024 + (size_t)r * 8;
    *(short8*)&Wth[o] = *(short8*)hs;
    *(short8*)&Wtl[o] = *(short8*)ls;
  }
}

// ---------------------------------------------------------------------------
// proj helpers: fp32 X tile load to regs / split-write to a slab buffer
__device__ __forceinline__ void loadX(float xs[2][8], const float* XP, int ks,
                                      int arow, int ak8) {
#pragma unroll
  for (int t = 0; t < 2; ++t) {
    const float* src = XP + (size_t)(t * 64 + arow) * DD + ks * 32 + ak8 * 8;
    *(float4*)&xs[t][0] = *(const float4*)src;
    *(float4*)&xs[t][4] = *(const float4*)(src + 4);
  }
}
__device__ __forceinline__ void writeAsplit(u16* Ab, const float xs[2][8],
                                            int arow, int ak8) {
#pragma unroll
  for (int t = 0; t < 2; ++t) {
    int row = t * 64 + arow;
    u16 hs[8], ls[8];
#pragma unroll
    for (int u = 0; u < 8; ++u) {
      u16 h = f2bf(xs[t][u]); hs[u] = h; ls[u] = f2bf(xs[t][u] - bf2f(h));
    }
    *(short8*)&Ab[ak8 * SLAB + row * 8] = *(short8*)hs;
    *(short8*)&Ab[4 * SLAB + ak8 * SLAB + row * 8] = *(short8*)ls;
  }
}

// ---------------------------------------------------------------------------
// 1) projections: Q~=(xWq+b)/16, K~=(xWk+b)/sqrt(c), V. Bounce epilogue.
//    (R7 form, 3 blocks/CU) A: fp32 X reg-prefetched, split into LDS dbuf.
//    B: W^T regs.
__global__ __launch_bounds__(256, 3) void proj_kernel(
    const float* __restrict__ xq, const float* __restrict__ xk, const float* __restrict__ xv,
    const u16* __restrict__ Wth, const u16* __restrict__ Wtl,
    const float* __restrict__ bq, const float* __restrict__ bk_, const float* __restrict__ bv,
    u16* __restrict__ Qh, u16* __restrict__ Ql,
    u16* __restrict__ Kh, u16* __restrict__ Kl,
    u16* __restrict__ KTh, u16* __restrict__ KTl, float* __restrict__ VT32,
    float* __restrict__ lVec)
{
  const int which = blockIdx.z;
  const float* bias = which == 0 ? bq : (which == 1 ? bk_ : bv);
  const int m0 = blockIdx.x * 128;
  const int pn = blockIdx.y;
  __shared__ u16 SM[16 * SLAB + 128];    // A dbuf (2x8 slabs) + pad; fb overlays
  __shared__ float rsc[128];
  __shared__ float wlut[128];
  __shared__ float kacc[64];
  float* fb = (float*)SM;                 // 128x65 fp32 bounce (epilogue only)
  const int tid = threadIdx.x, lane = tid & 63, wave = tid >> 6;
  const int wm0 = (wave >> 1) * 64, wn0 = (wave & 1) * 64;
  const int fm = lane & 15, fq = lane >> 4;
  if (which == 1) {
    if (tid < 128) {
      int sb = (m0 & (SS - 1)) + tid;
      rsc[tid] = rsqrtf((1.0f - exp2f((float)(sb + 1) * LOG2G)) * INV1MG);
      wlut[tid] = exp2f((float)(255 - ((m0 & (LL - 1)) + tid)) * LOG2G);
    }
    if (tid < 64) kacc[tid] = 0.f;
  }
  const float* XP = (which == 0 ? xq : (which == 1 ? xk : xv)) + (size_t)m0 * DD;
  const u16* WhP = Wth + (size_t)((which * 2 + pn) * 32) * 1024;
  const u16* WlP = Wtl + (size_t)((which * 2 + pn) * 32) * 1024;
  const int arow = tid >> 2, ak8 = tid & 3;  // A split-stage assignment
  f32x4 acc[4][4];
#pragma unroll
  for (int i = 0; i < 4; ++i)
#pragma unroll
    for (int j = 0; j < 4; ++j) acc[i][j] = (f32x4){0.f, 0.f, 0.f, 0.f};
  float xs[2][8];
  short8 bh[4], bl[4];
  // prologue: B(0) into regs, X(0) into buffer 0
  loadBW(bh, bl, WhP, WlP, 0, wn0, fm, fq);
  loadX(xs, XP, 0, arow, ak8);
  writeAsplit(SM, xs, arow, ak8);
  int cur = 0;
  for (int ks = 0; ks < 8; ++ks) {
    __syncthreads();                       // buf[cur] ready
    u16* Ac = SM + cur * 8 * SLAB;
    u16* An = SM + (cur ^ 1) * 8 * SLAB;
    if (ks < 7) loadX(xs, XP, ks + 1, arow, ak8);
    mfma_step_regB(Ac, Ac + 4 * SLAB, bh, bl, wm0, fm, fq, acc);
    if (ks < 7) {
      loadBW(bh, bl, WhP, WlP, ks + 1, wn0, fm, fq);  // prefetch next B
      writeAsplit(An, xs, arow, ak8);
    }
    cur ^= 1;
  }
  const int b = m0 >> 12, sbb = m0 & (SS - 1);
  for (int p = 0; p < 2; ++p) {
    __syncthreads();
    bounce_write(fb, acc, wm0, wn0, fm, fq, p);
    __syncthreads();
    if (which == 0) {
#pragma unroll
      for (int it = 0; it < 4; ++it) {
        int unit = it * 256 + tid;
        int k8l = unit >> 7, row = unit & 127;
        int gcol0 = pn * 128 + p * 64 + k8l * 8;
        u16 hs[8], ls[8];
#pragma unroll
        for (int u = 0; u < 8; ++u) {
          float v = (fb[row * 65 + k8l * 8 + u] + bias[gcol0 + u]) * (1.f / 16.f);
          u16 h = f2bf(v); hs[u] = h; ls[u] = f2bf(v - bf2f(h));
        }
        size_t o = (size_t)(m0 >> 7) * 32768 + (size_t)(pn * 16 + p * 8 + k8l) * 1024 + row * 8;
        *(short8*)&Qh[o] = *(short8*)hs;
        *(short8*)&Ql[o] = *(short8*)ls;
      }
    } else if (which == 1) {
#pragma unroll
      for (int it = 0; it < 4; ++it) {
        int unit = it * 256 + tid;
        int k8l = unit >> 7, row = unit & 127;
        int gcol0 = pn * 128 + p * 64 + k8l * 8;
        u16 hs[8], ls[8];
#pragma unroll
        for (int u = 0; u < 8; ++u) {
          float v = (fb[row * 65 + k8l * 8 + u] + bias[gcol0 + u]) * rsc[row];
          u16 h = f2bf(v); hs[u] = h; ls[u] = f2bf(v - bf2f(h));
        }
        size_t o = (size_t)(m0 >> 7) * 32768 + (size_t)(pn * 16 + p * 8 + k8l) * 1024 + row * 8;
        *(short8*)&Kh[o] = *(short8*)hs;
        *(short8*)&Kl[o] = *(short8*)ls;
      }
      float kpart = 0.f;
#pragma unroll
      for (int it = 0; it < 4; ++it) {
        int unit = it * 256 + tid;
        int dl = unit & 63, s8l = unit >> 6;
        int gcolg = pn * 128 + p * 64 + dl;
        float bs = bias[gcolg];
        u16 hs[8], ls[8];
#pragma unroll
        for (int u = 0; u < 8; ++u) {
          int row = s8l * 8 + u;
          float v = (fb[row * 65 + dl] + bs) * rsc[row];
          kpart = fmaf(v, wlut[row], kpart);
          u16 h = f2bf(v); hs[u] = h; ls[u] = f2bf(v - bf2f(h));
        }
        int sb0 = sbb + s8l * 8;
        size_t o = ((size_t)(b * 2 + (gcolg >> 7)) * 512 + (sb0 >> 3)) * 1024 + (size_t)(gcolg & 127) * 8;
        *(short8*)&KTh[o] = *(short8*)hs;
        *(short8*)&KTl[o] = *(short8*)ls;
      }
      atomicAdd(&kacc[tid & 63], kpart);
      __syncthreads();
      if (tid < 64) {
        int c = sbb >> 8;
        atomicAdd(&lVec[(size_t)(b * NCH + c) * DD + pn * 128 + p * 64 + tid], kacc[tid]);
        kacc[tid] = 0.f;
      }
    } else {
#pragma unroll
      for (int it = 0; it < 4; ++it) {
        int unit = it * 256 + tid;
        int dl = unit & 63, s8l = unit >> 6;
        int gcolg = pn * 128 + p * 64 + dl;
        float bs = bias[gcolg];
        float vv[8];
#pragma unroll
        for (int u = 0; u < 8; ++u) vv[u] = fb[(s8l * 8 + u) * 65 + dl] + bs;
        float* dst = &VT32[(size_t)b * DD * SS + (size_t)gcolg * SS + sbb + s8l * 8];
        *(float4*)dst = (float4){vv[0], vv[1], vv[2], vv[3]};
        *(float4*)(dst + 4) = (float4){vv[4], vv[5], vv[6], vv[7]};
      }
    }
  }
}

// ---------------------------------------------------------------------------
// 3) Sg = mask*(Q~.K~)*g^(il-jl); fused rowsum + Q.cVec dot -> rsP atomics.
//    Fully direct (coalesced bf16-slab operands); no k-loop LDS/barriers.
__global__ __launch_bounds__(256, 4) void scores_kernel(
    const u16* __restrict__ Qh, const u16* __restrict__ Ql,
    const u16* __restrict__ Kh, const u16* __restrict__ Kl,
    const float* __restrict__ lVec, u16* __restrict__ Sgh, u16* __restrict__ Sgl,
    float* __restrict__ rsP)
{
  const int chunk = blockIdx.x, b = chunk >> 4, c = chunk & 15;
  const int y = blockIdx.y;
  const int m0 = (y < 2) ? 0 : 128;
  const int jn0 = (y < 2) ? y * 64 : (y - 2) * 64;
  __shared__ float fb[64 * 65];
  __shared__ float cv[256], lut[256], rowAcc[128], qd2[2][128];
  const int tid = threadIdx.x, lane = tid & 63, wave = tid >> 6;
  const int wm0 = (wave >> 1) * 64, wn0 = (wave & 1) * 32;
  const int fm = lane & 15, fq = lane >> 4;
  if (jn0 == 0) {  // inline prefix scan: cv = sum_{cp<c} gL^(c-1-cp) lVec[cp]
    const float gL = exp2f((float)LL * LOG2G);
    float s = 0.f;
    for (int cp = 0; cp < c; ++cp)
      s = fmaf(gL, s, lVec[(size_t)(b * NCH + cp) * DD + tid]);
    cv[tid] = s;
  }
  lut[tid] = exp2f((float)tid * LOG2G);
  if (tid < 128) rowAcc[tid] = 0.f;
  const int growA = b * SS + c * LL + m0;
  const int growB = b * SS + c * LL + jn0;
  const u16* QhP = Qh + (size_t)(growA >> 7) * 32768;
  const u16* QlP = Ql + (size_t)(growA >> 7) * 32768;
  const u16* KhP = Kh + (size_t)(growB >> 7) * 32768 + (size_t)(growB & 127) * 8;
  const u16* KlP = Kl + (size_t)(growB >> 7) * 32768 + (size_t)(growB & 127) * 8;
  f32x4 acc[4][2];
#pragma unroll
  for (int i = 0; i < 4; ++i)
#pragma unroll
    for (int j = 0; j < 2; ++j) acc[i][j] = (f32x4){0.f, 0.f, 0.f, 0.f};
  float qdreg = 0.f;
  const int qrow = tid & 127, qk8b = tid >> 7;
  __syncthreads();                         // cv/lut ready
  for (int ks = 0; ks < 8; ++ks) {
    short8 ah[4], al[4], bh[2], bl[2];
    loadA4(ah, al, QhP, QlP, ks, wm0, fm, fq);
    loadB2(bh, bl, KhP, KlP, ks, wn0, fm, fq);
    mfma_regs_ab(ah, al, bh, bl, acc);
    if (jn0 == 0) {
#pragma unroll
      for (int h2 = 0; h2 < 2; ++h2) {
        int k8l = qk8b + 2 * h2;
        short8 hv = *(const short8*)&QhP[ks * 4096 + k8l * 1024 + qrow * 8];
        short8 lv = *(const short8*)&QlP[ks * 4096 + k8l * 1024 + qrow * 8];
#pragma unroll
        for (int u = 0; u < 8; ++u)
          qdreg = fmaf(bf2f((u16)hv[u]) + bf2f((u16)lv[u]),
                       cv[ks * 32 + k8l * 8 + u], qdreg);
      }
    }
  }
  qd2[qk8b][qrow] = qdreg;
  const int ps = chunk * 2 + (m0 >> 7);
  for (int rh = 0; rh < 2; ++rh) {
    __syncthreads();
    if (wm0 == rh * 64) {
#pragma unroll
      for (int i = 0; i < 4; ++i)
#pragma unroll
        for (int j = 0; j < 2; ++j)
#pragma unroll
          for (int r = 0; r < 4; ++r)
            fb[(i * 16 + fq * 4 + r) * 65 + wn0 + j * 16 + fm] = acc[i][j][r];
    }
    __syncthreads();
#pragma unroll
    for (int it = 0; it < 2; ++it) {
      int unit = it * 256 + tid;          // 8 k8-cols x 64 rows
      int k8l = unit >> 6, rowl = unit & 63;
      int il = m0 + rh * 64 + rowl;
      int jlb = jn0 + k8l * 8;
      float part = 0.f;
      u16 hs[8], ls[8];
#pragma unroll
      for (int u = 0; u < 8; ++u) {
        int jl = jlb + u;
        float v = (jl <= il) ? fb[rowl * 65 + k8l * 8 + u] * lut[il - jl] : 0.f;
        part += v;
        u16 h = f2bf(v); hs[u] = h; ls[u] = f2bf(v - bf2f(h));
      }
      atomicAdd(&rowAcc[rh * 64 + rowl], part);
      size_t o = (size_t)(ps * 32 + (jn0 >> 3) + k8l) * 1024 + (size_t)(rh * 64 + rowl) * 8;
      *(short8*)&Sgh[o] = *(short8*)hs;
      *(short8*)&Sgl[o] = *(short8*)ls;
    }
  }
  __syncthreads();
  if (tid < 128) {
    float rs = rowAcc[tid];
    if (jn0 == 0)
      rs += exp2f((float)(m0 + tid + 1) * LOG2G) * (qd2[0][tid] + qd2[1][tid]);
    atomicAdd(&rsP[(size_t)b * SS + c * LL + m0 + tid], rs);
  }
}

// ---------------------------------------------------------------------------
// 5) lMatT[e][d] = sum_jl Vw[jl,e] K~[jl,d] ; 128x64 tiles (grid 64x8)
//    A = V^T fp32 coalesced reg-stage -> LDS dbuf with (wtl/denom) fused
//    into the split; B = KT global->regs.
__global__ __launch_bounds__(256, 4) void lmat_kernel(
    const float* __restrict__ VT32, const float* __restrict__ rsP,
    const u16* __restrict__ KTh, const u16* __restrict__ KTl,
    float* __restrict__ lMatT)
{
  const int chunk = blockIdx.x, b = chunk >> 4, c = chunk & 15;
  const int ty = blockIdx.y;
  const int m0 = (ty >> 2) * 128, n0 = (ty & 3) * 64;
  __shared__ u16 SA[2 * 8 * SLAB];
  __shared__ float swl[256];
  const int tid = threadIdx.x, lane = tid & 63, wave = tid >> 6;
  const int wm0 = (wave >> 1) * 64, wn0 = (wave & 1) * 32;
  const int fm = lane & 15, fq = lane >> 4;
  // per-jl scale = gamma^(255-jl) / max(|rsP|,1)
  swl[tid] = exp2f((float)(255 - tid) * LOG2G) /
             fmaxf(fabsf(rsP[(size_t)b * SS + c * LL + tid]), 1.0f);
  const float* AP = VT32 + (size_t)b * DD * SS + (size_t)m0 * SS + c * LL;
  const u16* BhP = KTh + ((size_t)(b * 2 + (n0 >> 7)) * 512 + c * 32) * 1024 + (size_t)(n0 & 127) * 8;
  const u16* BlP = KTl + ((size_t)(b * 2 + (n0 >> 7)) * 512 + c * 32) * 1024 + (size_t)(n0 & 127) * 8;
  const int arow = tid >> 1;               // 128 rows, 2 threads/row
  f32x4 acc[4][2];
#pragma unroll
  for (int i = 0; i < 4; ++i)
#pragma unroll
    for (int j = 0; j < 2; ++j) acc[i][j] = (f32x4){0.f, 0.f, 0.f, 0.f};
  float as[2][8];
  short8 bh[2], bl[2];
  loadB2(bh, bl, BhP, BlP, 0, wn0, fm, fq);
#pragma unroll
  for (int t = 0; t < 2; ++t) {            // prologue loads ks=0
    int ak8 = (tid & 1) * 2 + t;
    const float* src = AP + (size_t)arow * SS + ak8 * 8;
    *(float4*)&as[t][0] = *(const float4*)src;
    *(float4*)&as[t][4] = *(const float4*)(src + 4);
  }
  __syncthreads();                         // swl ready
#pragma unroll
  for (int t = 0; t < 2; ++t) {
    int ak8 = (tid & 1) * 2 + t;
    u16 hs[8], ls[8];
#pragma unroll
    for (int u = 0; u < 8; ++u) {
      float v = as[t][u] * swl[ak8 * 8 + u];
      u16 h = f2bf(v); hs[u] = h; ls[u] = f2bf(v - bf2f(h));
    }
    *(short8*)&SA[ak8 * SLAB + arow * 8] = *(short8*)hs;
    *(short8*)&SA[4 * SLAB + ak8 * SLAB + arow * 8] = *(short8*)ls;
  }
  int cur = 0;
  for (int ks = 0; ks < 8; ++ks) {
    __syncthreads();
    u16* Ac = cur ? SA + 8 * SLAB : SA;
    u16* An = cur ? SA : SA + 8 * SLAB;
    if (ks < 7) {
#pragma unroll
      for (int t = 0; t < 2; ++t) {
        int ak8 = (tid & 1) * 2 + t;
        const float* src = AP + (size_t)arow * SS + (ks + 1) * 32 + ak8 * 8;
        *(float4*)&as[t][0] = *(const float4*)src;
        *(float4*)&as[t][4] = *(const float4*)(src + 4);
      }
    }
    mfma_ldsA_regB(Ac, Ac + 4 * SLAB, bh, bl, wm0, fm, fq, acc);
    if (ks < 7) {
      loadB2(bh, bl, BhP, BlP, ks + 1, wn0, fm, fq);
#pragma unroll
      for (int t = 0; t < 2; ++t) {
        int ak8 = (tid & 1) * 2 + t;
        u16 hs[8], ls[8];
#pragma unroll
        for (int u = 0; u < 8; ++u) {
          float v = as[t][u] * swl[(ks + 1) * 32 + ak8 * 8 + u];
          u16 h = f2bf(v); hs[u] = h; ls[u] = f2bf(v - bf2f(h));
        }
        *(short8*)&An[ak8 * SLAB + arow * 8] = *(short8*)hs;
        *(short8*)&An[4 * SLAB + ak8 * SLAB + arow * 8] = *(short8*)ls;
      }
    }
    cur ^= 1;
  }
#pragma unroll
  for (int i = 0; i < 4; ++i)
#pragma unroll
    for (int j = 0; j < 2; ++j)
#pragma unroll
      for (int r = 0; r < 4; ++r) {
        int e = m0 + wm0 + i * 16 + fq * 4 + r;
        int d = n0 + wn0 + j * 16 + fm;
        lMatT[(size_t)chunk * 65536 + (size_t)e * 256 + d] = acc[i][j][r];
      }
}

// 6) carry scan -> cM packed split
__global__ __launch_bounds__(256) void combine_mat_kernel(
    const float* __restrict__ lMatT, u16* __restrict__ cMh, u16* __restrict__ cMl)
{
  const int t = blockIdx.x * 256 + threadIdx.x;
  const int b = t >> 13, rem = t & 8191;
  const int k8 = rem >> 8, e = rem & 255;
  const float gL = powf(GAMMA, (float)LL);
  float s[8] = {0.f, 0.f, 0.f, 0.f, 0.f, 0.f, 0.f, 0.f};
  for (int ch = 0; ch < 16; ++ch) {
    size_t ro = (size_t)(b * 16 + ch) * 65536 + (size_t)e * 256 + k8 * 8;
    float4 a0 = *(const float4*)&lMatT[ro];
    float4 a1 = *(const float4*)&lMatT[ro + 4];
    float vals[8] = {a0.x, a0.y, a0.z, a0.w, a1.x, a1.y, a1.z, a1.w};
    u16 hh[8], ll[8];
#pragma unroll
    for (int u = 0; u < 8; ++u) {
      u16 h = f2bf(s[u]); hh[u] = h; ll[u] = f2bf(s[u] - bf2f(h));
    }
    size_t wo = ((size_t)(((b * 16 + ch) * 2 + (e >> 7)) * 32 + k8)) * 1024 + (size_t)(e & 127) * 8;
    *(short8*)&cMh[wo] = *(short8*)hh;
    *(short8*)&cMl[wo] = *(short8*)ll;
#pragma unroll
    for (int u = 0; u < 8; ++u) s[u] = gL * s[u] + vals[u];
  }
}

// ---------------------------------------------------------------------------
// 7) out = g^(il+1) * Q~ @ cM^T + Sg @ Vd ; 128x64 tiles (grid 64x8)
//    inter: A=Q, B=cM both direct (no LDS/barriers). intra: A=Sg direct,
//    B=VT32 coalesced reg-stage -> LDS dbuf with 1/denom fused.
__global__ __launch_bounds__(256, 4) void out_kernel(
    const u16* __restrict__ Qh, const u16* __restrict__ Ql,
    const u16* __restrict__ cMh, const u16* __restrict__ cMl,
    const u16* __restrict__ Sgh, const u16* __restrict__ Sgl,
    const float* __restrict__ VT32, const float* __restrict__ rsP,
    float* __restrict__ out)
{
  const int chunk = blockIdx.x, b = chunk >> 4, c = chunk & 15;
  const int ty = blockIdx.y;
  const int m0 = (ty >> 2) * 128, n0 = (ty & 3) * 64;
  __shared__ u16 SB[2 * 8 * SLABB];
  __shared__ float olut[128];
  __shared__ float sdn[256];
  const int tid = threadIdx.x, lane = tid & 63, wave = tid >> 6;
  const int wm0 = (wave >> 1) * 64, wn0 = (wave & 1) * 32;
  const int fm = lane & 15, fq = lane >> 4;
  if (tid < 128) olut[tid] = exp2f((float)(m0 + tid + 1) * LOG2G);
  sdn[tid] = 1.0f / fmaxf(fabsf(rsP[(size_t)b * SS + c * LL + tid]), 1.0f);
  f32x4 acc[4][2];
#pragma unroll
  for (int i = 0; i < 4; ++i)
#pragma unroll
    for (int j = 0; j < 2; ++j) acc[i][j] = (f32x4){0.f, 0.f, 0.f, 0.f};
  __syncthreads();                         // olut/sdn ready
  {  // inter: A = Q panel, B = cM rows n0..n0+64, both direct
    const u16* AhP = Qh + (size_t)(b * 32 + c * 2 + (m0 >> 7)) * 32768;
    const u16* AlP = Ql + (size_t)(b * 32 + c * 2 + (m0 >> 7)) * 32768;
    const u16* BhP = cMh + (size_t)(chunk * 2 + (n0 >> 7)) * 32768 + (size_t)(n0 & 127) * 8;
    const u16* BlP = cMl + (size_t)(chunk * 2 + (n0 >> 7)) * 32768 + (size_t)(n0 & 127) * 8;
    for (int ks = 0; ks < 8; ++ks) {
      short8 ah[4], al[4], bh[2], bl[2];
      loadA4(ah, al, AhP, AlP, ks, wm0, fm, fq);
      loadB2(bh, bl, BhP, BlP, ks, wn0, fm, fq);
      mfma_regs_ab(ah, al, bh, bl, acc);
    }
  }
#pragma unroll
  for (int i = 0; i < 4; ++i)
#pragma unroll
    for (int r = 0; r < 4; ++r) {
      int rl = wm0 + i * 16 + fq * 4 + r;
      float sc = olut[rl];
#pragma unroll
      for (int j = 0; j < 2; ++j) acc[i][j][r] *= sc;
    }
  {  // intra: A = Sg direct; B = VT32 reg-staged -> LDS dbuf (1/denom fused)
    const u16* AhP = Sgh + (size_t)(chunk * 2 + (m0 >> 7)) * 32768;
    const u16* AlP = Sgl + (size_t)(chunk * 2 + (m0 >> 7)) * 32768;
    const float* BP = VT32 + (size_t)b * DD * SS + (size_t)n0 * SS + c * LL;
    const int ber = tid >> 2, bk8 = tid & 3;  // 64 rows x 4 k8, 1 unit/thread
    const int nks = (m0 >> 5) + 4;
    float bs[8];
    {  // prologue: B(0) -> buf0 (first SB use; no hazard)
      const float* src = BP + (size_t)ber * SS + bk8 * 8;
      *(float4*)&bs[0] = *(const float4*)src;
      *(float4*)&bs[4] = *(const float4*)(src + 4);
      u16 hs[8], ls[8];
#pragma unroll
      for (int u = 0; u < 8; ++u) {
        float v = bs[u] * sdn[bk8 * 8 + u];
        u16 h = f2bf(v); hs[u] = h; ls[u] = f2bf(v - bf2f(h));
      }
      *(short8*)&SB[bk8 * SLABB + ber * 8] = *(short8*)hs;
      *(short8*)&SB[4 * SLABB + bk8 * SLABB + ber * 8] = *(short8*)ls;
    }
    int cur = 0;
    for (int ks = 0; ks < nks; ++ks) {
      __syncthreads();
      u16* Bc = cur ? SB + 8 * SLABB : SB;
      u16* Bn = cur ? SB : SB + 8 * SLABB;
      if (ks + 1 < nks) {
        const float* src = BP + (size_t)ber * SS + (ks + 1) * 32 + bk8 * 8;
        *(float4*)&bs[0] = *(const float4*)src;
        *(float4*)&bs[4] = *(const float4*)(src + 4);
      }
      short8 ah[4], al[4];
      loadA4(ah, al, AhP, AlP, ks, wm0, fm, fq);
      mfma_regA_ldsB(ah, al, Bc, Bc + 4 * SLABB, wn0, fm, fq, acc);
      if (ks + 1 < nks) {
        u16 hs[8], ls[8];
#pragma unroll
        for (int u = 0; u < 8; ++u) {
          float v = bs[u] * sdn[(ks + 1) * 32 + bk8 * 8 + u];
          u16 h = f2bf(v); hs[u] = h; ls[u] = f2bf(v - bf2f(h));
        }
        *(short8*)&Bn[bk8 * SLABB + ber * 8] = *(short8*)hs;
        *(short8*)&Bn[4 * SLABB + bk8 * SLABB + ber * 8] = *(short8*)ls;
      }
      cur ^= 1;
    }
  }
#pragma unroll
  for (int i = 0; i < 4; ++i)
#pragma unroll
    for (int j = 0; j < 2; ++j)
#pragma unroll
      for (int r = 0; r < 4; ++r) {
        int il = m0 + wm0 + i * 16 + fq * 4 + r;
        int e = n0 + wn0 + j * 16 + fm;
        out[(size_t)(b * SS + c * LL + il) * DD + e] = acc[i][j][r];
      }
}

// ---------------------------------------------------------------------------
extern "C" void kernel_launch(void* const* d_in, const int* in_sizes, int n_in,
                              void* d_out, int out_size, void* d_ws, size_t ws_size,
                              hipStream_t stream) {
  const float* xq = (const float*)d_in[0];
  const float* xk = (const float*)d_in[1];
  const float* xv = (const float*)d_in[2];
  const float* Wq = (const float*)d_in[3];
  const float* bq = (const float*)d_in[4];
  const float* Wk = (const float*)d_in[5];
  const float* bk = (const float*)d_in[6];
  const float* Wv = (const float*)d_in[7];
  const float* bv = (const float*)d_in[8];
  float* out = (float*)d_out;

  char* p = (char*)d_ws;
  const size_t H16 = (size_t)BB * SS * DD * 2;  // 8 MB
  u16* Qh   = (u16*)(p + 0 * H16);  u16* Ql   = (u16*)(p + 1 * H16);
  u16* Kh   = (u16*)(p + 2 * H16);  u16* Kl   = (u16*)(p + 3 * H16);
  u16* KTh  = (u16*)(p + 4 * H16);  u16* KTl  = (u16*)(p + 5 * H16);
  u16* Sgh  = (u16*)(p + 10 * H16); u16* Sgl  = (u16*)(p + 11 * H16);
  u16* cMh  = (u16*)(p + 12 * H16); u16* cMl  = (u16*)(p + 13 * H16);
  float* lMatT = (float*)(p + 14 * H16);
  float* VT32  = (float*)(p + 16 * H16);
  u16* Wth = (u16*)(p + 18 * H16);
  u16* Wtl = (u16*)(p + 18 * H16 + 3 * DD * DD * 2);
  float* rsP  = (float*)(p + 18 * H16 + 6 * DD * DD * 2);
  float* lVec = rsP + (size_t)BB * SS;

  init_pack_kernel<<<dim3(3, 16), 256, 0, stream>>>(Wq, Wk, Wv, Wth, Wtl, rsP, lVec);
  proj_kernel<<<dim3(BB * SS / 128, 2, 3), 256, 0, stream>>>(
      xq, xk, xv, Wth, Wtl, bq, bk, bv, Qh, Ql, Kh, Kl, KTh, KTl, VT32, lVec);
  scores_kernel<<<dim3(BB * NCH, 6), 256, 0, stream>>>(
      Qh, Ql, Kh, Kl, lVec, Sgh, Sgl, rsP);
  lmat_kernel<<<dim3(BB * NCH, 8), 256, 0, stream>>>(VT32, rsP, KTh, KTl, lMatT);
  combine_mat_kernel<<<128, 256, 0, stream>>>(lMatT, cMh, cMl);
  out_kernel<<<dim3(BB * NCH, 8), 256, 0, stream>>>(
      Qh, Ql, cMh, cMl, Sgh, Sgl, VT32, rsP, out);
}

// Round 12
// 200.718 us; speedup vs baseline: 1.1314x; 1.0272x over previous
//
#include <hip/hip_runtime.h>
#include <math.h>

// Retention (B=4, S=4096, D=256): chunkwise, split-bf16 MFMA, packed k8-slab
// operands.
// R1-R7: see history. R7 = 198us (best verified structure set).
// R8/R9/R10: FAILED (asm barriers / scattered fp32 loads / VGPR spill).
// R11: proj fixed but scores/out "fully direct A" = +8us vs R7 ->
//      gll16 A-staging beats duplicated direct A-loads. Reverted.
// R12: R7 structures everywhere + V stored as split-bf16 (VTh/VTl) in the
//      KT-packed layout instead of fp32 VT32 (-80MB traffic): proj which==2
//      epilogue mirrors the KT write; lmat/out reconstruct hi+lo, scale,
//      re-split in-register inside their R7 reg-stage->LDS schedules.
#define BB 4
#define SS 4096
#define DD 256
#define LL 256
#define NCH 16
#define GAMMA 0.9865f
#define LOG2G (-0.019609034f)   // log2(0.9865)
#define INV1MG 74.07407407f     // 1/(1-gamma)
#define SLAB 1032               // padded LDS slab stride (u16)
#define SLABB 520               // padded LDS slab stride (u16), 64-row panels

typedef __attribute__((ext_vector_type(8))) short short8;
typedef __attribute__((ext_vector_type(4))) float f32x4;
typedef unsigned short u16;
typedef unsigned int u32;

__device__ __forceinline__ u16 f2bf(float f) {
  union { float f; unsigned u; } v; v.f = f;
  unsigned r = v.u + 0x7FFFu + ((v.u >> 16) & 1u);
  return (u16)(r >> 16);
}
__device__ __forceinline__ float bf2f(u16 h) {
  union { unsigned u; float f; } v; v.u = ((unsigned)h) << 16; return v.f;
}

__device__ __forceinline__ void gll16(const u16* g, u16* l) {
  __builtin_amdgcn_global_load_lds(
      (const __attribute__((address_space(1))) u32*)g,
      (__attribute__((address_space(3))) u32*)l, 16, 0, 0);
}
// stage one BK=32 k-step of a 128-row panel (4 slabs) into padded LDS
__device__ __forceinline__ void stage8kp(const u16* g, u16* l, int lane) {
#pragma unroll
  for (int i = 0; i < 8; ++i)
    gll16(g + i * 512 + lane * 8, l + (i >> 1) * SLAB + (i & 1) * 512);
}

// 128x128 tile, A from LDS, B from regs (proj), split-bf16 3-product
__device__ __forceinline__ void mfma_step_regB(
    const u16* Ah, const u16* Al, const short8 bh[4], const short8 bl[4],
    int wm0, int fm, int fq, f32x4 acc[4][4])
{
  const int ka = fq * SLAB;
  short8 ah[4], al[4];
#pragma unroll
  for (int i = 0; i < 4; ++i) {
    ah[i] = *(const short8*)&Ah[ka + (wm0 + i * 16 + fm) * 8];
    al[i] = *(const short8*)&Al[ka + (wm0 + i * 16 + fm) * 8];
  }
#pragma unroll
  for (int j = 0; j < 4; ++j)
#pragma unroll
    for (int i = 0; i < 4; ++i) {
      acc[i][j] = __builtin_amdgcn_mfma_f32_16x16x32_bf16(al[i], bh[j], acc[i][j], 0, 0, 0);
      acc[i][j] = __builtin_amdgcn_mfma_f32_16x16x32_bf16(ah[i], bl[j], acc[i][j], 0, 0, 0);
      acc[i][j] = __builtin_amdgcn_mfma_f32_16x16x32_bf16(ah[i], bh[j], acc[i][j], 0, 0, 0);
    }
}

// 128x64 tile, A from LDS, B from regs, split-bf16 3-product
__device__ __forceinline__ void mfma_step_regB_ab(
    const u16* Ah, const u16* Al, const short8 bh[2], const short8 bl[2],
    int wm0, int fm, int fq, f32x4 acc[4][2])
{
  const int ka = fq * SLAB;
  short8 ah[4], al[4];
#pragma unroll
  for (int i = 0; i < 4; ++i) {
    ah[i] = *(const short8*)&Ah[ka + (wm0 + i * 16 + fm) * 8];
    al[i] = *(const short8*)&Al[ka + (wm0 + i * 16 + fm) * 8];
  }
#pragma unroll
  for (int j = 0; j < 2; ++j)
#pragma unroll
    for (int i = 0; i < 4; ++i) {
      acc[i][j] = __builtin_amdgcn_mfma_f32_16x16x32_bf16(al[i], bh[j], acc[i][j], 0, 0, 0);
      acc[i][j] = __builtin_amdgcn_mfma_f32_16x16x32_bf16(ah[i], bl[j], acc[i][j], 0, 0, 0);
      acc[i][j] = __builtin_amdgcn_mfma_f32_16x16x32_bf16(ah[i], bh[j], acc[i][j], 0, 0, 0);
    }
}

// load a wave's W^T B-fragments (4 col-groups, hi+lo) straight from global.
__device__ __forceinline__ void loadBW(short8 bh[4], short8 bl[4],
    const u16* WhP, const u16* WlP, int ks, int wn0, int fm, int fq)
{
  const int base = ks * 4096 + fq * 1024;
#pragma unroll
  for (int j = 0; j < 4; ++j) {
    int o = base + (wn0 + j * 16 + fm) * 8;
    bh[j] = *(const short8*)&WhP[o];
    bl[j] = *(const short8*)&WlP[o];
  }
}
// load a wave's 64-row-panel B-fragments (2 col-groups, hi+lo) from global.
__device__ __forceinline__ void loadB2(short8 bh[2], short8 bl[2],
    const u16* BhP, const u16* BlP, int ks, int wn0, int fm, int fq)
{
  const int base = ks * 4096 + fq * 1024;
#pragma unroll
  for (int j = 0; j < 2; ++j) {
    int o = base + (wn0 + j * 16 + fm) * 8;
    bh[j] = *(const short8*)&BhP[o];
    bl[j] = *(const short8*)&BlP[o];
  }
}

// 128x64 tile (4 waves, 64x32 each), A from LDS, B from LDS (out-intra)
__device__ __forceinline__ void mfma_step_ab(
    const u16* Ah, const u16* Al, const u16* Bh, const u16* Bl,
    int wm0, int wn0, int fm, int fq, f32x4 acc[4][2])
{
  const int ka = fq * SLAB, kb = fq * SLABB;
  short8 ah[4], al[4];
#pragma unroll
  for (int i = 0; i < 4; ++i) {
    ah[i] = *(const short8*)&Ah[ka + (wm0 + i * 16 + fm) * 8];
    al[i] = *(const short8*)&Al[ka + (wm0 + i * 16 + fm) * 8];
  }
#pragma unroll
  for (int j = 0; j < 2; ++j) {
    short8 bh = *(const short8*)&Bh[kb + (wn0 + j * 16 + fm) * 8];
    short8 bl = *(const short8*)&Bl[kb + (wn0 + j * 16 + fm) * 8];
#pragma unroll
    for (int i = 0; i < 4; ++i) {
      acc[i][j] = __builtin_amdgcn_mfma_f32_16x16x32_bf16(al[i], bh, acc[i][j], 0, 0, 0);
      acc[i][j] = __builtin_amdgcn_mfma_f32_16x16x32_bf16(ah[i], bl, acc[i][j], 0, 0, 0);
      acc[i][j] = __builtin_amdgcn_mfma_f32_16x16x32_bf16(ah[i], bh, acc[i][j], 0, 0, 0);
    }
  }
}

// write this pass's column-half of a 128x128 acc into fp32 bounce tile [128][65]
__device__ __forceinline__ void bounce_write(
    float* fb, const f32x4 acc[4][4], int wm0, int wn0, int fm, int fq, int p)
{
  if (wn0 == p * 64) {
#pragma unroll
    for (int i = 0; i < 4; ++i)
#pragma unroll
      for (int j = 0; j < 4; ++j)
#pragma unroll
        for (int r = 0; r < 4; ++r)
          fb[(wm0 + i * 16 + fq * 4 + r) * 65 + j * 16 + fm] = acc[i][j][r];
  }
}

// ---------------------------------------------------------------------------
// 0) pack W^T slabs (hi/lo) + zero rsP/lVec accumulators. grid (3, 16).
__global__ __launch_bounds__(256) void init_pack_kernel(
    const float* __restrict__ Wq, const float* __restrict__ Wk, const float* __restrict__ Wv,
    u16* __restrict__ Wth, u16* __restrict__ Wtl,
    float* __restrict__ rsP, float* __restrict__ lVec)
{
  const int which = blockIdx.x;
  const int it = blockIdx.y;
  const int t = threadIdx.x;
  if (which == 0) {
    *(float4*)&rsP[(size_t)(it * 256 + t) * 4] = (float4){0.f, 0.f, 0.f, 0.f};
  } else if (which == 1) {
    *(float4*)&lVec[(size_t)(it * 256 + t) * 4] = (float4){0.f, 0.f, 0.f, 0.f};
  }
  const float* W = which == 0 ? Wq : (which == 1 ? Wk : Wv);
  for (int pn = 0; pn < 2; ++pn) {
    int pos = it * 256 + t;
    int k8 = pos >> 7, r = pos & 127;
    u16 hs[8], ls[8];
#pragma unroll
    for (int u = 0; u < 8; ++u) {
      float x = W[(size_t)(k8 * 8 + u) * DD + pn * 128 + r];
      u16 h = f2bf(x); hs[u] = h; ls[u] = f2bf(x - bf2f(h));
    }
    size_t o = ((size_t)((which * 2 + pn) * 32 + k8)) * 1024 + (size_t)r * 8;
    *(short8*)&Wth[o] = *(short8*)hs;
    *(short8*)&Wtl[o] = *(short8*)ls;
  }
}

// ---------------------------------------------------------------------------
// proj helpers: fp32 X tile load to regs / split-write to a slab buffer
__device__ __forceinline__ void loadX(float xs[2][8], const float* XP, int ks,
                                      int arow, int ak8) {
#pragma unroll
  for (int t = 0; t < 2; ++t) {
    const float* src = XP + (size_t)(t * 64 + arow) * DD + ks * 32 + ak8 * 8;
    *(float4*)&xs[t][0] = *(const float4*)src;
    *(float4*)&xs[t][4] = *(const float4*)(src + 4);
  }
}
__device__ __forceinline__ void writeAsplit(u16* Ab, const float xs[2][8],
                                            int arow, int ak8) {
#pragma unroll
  for (int t = 0; t < 2; ++t) {
    int row = t * 64 + arow;
    u16 hs[8], ls[8];
#pragma unroll
    for (int u = 0; u < 8; ++u) {
      u16 h = f2bf(xs[t][u]); hs[u] = h; ls[u] = f2bf(xs[t][u] - bf2f(h));
    }
    *(short8*)&Ab[ak8 * SLAB + row * 8] = *(short8*)hs;
    *(short8*)&Ab[4 * SLAB + ak8 * SLAB + row * 8] = *(short8*)ls;
  }
}

// ---------------------------------------------------------------------------
// 1) projections: Q~=(xWq+b)/16, K~=(xWk+b)/sqrt(c), V. Bounce epilogue.
//    (R7 form) A: fp32 X reg-prefetched, split into LDS dbuf. B: W^T regs.
//    which==2 now writes V as split-bf16 in KT-packed layout (VTh/VTl).
__global__ __launch_bounds__(256, 3) void proj_kernel(
    const float* __restrict__ xq, const float* __restrict__ xk, const float* __restrict__ xv,
    const u16* __restrict__ Wth, const u16* __restrict__ Wtl,
    const float* __restrict__ bq, const float* __restrict__ bk_, const float* __restrict__ bv,
    u16* __restrict__ Qh, u16* __restrict__ Ql,
    u16* __restrict__ Kh, u16* __restrict__ Kl,
    u16* __restrict__ KTh, u16* __restrict__ KTl,
    u16* __restrict__ VTh, u16* __restrict__ VTl,
    float* __restrict__ lVec)
{
  const int which = blockIdx.z;
  const float* bias = which == 0 ? bq : (which == 1 ? bk_ : bv);
  const int m0 = blockIdx.x * 128;
  const int pn = blockIdx.y;
  __shared__ u16 SM[16 * SLAB + 128];    // A dbuf (2x8 slabs) + pad; fb overlays
  __shared__ float rsc[128];
  __shared__ float wlut[128];
  __shared__ float kacc[64];
  float* fb = (float*)SM;                 // 128x65 fp32 bounce (epilogue only)
  const int tid = threadIdx.x, lane = tid & 63, wave = tid >> 6;
  const int wm0 = (wave >> 1) * 64, wn0 = (wave & 1) * 64;
  const int fm = lane & 15, fq = lane >> 4;
  if (which == 1) {
    if (tid < 128) {
      int sb = (m0 & (SS - 1)) + tid;
      rsc[tid] = rsqrtf((1.0f - exp2f((float)(sb + 1) * LOG2G)) * INV1MG);
      wlut[tid] = exp2f((float)(255 - ((m0 & (LL - 1)) + tid)) * LOG2G);
    }
    if (tid < 64) kacc[tid] = 0.f;
  }
  const float* XP = (which == 0 ? xq : (which == 1 ? xk : xv)) + (size_t)m0 * DD;
  const u16* WhP = Wth + (size_t)((which * 2 + pn) * 32) * 1024;
  const u16* WlP = Wtl + (size_t)((which * 2 + pn) * 32) * 1024;
  const int arow = tid >> 2, ak8 = tid & 3;  // A split-stage assignment
  f32x4 acc[4][4];
#pragma unroll
  for (int i = 0; i < 4; ++i)
#pragma unroll
    for (int j = 0; j < 4; ++j) acc[i][j] = (f32x4){0.f, 0.f, 0.f, 0.f};
  float xs[2][8];
  short8 bh[4], bl[4];
  // prologue: B(0) into regs, X(0) into buffer 0
  loadBW(bh, bl, WhP, WlP, 0, wn0, fm, fq);
  loadX(xs, XP, 0, arow, ak8);
  writeAsplit(SM, xs, arow, ak8);
  int cur = 0;
  for (int ks = 0; ks < 8; ++ks) {
    __syncthreads();                       // buf[cur] ready
    u16* Ac = SM + cur * 8 * SLAB;
    u16* An = SM + (cur ^ 1) * 8 * SLAB;
    if (ks < 7) loadX(xs, XP, ks + 1, arow, ak8);
    mfma_step_regB(Ac, Ac + 4 * SLAB, bh, bl, wm0, fm, fq, acc);
    if (ks < 7) {
      loadBW(bh, bl, WhP, WlP, ks + 1, wn0, fm, fq);  // prefetch next B
      writeAsplit(An, xs, arow, ak8);
    }
    cur ^= 1;
  }
  const int b = m0 >> 12, sbb = m0 & (SS - 1);
  for (int p = 0; p < 2; ++p) {
    __syncthreads();
    bounce_write(fb, acc, wm0, wn0, fm, fq, p);
    __syncthreads();
    if (which == 0) {
#pragma unroll
      for (int it = 0; it < 4; ++it) {
        int unit = it * 256 + tid;
        int k8l = unit >> 7, row = unit & 127;
        int gcol0 = pn * 128 + p * 64 + k8l * 8;
        u16 hs[8], ls[8];
#pragma unroll
        for (int u = 0; u < 8; ++u) {
          float v = (fb[row * 65 + k8l * 8 + u] + bias[gcol0 + u]) * (1.f / 16.f);
          u16 h = f2bf(v); hs[u] = h; ls[u] = f2bf(v - bf2f(h));
        }
        size_t o = (size_t)(m0 >> 7) * 32768 + (size_t)(pn * 16 + p * 8 + k8l) * 1024 + row * 8;
        *(short8*)&Qh[o] = *(short8*)hs;
        *(short8*)&Ql[o] = *(short8*)ls;
      }
    } else if (which == 1) {
#pragma unroll
      for (int it = 0; it < 4; ++it) {
        int unit = it * 256 + tid;
        int k8l = unit >> 7, row = unit & 127;
        int gcol0 = pn * 128 + p * 64 + k8l * 8;
        u16 hs[8], ls[8];
#pragma unroll
        for (int u = 0; u < 8; ++u) {
          float v = (fb[row * 65 + k8l * 8 + u] + bias[gcol0 + u]) * rsc[row];
          u16 h = f2bf(v); hs[u] = h; ls[u] = f2bf(v - bf2f(h));
        }
        size_t o = (size_t)(m0 >> 7) * 32768 + (size_t)(pn * 16 + p * 8 + k8l) * 1024 + row * 8;
        *(short8*)&Kh[o] = *(short8*)hs;
        *(short8*)&Kl[o] = *(short8*)ls;
      }
      float kpart = 0.f;
#pragma unroll
      for (int it = 0; it < 4; ++it) {
        int unit = it * 256 + tid;
        int dl = unit & 63, s8l = unit >> 6;
        int gcolg = pn * 128 + p * 64 + dl;
        float bs = bias[gcolg];
        u16 hs[8], ls[8];
#pragma unroll
        for (int u = 0; u < 8; ++u) {
          int row = s8l * 8 + u;
          float v = (fb[row * 65 + dl] + bs) * rsc[row];
          kpart = fmaf(v, wlut[row], kpart);
          u16 h = f2bf(v); hs[u] = h; ls[u] = f2bf(v - bf2f(h));
        }
        int sb0 = sbb + s8l * 8;
        size_t o = ((size_t)(b * 2 + (gcolg >> 7)) * 512 + (sb0 >> 3)) * 1024 + (size_t)(gcolg & 127) * 8;
        *(short8*)&KTh[o] = *(short8*)hs;
        *(short8*)&KTl[o] = *(short8*)ls;
      }
      atomicAdd(&kacc[tid & 63], kpart);
      __syncthreads();
      if (tid < 64) {
        int c = sbb >> 8;
        atomicAdd(&lVec[(size_t)(b * NCH + c) * DD + pn * 128 + p * 64 + tid], kacc[tid]);
        kacc[tid] = 0.f;
      }
    } else {  // V: split-bf16, KT-packed layout (mirror of which==1 KT path)
#pragma unroll
      for (int it = 0; it < 4; ++it) {
        int unit = it * 256 + tid;
        int dl = unit & 63, s8l = unit >> 6;
        int gcolg = pn * 128 + p * 64 + dl;
        float bs = bias[gcolg];
        u16 hs[8], ls[8];
#pragma unroll
        for (int u = 0; u < 8; ++u) {
          float v = fb[(s8l * 8 + u) * 65 + dl] + bs;
          u16 h = f2bf(v); hs[u] = h; ls[u] = f2bf(v - bf2f(h));
        }
        int sb0 = sbb + s8l * 8;
        size_t o = ((size_t)(b * 2 + (gcolg >> 7)) * 512 + (sb0 >> 3)) * 1024 + (size_t)(gcolg & 127) * 8;
        *(short8*)&VTh[o] = *(short8*)hs;
        *(short8*)&VTl[o] = *(short8*)ls;
      }
    }
  }
}

// ---------------------------------------------------------------------------
// 3) Sg = mask*(Q~.K~)*g^(il-jl); fused rowsum + Q.cVec dot -> rsP atomics.
//    (R7 form) A = Q via gll16 dbuf; B = K fragments global->regs.
__global__ __launch_bounds__(256, 4) void scores_kernel(
    const u16* __restrict__ Qh, const u16* __restrict__ Ql,
    const u16* __restrict__ Kh, const u16* __restrict__ Kl,
    const float* __restrict__ lVec, u16* __restrict__ Sgh, u16* __restrict__ Sgl,
    float* __restrict__ rsP)
{
  const int chunk = blockIdx.x, b = chunk >> 4, c = chunk & 15;
  const int y = blockIdx.y;
  const int m0 = (y < 2) ? 0 : 128;
  const int jn0 = (y < 2) ? y * 64 : (y - 2) * 64;
  __shared__ u16 SA[2 * 8 * SLAB];
  __shared__ float cv[256], lut[256], rowAcc[128], qd2[2][128];
  float* fb = (float*)SA;  // 64x65 fp32 (epilogue; spans both A buffers)
  const int tid = threadIdx.x, lane = tid & 63, wave = tid >> 6;
  const int wm0 = (wave >> 1) * 64, wn0 = (wave & 1) * 32;
  const int fm = lane & 15, fq = lane >> 4;
  if (jn0 == 0) {  // inline prefix scan: cv = sum_{cp<c} gL^(c-1-cp) lVec[cp]
    const float gL = exp2f((float)LL * LOG2G);
    float s = 0.f;
    for (int cp = 0; cp < c; ++cp)
      s = fmaf(gL, s, lVec[(size_t)(b * NCH + cp) * DD + tid]);
    cv[tid] = s;
  }
  lut[tid] = exp2f((float)tid * LOG2G);
  if (tid < 128) rowAcc[tid] = 0.f;
  const int growA = b * SS + c * LL + m0;
  const int growB = b * SS + c * LL + jn0;
  const u16* QhP = Qh + (size_t)(growA >> 7) * 32768;
  const u16* QlP = Ql + (size_t)(growA >> 7) * 32768;
  const u16* KhP = Kh + (size_t)(growB >> 7) * 32768 + (size_t)(growB & 127) * 8;
  const u16* KlP = Kl + (size_t)(growB >> 7) * 32768 + (size_t)(growB & 127) * 8;
  f32x4 acc[4][2];
#pragma unroll
  for (int i = 0; i < 4; ++i)
#pragma unroll
    for (int j = 0; j < 2; ++j) acc[i][j] = (f32x4){0.f, 0.f, 0.f, 0.f};
  float qdreg = 0.f;
  const int qrow = tid & 127, qk8b = tid >> 7;
  short8 bh[2], bl[2];
  if (wave == 0) stage8kp(QhP, SA, lane);
  if (wave == 1) stage8kp(QlP, SA + 4 * SLAB, lane);
  loadB2(bh, bl, KhP, KlP, 0, wn0, fm, fq);
  int cur = 0;
  for (int ks = 0; ks < 8; ++ks) {
    __syncthreads();
    u16* Ac = cur ? SA + 8 * SLAB : SA;
    u16* An = cur ? SA : SA + 8 * SLAB;
    if (ks < 7) {
      if (wave == 0) stage8kp(QhP + (ks + 1) * 4096, An, lane);
      if (wave == 1) stage8kp(QlP + (ks + 1) * 4096, An + 4 * SLAB, lane);
    }
    mfma_step_regB_ab(Ac, Ac + 4 * SLAB, bh, bl, wm0, fm, fq, acc);
    if (ks < 7) loadB2(bh, bl, KhP, KlP, ks + 1, wn0, fm, fq);
    if (jn0 == 0) {
#pragma unroll
      for (int h2 = 0; h2 < 2; ++h2) {
        int k8l = qk8b + 2 * h2;
        const u16* ahp = &Ac[k8l * SLAB + qrow * 8];
        const u16* alp = &Ac[4 * SLAB + k8l * SLAB + qrow * 8];
#pragma unroll
        for (int u = 0; u < 8; ++u)
          qdreg = fmaf(bf2f(ahp[u]) + bf2f(alp[u]), cv[ks * 32 + k8l * 8 + u], qdreg);
      }
    }
    cur ^= 1;
  }
  qd2[qk8b][qrow] = qdreg;
  const int ps = chunk * 2 + (m0 >> 7);
  for (int rh = 0; rh < 2; ++rh) {
    __syncthreads();
    if (wm0 == rh * 64) {
#pragma unroll
      for (int i = 0; i < 4; ++i)
#pragma unroll
        for (int j = 0; j < 2; ++j)
#pragma unroll
          for (int r = 0; r < 4; ++r)
            fb[(i * 16 + fq * 4 + r) * 65 + wn0 + j * 16 + fm] = acc[i][j][r];
    }
    __syncthreads();
#pragma unroll
    for (int it = 0; it < 2; ++it) {
      int unit = it * 256 + tid;          // 8 k8-cols x 64 rows
      int k8l = unit >> 6, rowl = unit & 63;
      int il = m0 + rh * 64 + rowl;
      int jlb = jn0 + k8l * 8;
      float part = 0.f;
      u16 hs[8], ls[8];
#pragma unroll
      for (int u = 0; u < 8; ++u) {
        int jl = jlb + u;
        float v = (jl <= il) ? fb[rowl * 65 + k8l * 8 + u] * lut[il - jl] : 0.f;
        part += v;
        u16 h = f2bf(v); hs[u] = h; ls[u] = f2bf(v - bf2f(h));
      }
      atomicAdd(&rowAcc[rh * 64 + rowl], part);
      size_t o = (size_t)(ps * 32 + (jn0 >> 3) + k8l) * 1024 + (size_t)(rh * 64 + rowl) * 8;
      *(short8*)&Sgh[o] = *(short8*)hs;
      *(short8*)&Sgl[o] = *(short8*)ls;
    }
  }
  __syncthreads();
  if (tid < 128) {
    float rs = rowAcc[tid];
    if (jn0 == 0)
      rs += exp2f((float)(m0 + tid + 1) * LOG2G) * (qd2[0][tid] + qd2[1][tid]);
    atomicAdd(&rsP[(size_t)b * SS + c * LL + m0 + tid], rs);
  }
}

// ---------------------------------------------------------------------------
// 5) lMatT[e][d] = sum_jl Vw[jl,e] K~[jl,d] ; 128x64 tiles (grid 64x8)
//    (R7 schedule) A = V split-bf16 (VTh/VTl, KT layout) reg-staged -> LDS
//    dbuf with hi+lo reconstruct and (wtl/denom) fused; B = KT global->regs.
__global__ __launch_bounds__(256, 4) void lmat_kernel(
    const u16* __restrict__ VTh, const u16* __restrict__ VTl,
    const float* __restrict__ rsP,
    const u16* __restrict__ KTh, const u16* __restrict__ KTl,
    float* __restrict__ lMatT)
{
  const int chunk = blockIdx.x, b = chunk >> 4, c = chunk & 15;
  const int ty = blockIdx.y;
  const int m0 = (ty >> 2) * 128, n0 = (ty & 3) * 64;
  __shared__ u16 SA[2 * 8 * SLAB];
  __shared__ float swl[256];
  const int tid = threadIdx.x, lane = tid & 63, wave = tid >> 6;
  const int wm0 = (wave >> 1) * 64, wn0 = (wave & 1) * 32;
  const int fm = lane & 15, fq = lane >> 4;
  // per-jl scale = gamma^(255-jl) / max(|rsP|,1)
  swl[tid] = exp2f((float)(255 - tid) * LOG2G) /
             fmaxf(fabsf(rsP[(size_t)b * SS + c * LL + tid]), 1.0f);
  const u16* AThP = VTh + ((size_t)(b * 2 + (m0 >> 7)) * 512 + c * 32) * 1024;
  const u16* ATlP = VTl + ((size_t)(b * 2 + (m0 >> 7)) * 512 + c * 32) * 1024;
  const u16* BhP = KTh + ((size_t)(b * 2 + (n0 >> 7)) * 512 + c * 32) * 1024 + (size_t)(n0 & 127) * 8;
  const u16* BlP = KTl + ((size_t)(b * 2 + (n0 >> 7)) * 512 + c * 32) * 1024 + (size_t)(n0 & 127) * 8;
  const int arow = tid >> 1;               // 128 rows, 2 threads/row
  f32x4 acc[4][2];
#pragma unroll
  for (int i = 0; i < 4; ++i)
#pragma unroll
    for (int j = 0; j < 2; ++j) acc[i][j] = (f32x4){0.f, 0.f, 0.f, 0.f};
  short8 vh[2], vl[2];
  short8 bh[2], bl[2];
  loadB2(bh, bl, BhP, BlP, 0, wn0, fm, fq);
#pragma unroll
  for (int t = 0; t < 2; ++t) {            // prologue loads ks=0
    int ak8 = (tid & 1) * 2 + t;
    int off = ak8 * 1024 + arow * 8;
    vh[t] = *(const short8*)&AThP[off];
    vl[t] = *(const short8*)&ATlP[off];
  }
  __syncthreads();                         // swl ready
#pragma unroll
  for (int t = 0; t < 2; ++t) {
    int ak8 = (tid & 1) * 2 + t;
    u16 hs[8], ls[8];
#pragma unroll
    for (int u = 0; u < 8; ++u) {
      float v = (bf2f((u16)vh[t][u]) + bf2f((u16)vl[t][u])) * swl[ak8 * 8 + u];
      u16 h = f2bf(v); hs[u] = h; ls[u] = f2bf(v - bf2f(h));
    }
    *(short8*)&SA[ak8 * SLAB + arow * 8] = *(short8*)hs;
    *(short8*)&SA[4 * SLAB + ak8 * SLAB + arow * 8] = *(short8*)ls;
  }
  int cur = 0;
  for (int ks = 0; ks < 8; ++ks) {
    __syncthreads();
    u16* Ac = cur ? SA + 8 * SLAB : SA;
    u16* An = cur ? SA : SA + 8 * SLAB;
    if (ks < 7) {
#pragma unroll
      for (int t = 0; t < 2; ++t) {
        int ak8 = (tid & 1) * 2 + t;
        int off = ((ks + 1) * 4 + ak8) * 1024 + arow * 8;
        vh[t] = *(const short8*)&AThP[off];
        vl[t] = *(const short8*)&ATlP[off];
      }
    }
    mfma_step_regB_ab(Ac, Ac + 4 * SLAB, bh, bl, wm0, fm, fq, acc);
    if (ks < 7) {
      loadB2(bh, bl, BhP, BlP, ks + 1, wn0, fm, fq);
#pragma unroll
      for (int t = 0; t < 2; ++t) {
        int ak8 = (tid & 1) * 2 + t;
        u16 hs[8], ls[8];
#pragma unroll
        for (int u = 0; u < 8; ++u) {
          float v = (bf2f((u16)vh[t][u]) + bf2f((u16)vl[t][u])) *
                    swl[(ks + 1) * 32 + ak8 * 8 + u];
          u16 h = f2bf(v); hs[u] = h; ls[u] = f2bf(v - bf2f(h));
        }
        *(short8*)&An[ak8 * SLAB + arow * 8] = *(short8*)hs;
        *(short8*)&An[4 * SLAB + ak8 * SLAB + arow * 8] = *(short8*)ls;
      }
    }
    cur ^= 1;
  }
#pragma unroll
  for (int i = 0; i < 4; ++i)
#pragma unroll
    for (int j = 0; j < 2; ++j)
#pragma unroll
      for (int r = 0; r < 4; ++r) {
        int e = m0 + wm0 + i * 16 + fq * 4 + r;
        int d = n0 + wn0 + j * 16 + fm;
        lMatT[(size_t)chunk * 65536 + (size_t)e * 256 + d] = acc[i][j][r];
      }
}

// 6) carry scan -> cM packed split
__global__ __launch_bounds__(256) void combine_mat_kernel(
    const float* __restrict__ lMatT, u16* __restrict__ cMh, u16* __restrict__ cMl)
{
  const int t = blockIdx.x * 256 + threadIdx.x;
  const int b = t >> 13, rem = t & 8191;
  const int k8 = rem >> 8, e = rem & 255;
  const float gL = powf(GAMMA, (float)LL);
  float s[8] = {0.f, 0.f, 0.f, 0.f, 0.f, 0.f, 0.f, 0.f};
  for (int ch = 0; ch < 16; ++ch) {
    size_t ro = (size_t)(b * 16 + ch) * 65536 + (size_t)e * 256 + k8 * 8;
    float4 a0 = *(const float4*)&lMatT[ro];
    float4 a1 = *(const float4*)&lMatT[ro + 4];
    float vals[8] = {a0.x, a0.y, a0.z, a0.w, a1.x, a1.y, a1.z, a1.w};
    u16 hh[8], ll[8];
#pragma unroll
    for (int u = 0; u < 8; ++u) {
      u16 h = f2bf(s[u]); hh[u] = h; ll[u] = f2bf(s[u] - bf2f(h));
    }
    size_t wo = ((size_t)(((b * 16 + ch) * 2 + (e >> 7)) * 32 + k8)) * 1024 + (size_t)(e & 127) * 8;
    *(short8*)&cMh[wo] = *(short8*)hh;
    *(short8*)&cMl[wo] = *(short8*)ll;
#pragma unroll
    for (int u = 0; u < 8; ++u) s[u] = gL * s[u] + vals[u];
  }
}

// ---------------------------------------------------------------------------
// 7) out = g^(il+1) * Q~ @ cM^T + Sg @ Vd ; 128x64 tiles (grid 64x8)
//    (R7 schedule) inter: A=Q gll16 dbuf, B=cM regs. intra: A=Sg gll16,
//    B = V split-bf16 reg-staged -> LDS dbuf (hi+lo reconstruct, 1/denom).
__global__ __launch_bounds__(256, 3) void out_kernel(
    const u16* __restrict__ Qh, const u16* __restrict__ Ql,
    const u16* __restrict__ cMh, const u16* __restrict__ cMl,
    const u16* __restrict__ Sgh, const u16* __restrict__ Sgl,
    const u16* __restrict__ VTh, const u16* __restrict__ VTl,
    const float* __restrict__ rsP,
    float* __restrict__ out)
{
  const int chunk = blockIdx.x, b = chunk >> 4, c = chunk & 15;
  const int ty = blockIdx.y;
  const int m0 = (ty >> 2) * 128, n0 = (ty & 3) * 64;
  __shared__ u16 SA[2 * 8 * SLAB];
  __shared__ u16 SB[2 * 8 * SLABB];
  __shared__ float olut[128];
  __shared__ float sdn[256];
  const int tid = threadIdx.x, lane = tid & 63, wave = tid >> 6;
  const int wm0 = (wave >> 1) * 64, wn0 = (wave & 1) * 32;
  const int fm = lane & 15, fq = lane >> 4;
  if (tid < 128) olut[tid] = exp2f((float)(m0 + tid + 1) * LOG2G);
  sdn[tid] = 1.0f / fmaxf(fabsf(rsP[(size_t)b * SS + c * LL + tid]), 1.0f);
  f32x4 acc[4][2];
#pragma unroll
  for (int i = 0; i < 4; ++i)
#pragma unroll
    for (int j = 0; j < 2; ++j) acc[i][j] = (f32x4){0.f, 0.f, 0.f, 0.f};
  int cur = 0;
  {  // inter: A = Q panel (gll16 dbuf), B = cM rows n0..n0+64 (regs)
    const u16* AhP = Qh + (size_t)(b * 32 + c * 2 + (m0 >> 7)) * 32768;
    const u16* AlP = Ql + (size_t)(b * 32 + c * 2 + (m0 >> 7)) * 32768;
    const u16* BhP = cMh + (size_t)(chunk * 2 + (n0 >> 7)) * 32768 + (size_t)(n0 & 127) * 8;
    const u16* BlP = cMl + (size_t)(chunk * 2 + (n0 >> 7)) * 32768 + (size_t)(n0 & 127) * 8;
    short8 bh[2], bl[2];
    if (wave == 0) stage8kp(AhP, SA, lane);
    if (wave == 1) stage8kp(AlP, SA + 4 * SLAB, lane);
    loadB2(bh, bl, BhP, BlP, 0, wn0, fm, fq);
    for (int ks = 0; ks < 8; ++ks) {
      __syncthreads();
      u16* Ac = cur ? SA + 8 * SLAB : SA;
      u16* An = cur ? SA : SA + 8 * SLAB;
      if (ks < 7) {
        if (wave == 0) stage8kp(AhP + (ks + 1) * 4096, An, lane);
        if (wave == 1) stage8kp(AlP + (ks + 1) * 4096, An + 4 * SLAB, lane);
      }
      mfma_step_regB_ab(Ac, Ac + 4 * SLAB, bh, bl, wm0, fm, fq, acc);
      if (ks < 7) loadB2(bh, bl, BhP, BlP, ks + 1, wn0, fm, fq);
      cur ^= 1;
    }
  }
  {  // intra: A = Sg (gll16), B = V split-bf16 reg-staged -> LDS dbuf
    const u16* AhP = Sgh + (size_t)(chunk * 2 + (m0 >> 7)) * 32768;
    const u16* AlP = Sgl + (size_t)(chunk * 2 + (m0 >> 7)) * 32768;
    const u16* BThP = VTh + ((size_t)(b * 2 + (n0 >> 7)) * 512 + c * 32) * 1024 + (size_t)(n0 & 127) * 8;
    const u16* BTlP = VTl + ((size_t)(b * 2 + (n0 >> 7)) * 512 + c * 32) * 1024 + (size_t)(n0 & 127) * 8;
    const int ber = tid >> 2, bk8 = tid & 3;  // 64 rows x 4 k8, 1 unit/thread
    const int nks = (m0 >> 5) + 4;
    short8 vh, vl;
    {  // prologue into buf[cur] (last read 2 steps ago -> safe)
      u16* Ac = cur ? SA + 8 * SLAB : SA;
      u16* Bc = cur ? SB + 8 * SLABB : SB;
      if (wave == 0) stage8kp(AhP, Ac, lane);
      if (wave == 1) stage8kp(AlP, Ac + 4 * SLAB, lane);
      int off = bk8 * 1024 + ber * 8;
      vh = *(const short8*)&BThP[off];
      vl = *(const short8*)&BTlP[off];
      // overlap acc scaling with the loads
#pragma unroll
      for (int i = 0; i < 4; ++i)
#pragma unroll
        for (int r = 0; r < 4; ++r) {
          int rl = wm0 + i * 16 + fq * 4 + r;
          float sc = olut[rl];
#pragma unroll
          for (int j = 0; j < 2; ++j) acc[i][j][r] *= sc;
        }
      u16 hs[8], ls[8];
#pragma unroll
      for (int u = 0; u < 8; ++u) {
        float v = (bf2f((u16)vh[u]) + bf2f((u16)vl[u])) * sdn[bk8 * 8 + u];
        u16 h = f2bf(v); hs[u] = h; ls[u] = f2bf(v - bf2f(h));
      }
      *(short8*)&Bc[bk8 * SLABB + ber * 8] = *(short8*)hs;
      *(short8*)&Bc[4 * SLABB + bk8 * SLABB + ber * 8] = *(short8*)ls;
    }
    for (int ks = 0; ks < nks; ++ks) {
      __syncthreads();
      u16* Ac = cur ? SA + 8 * SLAB : SA;
      u16* Bc = cur ? SB + 8 * SLABB : SB;
      u16* An = cur ? SA : SA + 8 * SLAB;
      u16* Bn = cur ? SB : SB + 8 * SLABB;
      if (ks + 1 < nks) {
        if (wave == 0) stage8kp(AhP + (ks + 1) * 4096, An, lane);
        if (wave == 1) stage8kp(AlP + (ks + 1) * 4096, An + 4 * SLAB, lane);
        int off = ((ks + 1) * 4 + bk8) * 1024 + ber * 8;
        vh = *(const short8*)&BThP[off];
        vl = *(const short8*)&BTlP[off];
      }
      mfma_step_ab(Ac, Ac + 4 * SLAB, Bc, Bc + 4 * SLABB, wm0, wn0, fm, fq, acc);
      if (ks + 1 < nks) {
        u16 hs[8], ls[8];
#pragma unroll
        for (int u = 0; u < 8; ++u) {
          float v = (bf2f((u16)vh[u]) + bf2f((u16)vl[u])) *
                    sdn[(ks + 1) * 32 + bk8 * 8 + u];
          u16 h = f2bf(v); hs[u] = h; ls[u] = f2bf(v - bf2f(h));
        }
        *(short8*)&Bn[bk8 * SLABB + ber * 8] = *(short8*)hs;
        *(short8*)&Bn[4 * SLABB + bk8 * SLABB + ber * 8] = *(short8*)ls;
      }
      cur ^= 1;
    }
  }
#pragma unroll
  for (int i = 0; i < 4; ++i)
#pragma unroll
    for (int j = 0; j < 2; ++j)
#pragma unroll
      for (int r = 0; r < 4; ++r) {
        int il = m0 + wm0 + i * 16 + fq * 4 + r;
        int e = n0 + wn0 + j * 16 + fm;
        out[(size_t)(b * SS + c * LL + il) * DD + e] = acc[i][j][r];
      }
}

// ---------------------------------------------------------------------------
extern "C" void kernel_launch(void* const* d_in, const int* in_sizes, int n_in,
                              void* d_out, int out_size, void* d_ws, size_t ws_size,
                              hipStream_t stream) {
  const float* xq = (const float*)d_in[0];
  const float* xk = (const float*)d_in[1];
  const float* xv = (const float*)d_in[2];
  const float* Wq = (const float*)d_in[3];
  const float* bq = (const float*)d_in[4];
  const float* Wk = (const float*)d_in[5];
  const float* bk = (const float*)d_in[6];
  const float* Wv = (const float*)d_in[7];
  const float* bv = (const float*)d_in[8];
  float* out = (float*)d_out;

  char* p = (char*)d_ws;
  const size_t H16 = (size_t)BB * SS * DD * 2;  // 8 MB
  u16* Qh   = (u16*)(p + 0 * H16);  u16* Ql   = (u16*)(p + 1 * H16);
  u16* Kh   = (u16*)(p + 2 * H16);  u16* Kl   = (u16*)(p + 3 * H16);
  u16* KTh  = (u16*)(p + 4 * H16);  u16* KTl  = (u16*)(p + 5 * H16);
  u16* VTh  = (u16*)(p + 6 * H16);  u16* VTl  = (u16*)(p + 7 * H16);
  u16* Sgh  = (u16*)(p + 10 * H16); u16* Sgl  = (u16*)(p + 11 * H16);
  u16* cMh  = (u16*)(p + 12 * H16); u16* cMl  = (u16*)(p + 13 * H16);
  float* lMatT = (float*)(p + 14 * H16);
  u16* Wth = (u16*)(p + 18 * H16);
  u16* Wtl = (u16*)(p + 18 * H16 + 3 * DD * DD * 2);
  float* rsP  = (float*)(p + 18 * H16 + 6 * DD * DD * 2);
  float* lVec = rsP + (size_t)BB * SS;

  init_pack_kernel<<<dim3(3, 16), 256, 0, stream>>>(Wq, Wk, Wv, Wth, Wtl, rsP, lVec);
  proj_kernel<<<dim3(BB * SS / 128, 2, 3), 256, 0, stream>>>(
      xq, xk, xv, Wth, Wtl, bq, bk, bv, Qh, Ql, Kh, Kl, KTh, KTl, VTh, VTl, lVec);
  scores_kernel<<<dim3(BB * NCH, 6), 256, 0, stream>>>(
      Qh, Ql, Kh, Kl, lVec, Sgh, Sgl, rsP);
  lmat_kernel<<<dim3(BB * NCH, 8), 256, 0, stream>>>(VTh, VTl, rsP, KTh, KTl, lMatT);
  combine_mat_kernel<<<128, 256, 0, stream>>>(lMatT, cMh, cMl);
  out_kernel<<<dim3(BB * NCH, 8), 256, 0, stream>>>(
      Qh, Ql, cMh, cMl, Sgh, Sgl, VTh, VTl, rsP, out);
}

// Round 13
// 198.162 us; speedup vs baseline: 1.1460x; 1.0129x over previous
//
#include <hip/hip_runtime.h>
#include <math.h>

// Retention (B=4, S=4096, D=256): chunkwise, split-bf16 MFMA, packed k8-slab
// operands.
// R1-R7: see history. R7 = 198us. R12 = R7 + V split-bf16 (traffic -80MB,
//   L3-absorbed, time-neutral; kept for the freed L2 footprint).
// R8/R9/R10: FAILED (asm barriers / scattered fp32 loads / VGPR spill).
// R13: proj restructured BM=64 x BN=256 (pn merged): X loaded+split ONCE per
//   row-panel (was 2x across pn blocks), 4 waves own 64-col strips with W^T
//   frags in regs, A dbuf halves to 17.4KB, grid (256,1,3) stays 3/CU
//   uniform. Epilogue = 4 quarter-width passes. Others unchanged from R12.
#define BB 4
#define SS 4096
#define DD 256
#define LL 256
#define NCH 16
#define GAMMA 0.9865f
#define LOG2G (-0.019609034f)   // log2(0.9865)
#define INV1MG 74.07407407f     // 1/(1-gamma)
#define SLAB 1032               // padded LDS slab stride (u16), 128-row panels
#define SLABB 520               // padded LDS slab stride (u16), 64-row panels

typedef __attribute__((ext_vector_type(8))) short short8;
typedef __attribute__((ext_vector_type(4))) float f32x4;
typedef unsigned short u16;
typedef unsigned int u32;

__device__ __forceinline__ u16 f2bf(float f) {
  union { float f; unsigned u; } v; v.f = f;
  unsigned r = v.u + 0x7FFFu + ((v.u >> 16) & 1u);
  return (u16)(r >> 16);
}
__device__ __forceinline__ float bf2f(u16 h) {
  union { unsigned u; float f; } v; v.u = ((unsigned)h) << 16; return v.f;
}

__device__ __forceinline__ void gll16(const u16* g, u16* l) {
  __builtin_amdgcn_global_load_lds(
      (const __attribute__((address_space(1))) u32*)g,
      (__attribute__((address_space(3))) u32*)l, 16, 0, 0);
}
// stage one BK=32 k-step of a 128-row panel (4 slabs) into padded LDS
__device__ __forceinline__ void stage8kp(const u16* g, u16* l, int lane) {
#pragma unroll
  for (int i = 0; i < 8; ++i)
    gll16(g + i * 512 + lane * 8, l + (i >> 1) * SLAB + (i & 1) * 512);
}

// 64-row A from LDS (SLABB slabs), B regs[4]; 64x64 per wave (proj R13)
__device__ __forceinline__ void mfma_step_regB64(
    const u16* Ah, const u16* Al, const short8 bh[4], const short8 bl[4],
    int fm, int fq, f32x4 acc[4][4])
{
  const int ka = fq * SLABB;
  short8 ah[4], al[4];
#pragma unroll
  for (int i = 0; i < 4; ++i) {
    ah[i] = *(const short8*)&Ah[ka + (i * 16 + fm) * 8];
    al[i] = *(const short8*)&Al[ka + (i * 16 + fm) * 8];
  }
#pragma unroll
  for (int j = 0; j < 4; ++j)
#pragma unroll
    for (int i = 0; i < 4; ++i) {
      acc[i][j] = __builtin_amdgcn_mfma_f32_16x16x32_bf16(al[i], bh[j], acc[i][j], 0, 0, 0);
      acc[i][j] = __builtin_amdgcn_mfma_f32_16x16x32_bf16(ah[i], bl[j], acc[i][j], 0, 0, 0);
      acc[i][j] = __builtin_amdgcn_mfma_f32_16x16x32_bf16(ah[i], bh[j], acc[i][j], 0, 0, 0);
    }
}

// 128x64 tile, A from LDS, B from regs, split-bf16 3-product
__device__ __forceinline__ void mfma_step_regB_ab(
    const u16* Ah, const u16* Al, const short8 bh[2], const short8 bl[2],
    int wm0, int fm, int fq, f32x4 acc[4][2])
{
  const int ka = fq * SLAB;
  short8 ah[4], al[4];
#pragma unroll
  for (int i = 0; i < 4; ++i) {
    ah[i] = *(const short8*)&Ah[ka + (wm0 + i * 16 + fm) * 8];
    al[i] = *(const short8*)&Al[ka + (wm0 + i * 16 + fm) * 8];
  }
#pragma unroll
  for (int j = 0; j < 2; ++j)
#pragma unroll
    for (int i = 0; i < 4; ++i) {
      acc[i][j] = __builtin_amdgcn_mfma_f32_16x16x32_bf16(al[i], bh[j], acc[i][j], 0, 0, 0);
      acc[i][j] = __builtin_amdgcn_mfma_f32_16x16x32_bf16(ah[i], bl[j], acc[i][j], 0, 0, 0);
      acc[i][j] = __builtin_amdgcn_mfma_f32_16x16x32_bf16(ah[i], bh[j], acc[i][j], 0, 0, 0);
    }
}

// load a wave's 64-row-panel B-fragments (2 col-groups, hi+lo) from global.
__device__ __forceinline__ void loadB2(short8 bh[2], short8 bl[2],
    const u16* BhP, const u16* BlP, int ks, int wn0, int fm, int fq)
{
  const int base = ks * 4096 + fq * 1024;
#pragma unroll
  for (int j = 0; j < 2; ++j) {
    int o = base + (wn0 + j * 16 + fm) * 8;
    bh[j] = *(const short8*)&BhP[o];
    bl[j] = *(const short8*)&BlP[o];
  }
}

// 128x64 tile (4 waves, 64x32 each), A from LDS, B from LDS (out-intra)
__device__ __forceinline__ void mfma_step_ab(
    const u16* Ah, const u16* Al, const u16* Bh, const u16* Bl,
    int wm0, int wn0, int fm, int fq, f32x4 acc[4][2])
{
  const int ka = fq * SLAB, kb = fq * SLABB;
  short8 ah[4], al[4];
#pragma unroll
  for (int i = 0; i < 4; ++i) {
    ah[i] = *(const short8*)&Ah[ka + (wm0 + i * 16 + fm) * 8];
    al[i] = *(const short8*)&Al[ka + (wm0 + i * 16 + fm) * 8];
  }
#pragma unroll
  for (int j = 0; j < 2; ++j) {
    short8 bh = *(const short8*)&Bh[kb + (wn0 + j * 16 + fm) * 8];
    short8 bl = *(const short8*)&Bl[kb + (wn0 + j * 16 + fm) * 8];
#pragma unroll
    for (int i = 0; i < 4; ++i) {
      acc[i][j] = __builtin_amdgcn_mfma_f32_16x16x32_bf16(al[i], bh, acc[i][j], 0, 0, 0);
      acc[i][j] = __builtin_amdgcn_mfma_f32_16x16x32_bf16(ah[i], bl, acc[i][j], 0, 0, 0);
      acc[i][j] = __builtin_amdgcn_mfma_f32_16x16x32_bf16(ah[i], bh, acc[i][j], 0, 0, 0);
    }
  }
}

// ---------------------------------------------------------------------------
// 0) pack W^T slabs (hi/lo) + zero rsP/lVec accumulators. grid (3, 16).
__global__ __launch_bounds__(256) void init_pack_kernel(
    const float* __restrict__ Wq, const float* __restrict__ Wk, const float* __restrict__ Wv,
    u16* __restrict__ Wth, u16* __restrict__ Wtl,
    float* __restrict__ rsP, float* __restrict__ lVec)
{
  const int which = blockIdx.x;
  const int it = blockIdx.y;
  const int t = threadIdx.x;
  if (which == 0) {
    *(float4*)&rsP[(size_t)(it * 256 + t) * 4] = (float4){0.f, 0.f, 0.f, 0.f};
  } else if (which == 1) {
    *(float4*)&lVec[(size_t)(it * 256 + t) * 4] = (float4){0.f, 0.f, 0.f, 0.f};
  }
  const float* W = which == 0 ? Wq : (which == 1 ? Wk : Wv);
  for (int pn = 0; pn < 2; ++pn) {
    int pos = it * 256 + t;
    int k8 = pos >> 7, r = pos & 127;
    u16 hs[8], ls[8];
#pragma unroll
    for (int u = 0; u < 8; ++u) {
      float x = W[(size_t)(k8 * 8 + u) * DD + pn * 128 + r];
      u16 h = f2bf(x); hs[u] = h; ls[u] = f2bf(x - bf2f(h));
    }
    size_t o = ((size_t)((which * 2 + pn) * 32 + k8)) * 1024 + (size_t)r * 8;
    *(short8*)&Wth[o] = *(short8*)hs;
    *(short8*)&Wtl[o] = *(short8*)ls;
  }
}

// ---------------------------------------------------------------------------
// 1) projections (R13): BM=64 x BN=256, pn merged. A: fp32 X (64x32/step)
//    reg-prefetched, split once into SLABB dbuf. B: W^T frags in regs per
//    wave (4 col-groups over its 64-col strip). 4 quarter-width epilogues.
__global__ __launch_bounds__(256, 3) void proj_kernel(
    const float* __restrict__ xq, const float* __restrict__ xk, const float* __restrict__ xv,
    const u16* __restrict__ Wth, const u16* __restrict__ Wtl,
    const float* __restrict__ bq, const float* __restrict__ bk_, const float* __restrict__ bv,
    u16* __restrict__ Qh, u16* __restrict__ Ql,
    u16* __restrict__ Kh, u16* __restrict__ Kl,
    u16* __restrict__ KTh, u16* __restrict__ KTl,
    u16* __restrict__ VTh, u16* __restrict__ VTl,
    float* __restrict__ lVec)
{
  const int which = blockIdx.z;
  const float* bias = which == 0 ? bq : (which == 1 ? bk_ : bv);
  const int m0 = blockIdx.x * 64;
  __shared__ u16 SM[16 * SLABB];          // A dbuf (2 x (4hi+4lo) SLABB slabs)
  __shared__ float rsc[64];
  __shared__ float wlut[64];
  __shared__ float kacc[64];
  float* fb = (float*)SM;                 // 64x65 fp32 bounce (epilogue only)
  const int tid = threadIdx.x, lane = tid & 63, wave = tid >> 6;
  const int wn0g = wave * 64;             // wave's global col strip
  const int fm = lane & 15, fq = lane >> 4;
  if (which == 1 && tid < 64) {
    int sb = (m0 & (SS - 1)) + tid;
    rsc[tid] = rsqrtf((1.0f - exp2f((float)(sb + 1) * LOG2G)) * INV1MG);
    wlut[tid] = exp2f((float)(255 - ((m0 & (LL - 1)) + tid)) * LOG2G);
    kacc[tid] = 0.f;
  }
  const float* XP = (which == 0 ? xq : (which == 1 ? xk : xv)) + (size_t)m0 * DD;
  const int pnw = wn0g >> 7, wl = wn0g & 127;
  const u16* WhP = Wth + (size_t)((which * 2 + pnw) * 32) * 1024;
  const u16* WlP = Wtl + (size_t)((which * 2 + pnw) * 32) * 1024;
  const int arow = tid >> 2, ak8 = tid & 3;  // 64 rows x 4 k8, 1 unit/thread
  f32x4 acc[4][4];
#pragma unroll
  for (int i = 0; i < 4; ++i)
#pragma unroll
    for (int j = 0; j < 4; ++j) acc[i][j] = (f32x4){0.f, 0.f, 0.f, 0.f};
  float xs[8];
  short8 bh[4], bl[4];
  // prologue: W(0) into regs, X(0) into buffer 0
  {
    const int base = fq * 1024;
#pragma unroll
    for (int j = 0; j < 4; ++j) {
      int o = base + (wl + j * 16 + fm) * 8;
      bh[j] = *(const short8*)&WhP[o];
      bl[j] = *(const short8*)&WlP[o];
    }
  }
  {
    const float* src = XP + (size_t)arow * DD + ak8 * 8;
    *(float4*)&xs[0] = *(const float4*)src;
    *(float4*)&xs[4] = *(const float4*)(src + 4);
    u16 hs[8], ls[8];
#pragma unroll
    for (int u = 0; u < 8; ++u) {
      u16 h = f2bf(xs[u]); hs[u] = h; ls[u] = f2bf(xs[u] - bf2f(h));
    }
    *(short8*)&SM[ak8 * SLABB + arow * 8] = *(short8*)hs;
    *(short8*)&SM[4 * SLABB + ak8 * SLABB + arow * 8] = *(short8*)ls;
  }
  int cur = 0;
  for (int ks = 0; ks < 8; ++ks) {
    __syncthreads();                       // buf[cur] ready
    u16* Ac = SM + cur * 8 * SLABB;
    u16* An = SM + (cur ^ 1) * 8 * SLABB;
    if (ks < 7) {
      const float* src = XP + (size_t)arow * DD + (ks + 1) * 32 + ak8 * 8;
      *(float4*)&xs[0] = *(const float4*)src;
      *(float4*)&xs[4] = *(const float4*)(src + 4);
    }
    mfma_step_regB64(Ac, Ac + 4 * SLABB, bh, bl, fm, fq, acc);
    if (ks < 7) {
      const int base = (ks + 1) * 4096 + fq * 1024;
#pragma unroll
      for (int j = 0; j < 4; ++j) {        // prefetch next W frags
        int o = base + (wl + j * 16 + fm) * 8;
        bh[j] = *(const short8*)&WhP[o];
        bl[j] = *(const short8*)&WlP[o];
      }
      u16 hs[8], ls[8];
#pragma unroll
      for (int u = 0; u < 8; ++u) {
        u16 h = f2bf(xs[u]); hs[u] = h; ls[u] = f2bf(xs[u] - bf2f(h));
      }
      *(short8*)&An[ak8 * SLABB + arow * 8] = *(short8*)hs;
      *(short8*)&An[4 * SLABB + ak8 * SLABB + arow * 8] = *(short8*)ls;
    }
    cur ^= 1;
  }
  const int b = m0 >> 12, sbb = m0 & (SS - 1);
  for (int p = 0; p < 4; ++p) {            // quarter-width column passes
    __syncthreads();
    if (wn0g == p * 64) {                  // owning wave bounces acc -> fb
#pragma unroll
      for (int i = 0; i < 4; ++i)
#pragma unroll
        for (int j = 0; j < 4; ++j)
#pragma unroll
          for (int r = 0; r < 4; ++r)
            fb[(i * 16 + fq * 4 + r) * 65 + j * 16 + fm] = acc[i][j][r];
    }
    __syncthreads();
    if (which == 0) {
#pragma unroll
      for (int it = 0; it < 2; ++it) {
        int unit = it * 256 + tid;         // 8 k8 x 64 rows
        int k8l = unit >> 6, row = unit & 63;
        int gc0 = p * 64 + k8l * 8;
        u16 hs[8], ls[8];
#pragma unroll
        for (int u = 0; u < 8; ++u) {
          float v = (fb[row * 65 + k8l * 8 + u] + bias[gc0 + u]) * (1.f / 16.f);
          u16 h = f2bf(v); hs[u] = h; ls[u] = f2bf(v - bf2f(h));
        }
        size_t o = (size_t)(m0 >> 7) * 32768 + (size_t)(p * 8 + k8l) * 1024 +
                   (size_t)((m0 & 64) + row) * 8;
        *(short8*)&Qh[o] = *(short8*)hs;
        *(short8*)&Ql[o] = *(short8*)ls;
      }
    } else if (which == 1) {
#pragma unroll
      for (int it = 0; it < 2; ++it) {     // K (row-major panel)
        int unit = it * 256 + tid;
        int k8l = unit >> 6, row = unit & 63;
        int gc0 = p * 64 + k8l * 8;
        u16 hs[8], ls[8];
#pragma unroll
        for (int u = 0; u < 8; ++u) {
          float v = (fb[row * 65 + k8l * 8 + u] + bias[gc0 + u]) * rsc[row];
          u16 h = f2bf(v); hs[u] = h; ls[u] = f2bf(v - bf2f(h));
        }
        size_t o = (size_t)(m0 >> 7) * 32768 + (size_t)(p * 8 + k8l) * 1024 +
                   (size_t)((m0 & 64) + row) * 8;
        *(short8*)&Kh[o] = *(short8*)hs;
        *(short8*)&Kl[o] = *(short8*)ls;
      }
      float kpart = 0.f;
#pragma unroll
      for (int it = 0; it < 2; ++it) {     // KT (col-major packed) + lVec
        int unit = it * 256 + tid;
        int dl = unit & 63, s8l = unit >> 6;
        int gcolg = p * 64 + dl;
        float bs = bias[gcolg];
        u16 hs[8], ls[8];
#pragma unroll
        for (int u = 0; u < 8; ++u) {
          int row = s8l * 8 + u;
          float v = (fb[row * 65 + dl] + bs) * rsc[row];
          kpart = fmaf(v, wlut[row], kpart);
          u16 h = f2bf(v); hs[u] = h; ls[u] = f2bf(v - bf2f(h));
        }
        int sb0 = sbb + s8l * 8;
        size_t o = ((size_t)(b * 2 + (gcolg >> 7)) * 512 + (sb0 >> 3)) * 1024 + (size_t)(gcolg & 127) * 8;
        *(short8*)&KTh[o] = *(short8*)hs;
        *(short8*)&KTl[o] = *(short8*)ls;
      }
      atomicAdd(&kacc[tid & 63], kpart);
      __syncthreads();
      if (tid < 64) {
        int c = sbb >> 8;
        atomicAdd(&lVec[(size_t)(b * NCH + c) * DD + p * 64 + tid], kacc[tid]);
        kacc[tid] = 0.f;
      }
    } else {  // V: split-bf16, KT-packed layout
#pragma unroll
      for (int it = 0; it < 2; ++it) {
        int unit = it * 256 + tid;
        int dl = unit & 63, s8l = unit >> 6;
        int gcolg = p * 64 + dl;
        float bs = bias[gcolg];
        u16 hs[8], ls[8];
#pragma unroll
        for (int u = 0; u < 8; ++u) {
          float v = fb[(s8l * 8 + u) * 65 + dl] + bs;
          u16 h = f2bf(v); hs[u] = h; ls[u] = f2bf(v - bf2f(h));
        }
        int sb0 = sbb + s8l * 8;
        size_t o = ((size_t)(b * 2 + (gcolg >> 7)) * 512 + (sb0 >> 3)) * 1024 + (size_t)(gcolg & 127) * 8;
        *(short8*)&VTh[o] = *(short8*)hs;
        *(short8*)&VTl[o] = *(short8*)ls;
      }
    }
  }
}

// ---------------------------------------------------------------------------
// 3) Sg = mask*(Q~.K~)*g^(il-jl); fused rowsum + Q.cVec dot -> rsP atomics.
//    (R7 form) A = Q via gll16 dbuf; B = K fragments global->regs.
__global__ __launch_bounds__(256, 4) void scores_kernel(
    const u16* __restrict__ Qh, const u16* __restrict__ Ql,
    const u16* __restrict__ Kh, const u16* __restrict__ Kl,
    const float* __restrict__ lVec, u16* __restrict__ Sgh, u16* __restrict__ Sgl,
    float* __restrict__ rsP)
{
  const int chunk = blockIdx.x, b = chunk >> 4, c = chunk & 15;
  const int y = blockIdx.y;
  const int m0 = (y < 2) ? 0 : 128;
  const int jn0 = (y < 2) ? y * 64 : (y - 2) * 64;
  __shared__ u16 SA[2 * 8 * SLAB];
  __shared__ float cv[256], lut[256], rowAcc[128], qd2[2][128];
  float* fb = (float*)SA;  // 64x65 fp32 (epilogue; spans both A buffers)
  const int tid = threadIdx.x, lane = tid & 63, wave = tid >> 6;
  const int wm0 = (wave >> 1) * 64, wn0 = (wave & 1) * 32;
  const int fm = lane & 15, fq = lane >> 4;
  if (jn0 == 0) {  // inline prefix scan: cv = sum_{cp<c} gL^(c-1-cp) lVec[cp]
    const float gL = exp2f((float)LL * LOG2G);
    float s = 0.f;
    for (int cp = 0; cp < c; ++cp)
      s = fmaf(gL, s, lVec[(size_t)(b * NCH + cp) * DD + tid]);
    cv[tid] = s;
  }
  lut[tid] = exp2f((float)tid * LOG2G);
  if (tid < 128) rowAcc[tid] = 0.f;
  const int growA = b * SS + c * LL + m0;
  const int growB = b * SS + c * LL + jn0;
  const u16* QhP = Qh + (size_t)(growA >> 7) * 32768;
  const u16* QlP = Ql + (size_t)(growA >> 7) * 32768;
  const u16* KhP = Kh + (size_t)(growB >> 7) * 32768 + (size_t)(growB & 127) * 8;
  const u16* KlP = Kl + (size_t)(growB >> 7) * 32768 + (size_t)(growB & 127) * 8;
  f32x4 acc[4][2];
#pragma unroll
  for (int i = 0; i < 4; ++i)
#pragma unroll
    for (int j = 0; j < 2; ++j) acc[i][j] = (f32x4){0.f, 0.f, 0.f, 0.f};
  float qdreg = 0.f;
  const int qrow = tid & 127, qk8b = tid >> 7;
  short8 bh[2], bl[2];
  if (wave == 0) stage8kp(QhP, SA, lane);
  if (wave == 1) stage8kp(QlP, SA + 4 * SLAB, lane);
  loadB2(bh, bl, KhP, KlP, 0, wn0, fm, fq);
  int cur = 0;
  for (int ks = 0; ks < 8; ++ks) {
    __syncthreads();
    u16* Ac = cur ? SA + 8 * SLAB : SA;
    u16* An = cur ? SA : SA + 8 * SLAB;
    if (ks < 7) {
      if (wave == 0) stage8kp(QhP + (ks + 1) * 4096, An, lane);
      if (wave == 1) stage8kp(QlP + (ks + 1) * 4096, An + 4 * SLAB, lane);
    }
    mfma_step_regB_ab(Ac, Ac + 4 * SLAB, bh, bl, wm0, fm, fq, acc);
    if (ks < 7) loadB2(bh, bl, KhP, KlP, ks + 1, wn0, fm, fq);
    if (jn0 == 0) {
#pragma unroll
      for (int h2 = 0; h2 < 2; ++h2) {
        int k8l = qk8b + 2 * h2;
        const u16* ahp = &Ac[k8l * SLAB + qrow * 8];
        const u16* alp = &Ac[4 * SLAB + k8l * SLAB + qrow * 8];
#pragma unroll
        for (int u = 0; u < 8; ++u)
          qdreg = fmaf(bf2f(ahp[u]) + bf2f(alp[u]), cv[ks * 32 + k8l * 8 + u], qdreg);
      }
    }
    cur ^= 1;
  }
  qd2[qk8b][qrow] = qdreg;
  const int ps = chunk * 2 + (m0 >> 7);
  for (int rh = 0; rh < 2; ++rh) {
    __syncthreads();
    if (wm0 == rh * 64) {
#pragma unroll
      for (int i = 0; i < 4; ++i)
#pragma unroll
        for (int j = 0; j < 2; ++j)
#pragma unroll
          for (int r = 0; r < 4; ++r)
            fb[(i * 16 + fq * 4 + r) * 65 + wn0 + j * 16 + fm] = acc[i][j][r];
    }
    __syncthreads();
#pragma unroll
    for (int it = 0; it < 2; ++it) {
      int unit = it * 256 + tid;          // 8 k8-cols x 64 rows
      int k8l = unit >> 6, rowl = unit & 63;
      int il = m0 + rh * 64 + rowl;
      int jlb = jn0 + k8l * 8;
      float part = 0.f;
      u16 hs[8], ls[8];
#pragma unroll
      for (int u = 0; u < 8; ++u) {
        int jl = jlb + u;
        float v = (jl <= il) ? fb[rowl * 65 + k8l * 8 + u] * lut[il - jl] : 0.f;
        part += v;
        u16 h = f2bf(v); hs[u] = h; ls[u] = f2bf(v - bf2f(h));
      }
      atomicAdd(&rowAcc[rh * 64 + rowl], part);
      size_t o = (size_t)(ps * 32 + (jn0 >> 3) + k8l) * 1024 + (size_t)(rh * 64 + rowl) * 8;
      *(short8*)&Sgh[o] = *(short8*)hs;
      *(short8*)&Sgl[o] = *(short8*)ls;
    }
  }
  __syncthreads();
  if (tid < 128) {
    float rs = rowAcc[tid];
    if (jn0 == 0)
      rs += exp2f((float)(m0 + tid + 1) * LOG2G) * (qd2[0][tid] + qd2[1][tid]);
    atomicAdd(&rsP[(size_t)b * SS + c * LL + m0 + tid], rs);
  }
}

// ---------------------------------------------------------------------------
// 5) lMatT[e][d] = sum_jl Vw[jl,e] K~[jl,d] ; 128x64 tiles (grid 64x8)
//    (R12) A = V split-bf16 reg-staged -> LDS dbuf (hi+lo, wtl/denom fused);
//    B = KT global->regs.
__global__ __launch_bounds__(256, 4) void lmat_kernel(
    const u16* __restrict__ VTh, const u16* __restrict__ VTl,
    const float* __restrict__ rsP,
    const u16* __restrict__ KTh, const u16* __restrict__ KTl,
    float* __restrict__ lMatT)
{
  const int chunk = blockIdx.x, b = chunk >> 4, c = chunk & 15;
  const int ty = blockIdx.y;
  const int m0 = (ty >> 2) * 128, n0 = (ty & 3) * 64;
  __shared__ u16 SA[2 * 8 * SLAB];
  __shared__ float swl[256];
  const int tid = threadIdx.x, lane = tid & 63, wave = tid >> 6;
  const int wm0 = (wave >> 1) * 64, wn0 = (wave & 1) * 32;
  const int fm = lane & 15, fq = lane >> 4;
  // per-jl scale = gamma^(255-jl) / max(|rsP|,1)
  swl[tid] = exp2f((float)(255 - tid) * LOG2G) /
             fmaxf(fabsf(rsP[(size_t)b * SS + c * LL + tid]), 1.0f);
  const u16* AThP = VTh + ((size_t)(b * 2 + (m0 >> 7)) * 512 + c * 32) * 1024;
  const u16* ATlP = VTl + ((size_t)(b * 2 + (m0 >> 7)) * 512 + c * 32) * 1024;
  const u16* BhP = KTh + ((size_t)(b * 2 + (n0 >> 7)) * 512 + c * 32) * 1024 + (size_t)(n0 & 127) * 8;
  const u16* BlP = KTl + ((size_t)(b * 2 + (n0 >> 7)) * 512 + c * 32) * 1024 + (size_t)(n0 & 127) * 8;
  const int arow = tid >> 1;               // 128 rows, 2 threads/row
  f32x4 acc[4][2];
#pragma unroll
  for (int i = 0; i < 4; ++i)
#pragma unroll
    for (int j = 0; j < 2; ++j) acc[i][j] = (f32x4){0.f, 0.f, 0.f, 0.f};
  short8 vh[2], vl[2];
  short8 bh[2], bl[2];
  loadB2(bh, bl, BhP, BlP, 0, wn0, fm, fq);
#pragma unroll
  for (int t = 0; t < 2; ++t) {            // prologue loads ks=0
    int ak8 = (tid & 1) * 2 + t;
    int off = ak8 * 1024 + arow * 8;
    vh[t] = *(const short8*)&AThP[off];
    vl[t] = *(const short8*)&ATlP[off];
  }
  __syncthreads();                         // swl ready
#pragma unroll
  for (int t = 0; t < 2; ++t) {
    int ak8 = (tid & 1) * 2 + t;
    u16 hs[8], ls[8];
#pragma unroll
    for (int u = 0; u < 8; ++u) {
      float v = (bf2f((u16)vh[t][u]) + bf2f((u16)vl[t][u])) * swl[ak8 * 8 + u];
      u16 h = f2bf(v); hs[u] = h; ls[u] = f2bf(v - bf2f(h));
    }
    *(short8*)&SA[ak8 * SLAB + arow * 8] = *(short8*)hs;
    *(short8*)&SA[4 * SLAB + ak8 * SLAB + arow * 8] = *(short8*)ls;
  }
  int cur = 0;
  for (int ks = 0; ks < 8; ++ks) {
    __syncthreads();
    u16* Ac = cur ? SA + 8 * SLAB : SA;
    u16* An = cur ? SA : SA + 8 * SLAB;
    if (ks < 7) {
#pragma unroll
      for (int t = 0; t < 2; ++t) {
        int ak8 = (tid & 1) * 2 + t;
        int off = ((ks + 1) * 4 + ak8) * 1024 + arow * 8;
        vh[t] = *(const short8*)&AThP[off];
        vl[t] = *(const short8*)&ATlP[off];
      }
    }
    mfma_step_regB_ab(Ac, Ac + 4 * SLAB, bh, bl, wm0, fm, fq, acc);
    if (ks < 7) {
      loadB2(bh, bl, BhP, BlP, ks + 1, wn0, fm, fq);
#pragma unroll
      for (int t = 0; t < 2; ++t) {
        int ak8 = (tid & 1) * 2 + t;
        u16 hs[8], ls[8];
#pragma unroll
        for (int u = 0; u < 8; ++u) {
          float v = (bf2f((u16)vh[t][u]) + bf2f((u16)vl[t][u])) *
                    swl[(ks + 1) * 32 + ak8 * 8 + u];
          u16 h = f2bf(v); hs[u] = h; ls[u] = f2bf(v - bf2f(h));
        }
        *(short8*)&An[ak8 * SLAB + arow * 8] = *(short8*)hs;
        *(short8*)&An[4 * SLAB + ak8 * SLAB + arow * 8] = *(short8*)ls;
      }
    }
    cur ^= 1;
  }
#pragma unroll
  for (int i = 0; i < 4; ++i)
#pragma unroll
    for (int j = 0; j < 2; ++j)
#pragma unroll
      for (int r = 0; r < 4; ++r) {
        int e = m0 + wm0 + i * 16 + fq * 4 + r;
        int d = n0 + wn0 + j * 16 + fm;
        lMatT[(size_t)chunk * 65536 + (size_t)e * 256 + d] = acc[i][j][r];
      }
}

// 6) carry scan -> cM packed split
__global__ __launch_bounds__(256) void combine_mat_kernel(
    const float* __restrict__ lMatT, u16* __restrict__ cMh, u16* __restrict__ cMl)
{
  const int t = blockIdx.x * 256 + threadIdx.x;
  const int b = t >> 13, rem = t & 8191;
  const int k8 = rem >> 8, e = rem & 255;
  const float gL = powf(GAMMA, (float)LL);
  float s[8] = {0.f, 0.f, 0.f, 0.f, 0.f, 0.f, 0.f, 0.f};
  for (int ch = 0; ch < 16; ++ch) {
    size_t ro = (size_t)(b * 16 + ch) * 65536 + (size_t)e * 256 + k8 * 8;
    float4 a0 = *(const float4*)&lMatT[ro];
    float4 a1 = *(const float4*)&lMatT[ro + 4];
    float vals[8] = {a0.x, a0.y, a0.z, a0.w, a1.x, a1.y, a1.z, a1.w};
    u16 hh[8], ll[8];
#pragma unroll
    for (int u = 0; u < 8; ++u) {
      u16 h = f2bf(s[u]); hh[u] = h; ll[u] = f2bf(s[u] - bf2f(h));
    }
    size_t wo = ((size_t)(((b * 16 + ch) * 2 + (e >> 7)) * 32 + k8)) * 1024 + (size_t)(e & 127) * 8;
    *(short8*)&cMh[wo] = *(short8*)hh;
    *(short8*)&cMl[wo] = *(short8*)ll;
#pragma unroll
    for (int u = 0; u < 8; ++u) s[u] = gL * s[u] + vals[u];
  }
}

// ---------------------------------------------------------------------------
// 7) out = g^(il+1) * Q~ @ cM^T + Sg @ Vd ; 128x64 tiles (grid 64x8)
//    (R12) inter: A=Q gll16 dbuf, B=cM regs. intra: A=Sg gll16,
//    B = V split-bf16 reg-staged -> LDS dbuf (hi+lo reconstruct, 1/denom).
__global__ __launch_bounds__(256, 3) void out_kernel(
    const u16* __restrict__ Qh, const u16* __restrict__ Ql,
    const u16* __restrict__ cMh, const u16* __restrict__ cMl,
    const u16* __restrict__ Sgh, const u16* __restrict__ Sgl,
    const u16* __restrict__ VTh, const u16* __restrict__ VTl,
    const float* __restrict__ rsP,
    float* __restrict__ out)
{
  const int chunk = blockIdx.x, b = chunk >> 4, c = chunk & 15;
  const int ty = blockIdx.y;
  const int m0 = (ty >> 2) * 128, n0 = (ty & 3) * 64;
  __shared__ u16 SA[2 * 8 * SLAB];
  __shared__ u16 SB[2 * 8 * SLABB];
  __shared__ float olut[128];
  __shared__ float sdn[256];
  const int tid = threadIdx.x, lane = tid & 63, wave = tid >> 6;
  const int wm0 = (wave >> 1) * 64, wn0 = (wave & 1) * 32;
  const int fm = lane & 15, fq = lane >> 4;
  if (tid < 128) olut[tid] = exp2f((float)(m0 + tid + 1) * LOG2G);
  sdn[tid] = 1.0f / fmaxf(fabsf(rsP[(size_t)b * SS + c * LL + tid]), 1.0f);
  f32x4 acc[4][2];
#pragma unroll
  for (int i = 0; i < 4; ++i)
#pragma unroll
    for (int j = 0; j < 2; ++j) acc[i][j] = (f32x4){0.f, 0.f, 0.f, 0.f};
  int cur = 0;
  {  // inter: A = Q panel (gll16 dbuf), B = cM rows n0..n0+64 (regs)
    const u16* AhP = Qh + (size_t)(b * 32 + c * 2 + (m0 >> 7)) * 32768;
    const u16* AlP = Ql + (size_t)(b * 32 + c * 2 + (m0 >> 7)) * 32768;
    const u16* BhP = cMh + (size_t)(chunk * 2 + (n0 >> 7)) * 32768 + (size_t)(n0 & 127) * 8;
    const u16* BlP = cMl + (size_t)(chunk * 2 + (n0 >> 7)) * 32768 + (size_t)(n0 & 127) * 8;
    short8 bh[2], bl[2];
    if (wave == 0) stage8kp(AhP, SA, lane);
    if (wave == 1) stage8kp(AlP, SA + 4 * SLAB, lane);
    loadB2(bh, bl, BhP, BlP, 0, wn0, fm, fq);
    for (int ks = 0; ks < 8; ++ks) {
      __syncthreads();
      u16* Ac = cur ? SA + 8 * SLAB : SA;
      u16* An = cur ? SA : SA + 8 * SLAB;
      if (ks < 7) {
        if (wave == 0) stage8kp(AhP + (ks + 1) * 4096, An, lane);
        if (wave == 1) stage8kp(AlP + (ks + 1) * 4096, An + 4 * SLAB, lane);
      }
      mfma_step_regB_ab(Ac, Ac + 4 * SLAB, bh, bl, wm0, fm, fq, acc);
      if (ks < 7) loadB2(bh, bl, BhP, BlP, ks + 1, wn0, fm, fq);
      cur ^= 1;
    }
  }
  {  // intra: A = Sg (gll16), B = V split-bf16 reg-staged -> LDS dbuf
    const u16* AhP = Sgh + (size_t)(chunk * 2 + (m0 >> 7)) * 32768;
    const u16* AlP = Sgl + (size_t)(chunk * 2 + (m0 >> 7)) * 32768;
    const u16* BThP = VTh + ((size_t)(b * 2 + (n0 >> 7)) * 512 + c * 32) * 1024 + (size_t)(n0 & 127) * 8;
    const u16* BTlP = VTl + ((size_t)(b * 2 + (n0 >> 7)) * 512 + c * 32) * 1024 + (size_t)(n0 & 127) * 8;
    const int ber = tid >> 2, bk8 = tid & 3;  // 64 rows x 4 k8, 1 unit/thread
    const int nks = (m0 >> 5) + 4;
    short8 vh, vl;
    {  // prologue into buf[cur] (last read 2 steps ago -> safe)
      u16* Ac = cur ? SA + 8 * SLAB : SA;
      u16* Bc = cur ? SB + 8 * SLABB : SB;
      if (wave == 0) stage8kp(AhP, Ac, lane);
      if (wave == 1) stage8kp(AlP, Ac + 4 * SLAB, lane);
      int off = bk8 * 1024 + ber * 8;
      vh = *(const short8*)&BThP[off];
      vl = *(const short8*)&BTlP[off];
      // overlap acc scaling with the loads
#pragma unroll
      for (int i = 0; i < 4; ++i)
#pragma unroll
        for (int r = 0; r < 4; ++r) {
          int rl = wm0 + i * 16 + fq * 4 + r;
          float sc = olut[rl];
#pragma unroll
          for (int j = 0; j < 2; ++j) acc[i][j][r] *= sc;
        }
      u16 hs[8], ls[8];
#pragma unroll
      for (int u = 0; u < 8; ++u) {
        float v = (bf2f((u16)vh[u]) + bf2f((u16)vl[u])) * sdn[bk8 * 8 + u];
        u16 h = f2bf(v); hs[u] = h; ls[u] = f2bf(v - bf2f(h));
      }
      *(short8*)&Bc[bk8 * SLABB + ber * 8] = *(short8*)hs;
      *(short8*)&Bc[4 * SLABB + bk8 * SLABB + ber * 8] = *(short8*)ls;
    }
    for (int ks = 0; ks < nks; ++ks) {
      __syncthreads();
      u16* Ac = cur ? SA + 8 * SLAB : SA;
      u16* Bc = cur ? SB + 8 * SLABB : SB;
      u16* An = cur ? SA : SA + 8 * SLAB;
      u16* Bn = cur ? SB : SB + 8 * SLABB;
      if (ks + 1 < nks) {
        if (wave == 0) stage8kp(AhP + (ks + 1) * 4096, An, lane);
        if (wave == 1) stage8kp(AlP + (ks + 1) * 4096, An + 4 * SLAB, lane);
        int off = ((ks + 1) * 4 + bk8) * 1024 + ber * 8;
        vh = *(const short8*)&BThP[off];
        vl = *(const short8*)&BTlP[off];
      }
      mfma_step_ab(Ac, Ac + 4 * SLAB, Bc, Bc + 4 * SLABB, wm0, wn0, fm, fq, acc);
      if (ks + 1 < nks) {
        u16 hs[8], ls[8];
#pragma unroll
        for (int u = 0; u < 8; ++u) {
          float v = (bf2f((u16)vh[u]) + bf2f((u16)vl[u])) *
                    sdn[(ks + 1) * 32 + bk8 * 8 + u];
          u16 h = f2bf(v); hs[u] = h; ls[u] = f2bf(v - bf2f(h));
        }
        *(short8*)&Bn[bk8 * SLABB + ber * 8] = *(short8*)hs;
        *(short8*)&Bn[4 * SLABB + bk8 * SLABB + ber * 8] = *(short8*)ls;
      }
      cur ^= 1;
    }
  }
#pragma unroll
  for (int i = 0; i < 4; ++i)
#pragma unroll
    for (int j = 0; j < 2; ++j)
#pragma unroll
      for (int r = 0; r < 4; ++r) {
        int il = m0 + wm0 + i * 16 + fq * 4 + r;
        int e = n0 + wn0 + j * 16 + fm;
        out[(size_t)(b * SS + c * LL + il) * DD + e] = acc[i][j][r];
      }
}

// ---------------------------------------------------------------------------
extern "C" void kernel_launch(void* const* d_in, const int* in_sizes, int n_in,
                              void* d_out, int out_size, void* d_ws, size_t ws_size,
                              hipStream_t stream) {
  const float* xq = (const float*)d_in[0];
  const float* xk = (const float*)d_in[1];
  const float* xv = (const float*)d_in[2];
  const float* Wq = (const float*)d_in[3];
  const float* bq = (const float*)d_in[4];
  const float* Wk = (const float*)d_in[5];
  const float* bk = (const float*)d_in[6];
  const float* Wv = (const float*)d_in[7];
  const float* bv = (const float*)d_in[8];
  float* out = (float*)d_out;

  char* p = (char*)d_ws;
  const size_t H16 = (size_t)BB * SS * DD * 2;  // 8 MB
  u16* Qh   = (u16*)(p + 0 * H16);  u16* Ql   = (u16*)(p + 1 * H16);
  u16* Kh   = (u16*)(p + 2 * H16);  u16* Kl   = (u16*)(p + 3 * H16);
  u16* KTh  = (u16*)(p + 4 * H16);  u16* KTl  = (u16*)(p + 5 * H16);
  u16* VTh  = (u16*)(p + 6 * H16);  u16* VTl  = (u16*)(p + 7 * H16);
  u16* Sgh  = (u16*)(p + 10 * H16); u16* Sgl  = (u16*)(p + 11 * H16);
  u16* cMh  = (u16*)(p + 12 * H16); u16* cMl  = (u16*)(p + 13 * H16);
  float* lMatT = (float*)(p + 14 * H16);
  u16* Wth = (u16*)(p + 18 * H16);
  u16* Wtl = (u16*)(p + 18 * H16 + 3 * DD * DD * 2);
  float* rsP  = (float*)(p + 18 * H16 + 6 * DD * DD * 2);
  float* lVec = rsP + (size_t)BB * SS;

  init_pack_kernel<<<dim3(3, 16), 256, 0, stream>>>(Wq, Wk, Wv, Wth, Wtl, rsP, lVec);
  proj_kernel<<<dim3(BB * SS / 64, 1, 3), 256, 0, stream>>>(
      xq, xk, xv, Wth, Wtl, bq, bk, bv, Qh, Ql, Kh, Kl, KTh, KTl, VTh, VTl, lVec);
  scores_kernel<<<dim3(BB * NCH, 6), 256, 0, stream>>>(
      Qh, Ql, Kh, Kl, lVec, Sgh, Sgl, rsP);
  lmat_kernel<<<dim3(BB * NCH, 8), 256, 0, stream>>>(VTh, VTl, rsP, KTh, KTl, lMatT);
  combine_mat_kernel<<<128, 256, 0, stream>>>(lMatT, cMh, cMl);
  out_kernel<<<dim3(BB * NCH, 8), 256, 0, stream>>>(
      Qh, Ql, cMh, cMl, Sgh, Sgl, VTh, VTl, rsP, out);
}

// Round 14
// 196.999 us; speedup vs baseline: 1.1527x; 1.0059x over previous
//
#include <hip/hip_runtime.h>
#include <math.h>

// Retention (B=4, S=4096, D=256): chunkwise, split-bf16 MFMA, packed k8-slab
// operands.
// R1-R13: see history. R13 = 198us; proj now <40us; AB kernels dominate.
// R14: scores/lmat re-tiled to 64-row blocks (scores grid 64x10 causal
//   triangle, lmat 64x16): waves/SIMD 1.5-2 -> 2.5-4 (grid-limited latency
//   hiding was the MfmaUtil~16% plateau). Wave tile 32x32 (acc[2][2]),
//   A dbuf halves to SLABB stride. proj/out/combine/init unchanged.
#define BB 4
#define SS 4096
#define DD 256
#define LL 256
#define NCH 16
#define GAMMA 0.9865f
#define LOG2G (-0.019609034f)   // log2(0.9865)
#define INV1MG 74.07407407f     // 1/(1-gamma)
#define SLAB 1032               // padded LDS slab stride (u16), 128-row panels
#define SLABB 520               // padded LDS slab stride (u16), 64-row panels

typedef __attribute__((ext_vector_type(8))) short short8;
typedef __attribute__((ext_vector_type(4))) float f32x4;
typedef unsigned short u16;
typedef unsigned int u32;

__device__ __forceinline__ u16 f2bf(float f) {
  union { float f; unsigned u; } v; v.f = f;
  unsigned r = v.u + 0x7FFFu + ((v.u >> 16) & 1u);
  return (u16)(r >> 16);
}
__device__ __forceinline__ float bf2f(u16 h) {
  union { unsigned u; float f; } v; v.u = ((unsigned)h) << 16; return v.f;
}

__device__ __forceinline__ void gll16(const u16* g, u16* l) {
  __builtin_amdgcn_global_load_lds(
      (const __attribute__((address_space(1))) u32*)g,
      (__attribute__((address_space(3))) u32*)l, 16, 0, 0);
}
// stage one BK=32 k-step of a 128-row panel (4 slabs) into padded LDS
__device__ __forceinline__ void stage8kp(const u16* g, u16* l, int lane) {
#pragma unroll
  for (int i = 0; i < 8; ++i)
    gll16(g + i * 512 + lane * 8, l + (i >> 1) * SLAB + (i & 1) * 512);
}
// stage one BK=32 k-step of 64 rows from a 128-row panel (row offset folded
// into g by caller): 4 slabs x 64 rows, SLABB stride
__device__ __forceinline__ void stageB64(const u16* g, u16* l, int lane) {
#pragma unroll
  for (int i = 0; i < 4; ++i)
    gll16(g + i * 1024 + lane * 8, l + i * SLABB);
}

// 64-row A from LDS (SLABB slabs), B regs[4]; 64x64 per wave (proj R13)
__device__ __forceinline__ void mfma_step_regB64(
    const u16* Ah, const u16* Al, const short8 bh[4], const short8 bl[4],
    int fm, int fq, f32x4 acc[4][4])
{
  const int ka = fq * SLABB;
  short8 ah[4], al[4];
#pragma unroll
  for (int i = 0; i < 4; ++i) {
    ah[i] = *(const short8*)&Ah[ka + (i * 16 + fm) * 8];
    al[i] = *(const short8*)&Al[ka + (i * 16 + fm) * 8];
  }
#pragma unroll
  for (int j = 0; j < 4; ++j)
#pragma unroll
    for (int i = 0; i < 4; ++i) {
      acc[i][j] = __builtin_amdgcn_mfma_f32_16x16x32_bf16(al[i], bh[j], acc[i][j], 0, 0, 0);
      acc[i][j] = __builtin_amdgcn_mfma_f32_16x16x32_bf16(ah[i], bl[j], acc[i][j], 0, 0, 0);
      acc[i][j] = __builtin_amdgcn_mfma_f32_16x16x32_bf16(ah[i], bh[j], acc[i][j], 0, 0, 0);
    }
}

// 64-row-A tile (SLABB stride), wave does 32x32: A rows wm0+{0,16}, B regs[2]
__device__ __forceinline__ void mfma_64_ab(
    const u16* Ah, const u16* Al, const short8 bh[2], const short8 bl[2],
    int wm0, int fm, int fq, f32x4 acc[2][2])
{
  const int ka = fq * SLABB;
  short8 ah[2], al[2];
#pragma unroll
  for (int i = 0; i < 2; ++i) {
    ah[i] = *(const short8*)&Ah[ka + (wm0 + i * 16 + fm) * 8];
    al[i] = *(const short8*)&Al[ka + (wm0 + i * 16 + fm) * 8];
  }
#pragma unroll
  for (int j = 0; j < 2; ++j)
#pragma unroll
    for (int i = 0; i < 2; ++i) {
      acc[i][j] = __builtin_amdgcn_mfma_f32_16x16x32_bf16(al[i], bh[j], acc[i][j], 0, 0, 0);
      acc[i][j] = __builtin_amdgcn_mfma_f32_16x16x32_bf16(ah[i], bl[j], acc[i][j], 0, 0, 0);
      acc[i][j] = __builtin_amdgcn_mfma_f32_16x16x32_bf16(ah[i], bh[j], acc[i][j], 0, 0, 0);
    }
}

// 128x64 tile, A from LDS (SLAB), B from regs (out-inter)
__device__ __forceinline__ void mfma_step_regB_ab(
    const u16* Ah, const u16* Al, const short8 bh[2], const short8 bl[2],
    int wm0, int fm, int fq, f32x4 acc[4][2])
{
  const int ka = fq * SLAB;
  short8 ah[4], al[4];
#pragma unroll
  for (int i = 0; i < 4; ++i) {
    ah[i] = *(const short8*)&Ah[ka + (wm0 + i * 16 + fm) * 8];
    al[i] = *(const short8*)&Al[ka + (wm0 + i * 16 + fm) * 8];
  }
#pragma unroll
  for (int j = 0; j < 2; ++j)
#pragma unroll
    for (int i = 0; i < 4; ++i) {
      acc[i][j] = __builtin_amdgcn_mfma_f32_16x16x32_bf16(al[i], bh[j], acc[i][j], 0, 0, 0);
      acc[i][j] = __builtin_amdgcn_mfma_f32_16x16x32_bf16(ah[i], bl[j], acc[i][j], 0, 0, 0);
      acc[i][j] = __builtin_amdgcn_mfma_f32_16x16x32_bf16(ah[i], bh[j], acc[i][j], 0, 0, 0);
    }
}

// load a wave's 64-row-panel B-fragments (2 col-groups, hi+lo) from global.
__device__ __forceinline__ void loadB2(short8 bh[2], short8 bl[2],
    const u16* BhP, const u16* BlP, int ks, int wn0, int fm, int fq)
{
  const int base = ks * 4096 + fq * 1024;
#pragma unroll
  for (int j = 0; j < 2; ++j) {
    int o = base + (wn0 + j * 16 + fm) * 8;
    bh[j] = *(const short8*)&BhP[o];
    bl[j] = *(const short8*)&BlP[o];
  }
}

// 128x64 tile (4 waves, 64x32 each), A from LDS, B from LDS (out-intra)
__device__ __forceinline__ void mfma_step_ab(
    const u16* Ah, const u16* Al, const u16* Bh, const u16* Bl,
    int wm0, int wn0, int fm, int fq, f32x4 acc[4][2])
{
  const int ka = fq * SLAB, kb = fq * SLABB;
  short8 ah[4], al[4];
#pragma unroll
  for (int i = 0; i < 4; ++i) {
    ah[i] = *(const short8*)&Ah[ka + (wm0 + i * 16 + fm) * 8];
    al[i] = *(const short8*)&Al[ka + (wm0 + i * 16 + fm) * 8];
  }
#pragma unroll
  for (int j = 0; j < 2; ++j) {
    short8 bh = *(const short8*)&Bh[kb + (wn0 + j * 16 + fm) * 8];
    short8 bl = *(const short8*)&Bl[kb + (wn0 + j * 16 + fm) * 8];
#pragma unroll
    for (int i = 0; i < 4; ++i) {
      acc[i][j] = __builtin_amdgcn_mfma_f32_16x16x32_bf16(al[i], bh, acc[i][j], 0, 0, 0);
      acc[i][j] = __builtin_amdgcn_mfma_f32_16x16x32_bf16(ah[i], bl, acc[i][j], 0, 0, 0);
      acc[i][j] = __builtin_amdgcn_mfma_f32_16x16x32_bf16(ah[i], bh, acc[i][j], 0, 0, 0);
    }
  }
}

// ---------------------------------------------------------------------------
// 0) pack W^T slabs (hi/lo) + zero rsP/lVec accumulators. grid (3, 16).
__global__ __launch_bounds__(256) void init_pack_kernel(
    const float* __restrict__ Wq, const float* __restrict__ Wk, const float* __restrict__ Wv,
    u16* __restrict__ Wth, u16* __restrict__ Wtl,
    float* __restrict__ rsP, float* __restrict__ lVec)
{
  const int which = blockIdx.x;
  const int it = blockIdx.y;
  const int t = threadIdx.x;
  if (which == 0) {
    *(float4*)&rsP[(size_t)(it * 256 + t) * 4] = (float4){0.f, 0.f, 0.f, 0.f};
  } else if (which == 1) {
    *(float4*)&lVec[(size_t)(it * 256 + t) * 4] = (float4){0.f, 0.f, 0.f, 0.f};
  }
  const float* W = which == 0 ? Wq : (which == 1 ? Wk : Wv);
  for (int pn = 0; pn < 2; ++pn) {
    int pos = it * 256 + t;
    int k8 = pos >> 7, r = pos & 127;
    u16 hs[8], ls[8];
#pragma unroll
    for (int u = 0; u < 8; ++u) {
      float x = W[(size_t)(k8 * 8 + u) * DD + pn * 128 + r];
      u16 h = f2bf(x); hs[u] = h; ls[u] = f2bf(x - bf2f(h));
    }
    size_t o = ((size_t)((which * 2 + pn) * 32 + k8)) * 1024 + (size_t)r * 8;
    *(short8*)&Wth[o] = *(short8*)hs;
    *(short8*)&Wtl[o] = *(short8*)ls;
  }
}

// ---------------------------------------------------------------------------
// 1) projections (R13): BM=64 x BN=256, pn merged. A: fp32 X (64x32/step)
//    reg-prefetched, split once into SLABB dbuf. B: W^T frags in regs per
//    wave (4 col-groups over its 64-col strip). 4 quarter-width epilogues.
__global__ __launch_bounds__(256, 3) void proj_kernel(
    const float* __restrict__ xq, const float* __restrict__ xk, const float* __restrict__ xv,
    const u16* __restrict__ Wth, const u16* __restrict__ Wtl,
    const float* __restrict__ bq, const float* __restrict__ bk_, const float* __restrict__ bv,
    u16* __restrict__ Qh, u16* __restrict__ Ql,
    u16* __restrict__ Kh, u16* __restrict__ Kl,
    u16* __restrict__ KTh, u16* __restrict__ KTl,
    u16* __restrict__ VTh, u16* __restrict__ VTl,
    float* __restrict__ lVec)
{
  const int which = blockIdx.z;
  const float* bias = which == 0 ? bq : (which == 1 ? bk_ : bv);
  const int m0 = blockIdx.x * 64;
  __shared__ u16 SM[16 * SLABB];          // A dbuf (2 x (4hi+4lo) SLABB slabs)
  __shared__ float rsc[64];
  __shared__ float wlut[64];
  __shared__ float kacc[64];
  float* fb = (float*)SM;                 // 64x65 fp32 bounce (epilogue only)
  const int tid = threadIdx.x, lane = tid & 63, wave = tid >> 6;
  const int wn0g = wave * 64;             // wave's global col strip
  const int fm = lane & 15, fq = lane >> 4;
  if (which == 1 && tid < 64) {
    int sb = (m0 & (SS - 1)) + tid;
    rsc[tid] = rsqrtf((1.0f - exp2f((float)(sb + 1) * LOG2G)) * INV1MG);
    wlut[tid] = exp2f((float)(255 - ((m0 & (LL - 1)) + tid)) * LOG2G);
    kacc[tid] = 0.f;
  }
  const float* XP = (which == 0 ? xq : (which == 1 ? xk : xv)) + (size_t)m0 * DD;
  const int pnw = wn0g >> 7, wl = wn0g & 127;
  const u16* WhP = Wth + (size_t)((which * 2 + pnw) * 32) * 1024;
  const u16* WlP = Wtl + (size_t)((which * 2 + pnw) * 32) * 1024;
  const int arow = tid >> 2, ak8 = tid & 3;  // 64 rows x 4 k8, 1 unit/thread
  f32x4 acc[4][4];
#pragma unroll
  for (int i = 0; i < 4; ++i)
#pragma unroll
    for (int j = 0; j < 4; ++j) acc[i][j] = (f32x4){0.f, 0.f, 0.f, 0.f};
  float xs[8];
  short8 bh[4], bl[4];
  // prologue: W(0) into regs, X(0) into buffer 0
  {
    const int base = fq * 1024;
#pragma unroll
    for (int j = 0; j < 4; ++j) {
      int o = base + (wl + j * 16 + fm) * 8;
      bh[j] = *(const short8*)&WhP[o];
      bl[j] = *(const short8*)&WlP[o];
    }
  }
  {
    const float* src = XP + (size_t)arow * DD + ak8 * 8;
    *(float4*)&xs[0] = *(const float4*)src;
    *(float4*)&xs[4] = *(const float4*)(src + 4);
    u16 hs[8], ls[8];
#pragma unroll
    for (int u = 0; u < 8; ++u) {
      u16 h = f2bf(xs[u]); hs[u] = h; ls[u] = f2bf(xs[u] - bf2f(h));
    }
    *(short8*)&SM[ak8 * SLABB + arow * 8] = *(short8*)hs;
    *(short8*)&SM[4 * SLABB + ak8 * SLABB + arow * 8] = *(short8*)ls;
  }
  int cur = 0;
  for (int ks = 0; ks < 8; ++ks) {
    __syncthreads();                       // buf[cur] ready
    u16* Ac = SM + cur * 8 * SLABB;
    u16* An = SM + (cur ^ 1) * 8 * SLABB;
    if (ks < 7) {
      const float* src = XP + (size_t)arow * DD + (ks + 1) * 32 + ak8 * 8;
      *(float4*)&xs[0] = *(const float4*)src;
      *(float4*)&xs[4] = *(const float4*)(src + 4);
    }
    mfma_step_regB64(Ac, Ac + 4 * SLABB, bh, bl, fm, fq, acc);
    if (ks < 7) {
      const int base = (ks + 1) * 4096 + fq * 1024;
#pragma unroll
      for (int j = 0; j < 4; ++j) {        // prefetch next W frags
        int o = base + (wl + j * 16 + fm) * 8;
        bh[j] = *(const short8*)&WhP[o];
        bl[j] = *(const short8*)&WlP[o];
      }
      u16 hs[8], ls[8];
#pragma unroll
      for (int u = 0; u < 8; ++u) {
        u16 h = f2bf(xs[u]); hs[u] = h; ls[u] = f2bf(xs[u] - bf2f(h));
      }
      *(short8*)&An[ak8 * SLABB + arow * 8] = *(short8*)hs;
      *(short8*)&An[4 * SLABB + ak8 * SLABB + arow * 8] = *(short8*)ls;
    }
    cur ^= 1;
  }
  const int b = m0 >> 12, sbb = m0 & (SS - 1);
  for (int p = 0; p < 4; ++p) {            // quarter-width column passes
    __syncthreads();
    if (wn0g == p * 64) {                  // owning wave bounces acc -> fb
#pragma unroll
      for (int i = 0; i < 4; ++i)
#pragma unroll
        for (int j = 0; j < 4; ++j)
#pragma unroll
          for (int r = 0; r < 4; ++r)
            fb[(i * 16 + fq * 4 + r) * 65 + j * 16 + fm] = acc[i][j][r];
    }
    __syncthreads();
    if (which == 0) {
#pragma unroll
      for (int it = 0; it < 2; ++it) {
        int unit = it * 256 + tid;         // 8 k8 x 64 rows
        int k8l = unit >> 6, row = unit & 63;
        int gc0 = p * 64 + k8l * 8;
        u16 hs[8], ls[8];
#pragma unroll
        for (int u = 0; u < 8; ++u) {
          float v = (fb[row * 65 + k8l * 8 + u] + bias[gc0 + u]) * (1.f / 16.f);
          u16 h = f2bf(v); hs[u] = h; ls[u] = f2bf(v - bf2f(h));
        }
        size_t o = (size_t)(m0 >> 7) * 32768 + (size_t)(p * 8 + k8l) * 1024 +
                   (size_t)((m0 & 64) + row) * 8;
        *(short8*)&Qh[o] = *(short8*)hs;
        *(short8*)&Ql[o] = *(short8*)ls;
      }
    } else if (which == 1) {
#pragma unroll
      for (int it = 0; it < 2; ++it) {     // K (row-major panel)
        int unit = it * 256 + tid;
        int k8l = unit >> 6, row = unit & 63;
        int gc0 = p * 64 + k8l * 8;
        u16 hs[8], ls[8];
#pragma unroll
        for (int u = 0; u < 8; ++u) {
          float v = (fb[row * 65 + k8l * 8 + u] + bias[gc0 + u]) * rsc[row];
          u16 h = f2bf(v); hs[u] = h; ls[u] = f2bf(v - bf2f(h));
        }
        size_t o = (size_t)(m0 >> 7) * 32768 + (size_t)(p * 8 + k8l) * 1024 +
                   (size_t)((m0 & 64) + row) * 8;
        *(short8*)&Kh[o] = *(short8*)hs;
        *(short8*)&Kl[o] = *(short8*)ls;
      }
      float kpart = 0.f;
#pragma unroll
      for (int it = 0; it < 2; ++it) {     // KT (col-major packed) + lVec
        int unit = it * 256 + tid;
        int dl = unit & 63, s8l = unit >> 6;
        int gcolg = p * 64 + dl;
        float bs = bias[gcolg];
        u16 hs[8], ls[8];
#pragma unroll
        for (int u = 0; u < 8; ++u) {
          int row = s8l * 8 + u;
          float v = (fb[row * 65 + dl] + bs) * rsc[row];
          kpart = fmaf(v, wlut[row], kpart);
          u16 h = f2bf(v); hs[u] = h; ls[u] = f2bf(v - bf2f(h));
        }
        int sb0 = sbb + s8l * 8;
        size_t o = ((size_t)(b * 2 + (gcolg >> 7)) * 512 + (sb0 >> 3)) * 1024 + (size_t)(gcolg & 127) * 8;
        *(short8*)&KTh[o] = *(short8*)hs;
        *(short8*)&KTl[o] = *(short8*)ls;
      }
      atomicAdd(&kacc[tid & 63], kpart);
      __syncthreads();
      if (tid < 64) {
        int c = sbb >> 8;
        atomicAdd(&lVec[(size_t)(b * NCH + c) * DD + p * 64 + tid], kacc[tid]);
        kacc[tid] = 0.f;
      }
    } else {  // V: split-bf16, KT-packed layout
#pragma unroll
      for (int it = 0; it < 2; ++it) {
        int unit = it * 256 + tid;
        int dl = unit & 63, s8l = unit >> 6;
        int gcolg = p * 64 + dl;
        float bs = bias[gcolg];
        u16 hs[8], ls[8];
#pragma unroll
        for (int u = 0; u < 8; ++u) {
          float v = fb[(s8l * 8 + u) * 65 + dl] + bs;
          u16 h = f2bf(v); hs[u] = h; ls[u] = f2bf(v - bf2f(h));
        }
        int sb0 = sbb + s8l * 8;
        size_t o = ((size_t)(b * 2 + (gcolg >> 7)) * 512 + (sb0 >> 3)) * 1024 + (size_t)(gcolg & 127) * 8;
        *(short8*)&VTh[o] = *(short8*)hs;
        *(short8*)&VTl[o] = *(short8*)ls;
      }
    }
  }
}

// ---------------------------------------------------------------------------
// 3) Sg = mask*(Q~.K~)*g^(il-jl); fused rowsum + Q.cVec dot -> rsP atomics.
//    R14: 64x64 tiles, causal triangle grid (64 x 10). A = Q 64-row half
//    panel via stageB64 dbuf; B = K frags global->regs. Wave tile 32x32.
__global__ __launch_bounds__(256, 4) void scores_kernel(
    const u16* __restrict__ Qh, const u16* __restrict__ Ql,
    const u16* __restrict__ Kh, const u16* __restrict__ Kl,
    const float* __restrict__ lVec, u16* __restrict__ Sgh, u16* __restrict__ Sgl,
    float* __restrict__ rsP)
{
  const int chunk = blockIdx.x, b = chunk >> 4, c = chunk & 15;
  const int y = blockIdx.y;
  const int mi = (y >= 6) ? 3 : (y >= 3) ? 2 : (y >= 1) ? 1 : 0;
  const int ji = y - mi * (mi + 1) / 2;
  const int m0 = mi * 64, jn0 = ji * 64;
  __shared__ u16 SA[2 * 8 * SLABB];
  __shared__ float cv[256], lut[256], rowAcc[64], qd4[4][64];
  float* fb = (float*)SA;  // 64x65 fp32 = 16640B = |SA| (epilogue only)
  const int tid = threadIdx.x, lane = tid & 63, wave = tid >> 6;
  const int wm0 = (wave >> 1) * 32, wn0 = (wave & 1) * 32;
  const int fm = lane & 15, fq = lane >> 4;
  if (jn0 == 0) {  // inline prefix scan: cv = sum_{cp<c} gL^(c-1-cp) lVec[cp]
    const float gL = exp2f((float)LL * LOG2G);
    float s = 0.f;
    for (int cp = 0; cp < c; ++cp)
      s = fmaf(gL, s, lVec[(size_t)(b * NCH + cp) * DD + tid]);
    cv[tid] = s;
  }
  lut[tid] = exp2f((float)tid * LOG2G);
  if (tid < 64) rowAcc[tid] = 0.f;
  const int growA = b * SS + c * LL + m0;
  const int growB = b * SS + c * LL + jn0;
  const u16* QhP = Qh + (size_t)(growA >> 7) * 32768 + (size_t)(growA & 127) * 8;
  const u16* QlP = Ql + (size_t)(growA >> 7) * 32768 + (size_t)(growA & 127) * 8;
  const u16* KhP = Kh + (size_t)(growB >> 7) * 32768 + (size_t)(growB & 127) * 8;
  const u16* KlP = Kl + (size_t)(growB >> 7) * 32768 + (size_t)(growB & 127) * 8;
  f32x4 acc[2][2];
#pragma unroll
  for (int i = 0; i < 2; ++i)
#pragma unroll
    for (int j = 0; j < 2; ++j) acc[i][j] = (f32x4){0.f, 0.f, 0.f, 0.f};
  float qdreg = 0.f;
  const int qrow = tid & 63, qk8b = tid >> 6;  // 64 rows x 4 k8
  short8 bh[2], bl[2];
  if (wave == 0) stageB64(QhP, SA, lane);
  if (wave == 1) stageB64(QlP, SA + 4 * SLABB, lane);
  loadB2(bh, bl, KhP, KlP, 0, wn0, fm, fq);
  int cur = 0;
  for (int ks = 0; ks < 8; ++ks) {
    __syncthreads();
    u16* Ac = cur ? SA + 8 * SLABB : SA;
    u16* An = cur ? SA : SA + 8 * SLABB;
    if (ks < 7) {
      if (wave == 0) stageB64(QhP + (ks + 1) * 4096, An, lane);
      if (wave == 1) stageB64(QlP + (ks + 1) * 4096, An + 4 * SLABB, lane);
    }
    mfma_64_ab(Ac, Ac + 4 * SLABB, bh, bl, wm0, fm, fq, acc);
    if (ks < 7) loadB2(bh, bl, KhP, KlP, ks + 1, wn0, fm, fq);
    if (jn0 == 0) {
      short8 hv = *(const short8*)&Ac[qk8b * SLABB + qrow * 8];
      short8 lv = *(const short8*)&Ac[4 * SLABB + qk8b * SLABB + qrow * 8];
#pragma unroll
      for (int u = 0; u < 8; ++u)
        qdreg = fmaf(bf2f((u16)hv[u]) + bf2f((u16)lv[u]),
                     cv[ks * 32 + qk8b * 8 + u], qdreg);
    }
    cur ^= 1;
  }
  qd4[qk8b][qrow] = qdreg;
  const int ps = chunk * 2 + (m0 >> 7);
  __syncthreads();                          // SA reads done; fb overlay safe
#pragma unroll
  for (int i = 0; i < 2; ++i)
#pragma unroll
    for (int j = 0; j < 2; ++j)
#pragma unroll
      for (int r = 0; r < 4; ++r)
        fb[(wm0 + i * 16 + fq * 4 + r) * 65 + wn0 + j * 16 + fm] = acc[i][j][r];
  __syncthreads();
#pragma unroll
  for (int it = 0; it < 2; ++it) {
    int unit = it * 256 + tid;              // 8 k8-cols x 64 rows
    int k8l = unit >> 6, rowl = unit & 63;
    int il = m0 + rowl;
    int jlb = jn0 + k8l * 8;
    float part = 0.f;
    u16 hs[8], ls[8];
#pragma unroll
    for (int u = 0; u < 8; ++u) {
      int jl = jlb + u;
      float v = (jl <= il) ? fb[rowl * 65 + k8l * 8 + u] * lut[il - jl] : 0.f;
      part += v;
      u16 h = f2bf(v); hs[u] = h; ls[u] = f2bf(v - bf2f(h));
    }
    atomicAdd(&rowAcc[rowl], part);
    size_t o = (size_t)(ps * 32 + (jn0 >> 3) + k8l) * 1024 +
               (size_t)((m0 & 64) + rowl) * 8;
    *(short8*)&Sgh[o] = *(short8*)hs;
    *(short8*)&Sgl[o] = *(short8*)ls;
  }
  __syncthreads();
  if (tid < 64) {
    float rs = rowAcc[tid];
    if (jn0 == 0)
      rs += exp2f((float)(m0 + tid + 1) * LOG2G) *
            (qd4[0][tid] + qd4[1][tid] + qd4[2][tid] + qd4[3][tid]);
    atomicAdd(&rsP[(size_t)b * SS + c * LL + m0 + tid], rs);
  }
}

// ---------------------------------------------------------------------------
// 5) lMatT[e][d] = sum_jl Vw[jl,e] K~[jl,d] ; R14: 64x64 tiles (grid 64x16).
//    A = V split-bf16 reg-staged (hi+lo reconstruct, wtl/denom fused) ->
//    SLABB dbuf; B = KT global->regs. Wave tile 32x32.
__global__ __launch_bounds__(256, 4) void lmat_kernel(
    const u16* __restrict__ VTh, const u16* __restrict__ VTl,
    const float* __restrict__ rsP,
    const u16* __restrict__ KTh, const u16* __restrict__ KTl,
    float* __restrict__ lMatT)
{
  const int chunk = blockIdx.x, b = chunk >> 4, c = chunk & 15;
  const int ty = blockIdx.y;
  const int m0 = (ty >> 2) * 64, n0 = (ty & 3) * 64;
  __shared__ u16 SA[2 * 8 * SLABB];
  __shared__ float swl[256];
  const int tid = threadIdx.x, lane = tid & 63, wave = tid >> 6;
  const int wm0 = (wave >> 1) * 32, wn0 = (wave & 1) * 32;
  const int fm = lane & 15, fq = lane >> 4;
  // per-jl scale = gamma^(255-jl) / max(|rsP|,1)
  swl[tid] = exp2f((float)(255 - tid) * LOG2G) /
             fmaxf(fabsf(rsP[(size_t)b * SS + c * LL + tid]), 1.0f);
  const u16* AThP = VTh + ((size_t)(b * 2 + (m0 >> 7)) * 512 + c * 32) * 1024 +
                    (size_t)(m0 & 127) * 8;
  const u16* ATlP = VTl + ((size_t)(b * 2 + (m0 >> 7)) * 512 + c * 32) * 1024 +
                    (size_t)(m0 & 127) * 8;
  const u16* BhP = KTh + ((size_t)(b * 2 + (n0 >> 7)) * 512 + c * 32) * 1024 + (size_t)(n0 & 127) * 8;
  const u16* BlP = KTl + ((size_t)(b * 2 + (n0 >> 7)) * 512 + c * 32) * 1024 + (size_t)(n0 & 127) * 8;
  const int arow = tid >> 2, ak8 = tid & 3;  // 64 rows x 4 k8, 1 unit/thread
  f32x4 acc[2][2];
#pragma unroll
  for (int i = 0; i < 2; ++i)
#pragma unroll
    for (int j = 0; j < 2; ++j) acc[i][j] = (f32x4){0.f, 0.f, 0.f, 0.f};
  short8 vh, vl;
  short8 bh[2], bl[2];
  loadB2(bh, bl, BhP, BlP, 0, wn0, fm, fq);
  {
    int off = ak8 * 1024 + arow * 8;
    vh = *(const short8*)&AThP[off];
    vl = *(const short8*)&ATlP[off];
  }
  __syncthreads();                         // swl ready
  {
    u16 hs[8], ls[8];
#pragma unroll
    for (int u = 0; u < 8; ++u) {
      float v = (bf2f((u16)vh[u]) + bf2f((u16)vl[u])) * swl[ak8 * 8 + u];
      u16 h = f2bf(v); hs[u] = h; ls[u] = f2bf(v - bf2f(h));
    }
    *(short8*)&SA[ak8 * SLABB + arow * 8] = *(short8*)hs;
    *(short8*)&SA[4 * SLABB + ak8 * SLABB + arow * 8] = *(short8*)ls;
  }
  int cur = 0;
  for (int ks = 0; ks < 8; ++ks) {
    __syncthreads();
    u16* Ac = cur ? SA + 8 * SLABB : SA;
    u16* An = cur ? SA : SA + 8 * SLABB;
    if (ks < 7) {
      int off = ((ks + 1) * 4 + ak8) * 1024 + arow * 8;
      vh = *(const short8*)&AThP[off];
      vl = *(const short8*)&ATlP[off];
    }
    mfma_64_ab(Ac, Ac + 4 * SLABB, bh, bl, wm0, fm, fq, acc);
    if (ks < 7) {
      loadB2(bh, bl, BhP, BlP, ks + 1, wn0, fm, fq);
      u16 hs[8], ls[8];
#pragma unroll
      for (int u = 0; u < 8; ++u) {
        float v = (bf2f((u16)vh[u]) + bf2f((u16)vl[u])) *
                  swl[(ks + 1) * 32 + ak8 * 8 + u];
        u16 h = f2bf(v); hs[u] = h; ls[u] = f2bf(v - bf2f(h));
      }
      *(short8*)&An[ak8 * SLABB + arow * 8] = *(short8*)hs;
      *(short8*)&An[4 * SLABB + ak8 * SLABB + arow * 8] = *(short8*)ls;
    }
    cur ^= 1;
  }
#pragma unroll
  for (int i = 0; i < 2; ++i)
#pragma unroll
    for (int j = 0; j < 2; ++j)
#pragma unroll
      for (int r = 0; r < 4; ++r) {
        int e = m0 + wm0 + i * 16 + fq * 4 + r;
        int d = n0 + wn0 + j * 16 + fm;
        lMatT[(size_t)chunk * 65536 + (size_t)e * 256 + d] = acc[i][j][r];
      }
}

// 6) carry scan -> cM packed split
__global__ __launch_bounds__(256) void combine_mat_kernel(
    const float* __restrict__ lMatT, u16* __restrict__ cMh, u16* __restrict__ cMl)
{
  const int t = blockIdx.x * 256 + threadIdx.x;
  const int b = t >> 13, rem = t & 8191;
  const int k8 = rem >> 8, e = rem & 255;
  const float gL = powf(GAMMA, (float)LL);
  float s[8] = {0.f, 0.f, 0.f, 0.f, 0.f, 0.f, 0.f, 0.f};
  for (int ch = 0; ch < 16; ++ch) {
    size_t ro = (size_t)(b * 16 + ch) * 65536 + (size_t)e * 256 + k8 * 8;
    float4 a0 = *(const float4*)&lMatT[ro];
    float4 a1 = *(const float4*)&lMatT[ro + 4];
    float vals[8] = {a0.x, a0.y, a0.z, a0.w, a1.x, a1.y, a1.z, a1.w};
    u16 hh[8], ll[8];
#pragma unroll
    for (int u = 0; u < 8; ++u) {
      u16 h = f2bf(s[u]); hh[u] = h; ll[u] = f2bf(s[u] - bf2f(h));
    }
    size_t wo = ((size_t)(((b * 16 + ch) * 2 + (e >> 7)) * 32 + k8)) * 1024 + (size_t)(e & 127) * 8;
    *(short8*)&cMh[wo] = *(short8*)hh;
    *(short8*)&cMl[wo] = *(short8*)ll;
#pragma unroll
    for (int u = 0; u < 8; ++u) s[u] = gL * s[u] + vals[u];
  }
}

// ---------------------------------------------------------------------------
// 7) out = g^(il+1) * Q~ @ cM^T + Sg @ Vd ; 128x64 tiles (grid 64x8)
//    (R12) inter: A=Q gll16 dbuf, B=cM regs. intra: A=Sg gll16,
//    B = V split-bf16 reg-staged -> LDS dbuf (hi+lo reconstruct, 1/denom).
__global__ __launch_bounds__(256, 3) void out_kernel(
    const u16* __restrict__ Qh, const u16* __restrict__ Ql,
    const u16* __restrict__ cMh, const u16* __restrict__ cMl,
    const u16* __restrict__ Sgh, const u16* __restrict__ Sgl,
    const u16* __restrict__ VTh, const u16* __restrict__ VTl,
    const float* __restrict__ rsP,
    float* __restrict__ out)
{
  const int chunk = blockIdx.x, b = chunk >> 4, c = chunk & 15;
  const int ty = blockIdx.y;
  const int m0 = (ty >> 2) * 128, n0 = (ty & 3) * 64;
  __shared__ u16 SA[2 * 8 * SLAB];
  __shared__ u16 SB[2 * 8 * SLABB];
  __shared__ float olut[128];
  __shared__ float sdn[256];
  const int tid = threadIdx.x, lane = tid & 63, wave = tid >> 6;
  const int wm0 = (wave >> 1) * 64, wn0 = (wave & 1) * 32;
  const int fm = lane & 15, fq = lane >> 4;
  if (tid < 128) olut[tid] = exp2f((float)(m0 + tid + 1) * LOG2G);
  sdn[tid] = 1.0f / fmaxf(fabsf(rsP[(size_t)b * SS + c * LL + tid]), 1.0f);
  f32x4 acc[4][2];
#pragma unroll
  for (int i = 0; i < 4; ++i)
#pragma unroll
    for (int j = 0; j < 2; ++j) acc[i][j] = (f32x4){0.f, 0.f, 0.f, 0.f};
  int cur = 0;
  {  // inter: A = Q panel (gll16 dbuf), B = cM rows n0..n0+64 (regs)
    const u16* AhP = Qh + (size_t)(b * 32 + c * 2 + (m0 >> 7)) * 32768;
    const u16* AlP = Ql + (size_t)(b * 32 + c * 2 + (m0 >> 7)) * 32768;
    const u16* BhP = cMh + (size_t)(chunk * 2 + (n0 >> 7)) * 32768 + (size_t)(n0 & 127) * 8;
    const u16* BlP = cMl + (size_t)(chunk * 2 + (n0 >> 7)) * 32768 + (size_t)(n0 & 127) * 8;
    short8 bh[2], bl[2];
    if (wave == 0) stage8kp(AhP, SA, lane);
    if (wave == 1) stage8kp(AlP, SA + 4 * SLAB, lane);
    loadB2(bh, bl, BhP, BlP, 0, wn0, fm, fq);
    for (int ks = 0; ks < 8; ++ks) {
      __syncthreads();
      u16* Ac = cur ? SA + 8 * SLAB : SA;
      u16* An = cur ? SA : SA + 8 * SLAB;
      if (ks < 7) {
        if (wave == 0) stage8kp(AhP + (ks + 1) * 4096, An, lane);
        if (wave == 1) stage8kp(AlP + (ks + 1) * 4096, An + 4 * SLAB, lane);
      }
      mfma_step_regB_ab(Ac, Ac + 4 * SLAB, bh, bl, wm0, fm, fq, acc);
      if (ks < 7) loadB2(bh, bl, BhP, BlP, ks + 1, wn0, fm, fq);
      cur ^= 1;
    }
  }
  {  // intra: A = Sg (gll16), B = V split-bf16 reg-staged -> LDS dbuf
    const u16* AhP = Sgh + (size_t)(chunk * 2 + (m0 >> 7)) * 32768;
    const u16* AlP = Sgl + (size_t)(chunk * 2 + (m0 >> 7)) * 32768;
    const u16* BThP = VTh + ((size_t)(b * 2 + (n0 >> 7)) * 512 + c * 32) * 1024 + (size_t)(n0 & 127) * 8;
    const u16* BTlP = VTl + ((size_t)(b * 2 + (n0 >> 7)) * 512 + c * 32) * 1024 + (size_t)(n0 & 127) * 8;
    const int ber = tid >> 2, bk8 = tid & 3;  // 64 rows x 4 k8, 1 unit/thread
    const int nks = (m0 >> 5) + 4;
    short8 vh, vl;
    {  // prologue into buf[cur] (last read 2 steps ago -> safe)
      u16* Ac = cur ? SA + 8 * SLAB : SA;
      u16* Bc = cur ? SB + 8 * SLABB : SB;
      if (wave == 0) stage8kp(AhP, Ac, lane);
      if (wave == 1) stage8kp(AlP, Ac + 4 * SLAB, lane);
      int off = bk8 * 1024 + ber * 8;
      vh = *(const short8*)&BThP[off];
      vl = *(const short8*)&BTlP[off];
      // overlap acc scaling with the loads
#pragma unroll
      for (int i = 0; i < 4; ++i)
#pragma unroll
        for (int r = 0; r < 4; ++r) {
          int rl = wm0 + i * 16 + fq * 4 + r;
          float sc = olut[rl];
#pragma unroll
          for (int j = 0; j < 2; ++j) acc[i][j][r] *= sc;
        }
      u16 hs[8], ls[8];
#pragma unroll
      for (int u = 0; u < 8; ++u) {
        float v = (bf2f((u16)vh[u]) + bf2f((u16)vl[u])) * sdn[bk8 * 8 + u];
        u16 h = f2bf(v); hs[u] = h; ls[u] = f2bf(v - bf2f(h));
      }
      *(short8*)&Bc[bk8 * SLABB + ber * 8] = *(short8*)hs;
      *(short8*)&Bc[4 * SLABB + bk8 * SLABB + ber * 8] = *(short8*)ls;
    }
    for (int ks = 0; ks < nks; ++ks) {
      __syncthreads();
      u16* Ac = cur ? SA + 8 * SLAB : SA;
      u16* Bc = cur ? SB + 8 * SLABB : SB;
      u16* An = cur ? SA : SA + 8 * SLAB;
      u16* Bn = cur ? SB : SB + 8 * SLABB;
      if (ks + 1 < nks) {
        if (wave == 0) stage8kp(AhP + (ks + 1) * 4096, An, lane);
        if (wave == 1) stage8kp(AlP + (ks + 1) * 4096, An + 4 * SLAB, lane);
        int off = ((ks + 1) * 4 + bk8) * 1024 + ber * 8;
        vh = *(const short8*)&BThP[off];
        vl = *(const short8*)&BTlP[off];
      }
      mfma_step_ab(Ac, Ac + 4 * SLAB, Bc, Bc + 4 * SLABB, wm0, wn0, fm, fq, acc);
      if (ks + 1 < nks) {
        u16 hs[8], ls[8];
#pragma unroll
        for (int u = 0; u < 8; ++u) {
          float v = (bf2f((u16)vh[u]) + bf2f((u16)vl[u])) *
                    sdn[(ks + 1) * 32 + bk8 * 8 + u];
          u16 h = f2bf(v); hs[u] = h; ls[u] = f2bf(v - bf2f(h));
        }
        *(short8*)&Bn[bk8 * SLABB + ber * 8] = *(short8*)hs;
        *(short8*)&Bn[4 * SLABB + bk8 * SLABB + ber * 8] = *(short8*)ls;
      }
      cur ^= 1;
    }
  }
#pragma unroll
  for (int i = 0; i < 4; ++i)
#pragma unroll
    for (int j = 0; j < 2; ++j)
#pragma unroll
      for (int r = 0; r < 4; ++r) {
        int il = m0 + wm0 + i * 16 + fq * 4 + r;
        int e = n0 + wn0 + j * 16 + fm;
        out[(size_t)(b * SS + c * LL + il) * DD + e] = acc[i][j][r];
      }
}

// ---------------------------------------------------------------------------
extern "C" void kernel_launch(void* const* d_in, const int* in_sizes, int n_in,
                              void* d_out, int out_size, void* d_ws, size_t ws_size,
                              hipStream_t stream) {
  const float* xq = (const float*)d_in[0];
  const float* xk = (const float*)d_in[1];
  const float* xv = (const float*)d_in[2];
  const float* Wq = (const float*)d_in[3];
  const float* bq = (const float*)d_in[4];
  const float* Wk = (const float*)d_in[5];
  const float* bk = (const float*)d_in[6];
  const float* Wv = (const float*)d_in[7];
  const float* bv = (const float*)d_in[8];
  float* out = (float*)d_out;

  char* p = (char*)d_ws;
  const size_t H16 = (size_t)BB * SS * DD * 2;  // 8 MB
  u16* Qh   = (u16*)(p + 0 * H16);  u16* Ql   = (u16*)(p + 1 * H16);
  u16* Kh   = (u16*)(p + 2 * H16);  u16* Kl   = (u16*)(p + 3 * H16);
  u16* KTh  = (u16*)(p + 4 * H16);  u16* KTl  = (u16*)(p + 5 * H16);
  u16* VTh  = (u16*)(p + 6 * H16);  u16* VTl  = (u16*)(p + 7 * H16);
  u16* Sgh  = (u16*)(p + 10 * H16); u16* Sgl  = (u16*)(p + 11 * H16);
  u16* cMh  = (u16*)(p + 12 * H16); u16* cMl  = (u16*)(p + 13 * H16);
  float* lMatT = (float*)(p + 14 * H16);
  u16* Wth = (u16*)(p + 18 * H16);
  u16* Wtl = (u16*)(p + 18 * H16 + 3 * DD * DD * 2);
  float* rsP  = (float*)(p + 18 * H16 + 6 * DD * DD * 2);
  float* lVec = rsP + (size_t)BB * SS;

  init_pack_kernel<<<dim3(3, 16), 256, 0, stream>>>(Wq, Wk, Wv, Wth, Wtl, rsP, lVec);
  proj_kernel<<<dim3(BB * SS / 64, 1, 3), 256, 0, stream>>>(
      xq, xk, xv, Wth, Wtl, bq, bk, bv, Qh, Ql, Kh, Kl, KTh, KTl, VTh, VTl, lVec);
  scores_kernel<<<dim3(BB * NCH, 10), 256, 0, stream>>>(
      Qh, Ql, Kh, Kl, lVec, Sgh, Sgl, rsP);
  lmat_kernel<<<dim3(BB * NCH, 16), 256, 0, stream>>>(VTh, VTl, rsP, KTh, KTl, lMatT);
  combine_mat_kernel<<<128, 256, 0, stream>>>(lMatT, cMh, cMl);
  out_kernel<<<dim3(BB * NCH, 8), 256, 0, stream>>>(
      Qh, Ql, cMh, cMl, Sgh, Sgl, VTh, VTl, rsP, out);
}

// Round 15
// 194.911 us; speedup vs baseline: 1.1651x; 1.0107x over previous
//
#include <hip/hip_runtime.h>
#include <math.h>

// Retention (B=4, S=4096, D=256): chunkwise, split-bf16 MFMA, packed k8-slab
// operands.
// R1-R14: see history. R14 = 197us (64-row retile of scores/lmat helped).
// R15: same retile for out: 64-row tiles (grid 64x16, 4 blocks/CU, wave
//   32x32, SLABB dbufs, LDS 51->33KB) + tighter causality nks=m0/32+2
//   (-17% intra work). proj/scores/lmat/combine/init unchanged.
#define BB 4
#define SS 4096
#define DD 256
#define LL 256
#define NCH 16
#define GAMMA 0.9865f
#define LOG2G (-0.019609034f)   // log2(0.9865)
#define INV1MG 74.07407407f     // 1/(1-gamma)
#define SLAB 1032               // padded LDS slab stride (u16), 128-row panels
#define SLABB 520               // padded LDS slab stride (u16), 64-row panels

typedef __attribute__((ext_vector_type(8))) short short8;
typedef __attribute__((ext_vector_type(4))) float f32x4;
typedef unsigned short u16;
typedef unsigned int u32;

__device__ __forceinline__ u16 f2bf(float f) {
  union { float f; unsigned u; } v; v.f = f;
  unsigned r = v.u + 0x7FFFu + ((v.u >> 16) & 1u);
  return (u16)(r >> 16);
}
__device__ __forceinline__ float bf2f(u16 h) {
  union { unsigned u; float f; } v; v.u = ((unsigned)h) << 16; return v.f;
}

__device__ __forceinline__ void gll16(const u16* g, u16* l) {
  __builtin_amdgcn_global_load_lds(
      (const __attribute__((address_space(1))) u32*)g,
      (__attribute__((address_space(3))) u32*)l, 16, 0, 0);
}
// stage one BK=32 k-step of 64 rows from a 128-row panel (row offset folded
// into g by caller): 4 slabs x 64 rows, SLABB stride
__device__ __forceinline__ void stageB64(const u16* g, u16* l, int lane) {
#pragma unroll
  for (int i = 0; i < 4; ++i)
    gll16(g + i * 1024 + lane * 8, l + i * SLABB);
}

// 64-row A from LDS (SLABB slabs), B regs[4]; 64x64 per wave (proj R13)
__device__ __forceinline__ void mfma_step_regB64(
    const u16* Ah, const u16* Al, const short8 bh[4], const short8 bl[4],
    int fm, int fq, f32x4 acc[4][4])
{
  const int ka = fq * SLABB;
  short8 ah[4], al[4];
#pragma unroll
  for (int i = 0; i < 4; ++i) {
    ah[i] = *(const short8*)&Ah[ka + (i * 16 + fm) * 8];
    al[i] = *(const short8*)&Al[ka + (i * 16 + fm) * 8];
  }
#pragma unroll
  for (int j = 0; j < 4; ++j)
#pragma unroll
    for (int i = 0; i < 4; ++i) {
      acc[i][j] = __builtin_amdgcn_mfma_f32_16x16x32_bf16(al[i], bh[j], acc[i][j], 0, 0, 0);
      acc[i][j] = __builtin_amdgcn_mfma_f32_16x16x32_bf16(ah[i], bl[j], acc[i][j], 0, 0, 0);
      acc[i][j] = __builtin_amdgcn_mfma_f32_16x16x32_bf16(ah[i], bh[j], acc[i][j], 0, 0, 0);
    }
}

// 64-row-A tile (SLABB stride), wave does 32x32: A rows wm0+{0,16}, B regs[2]
__device__ __forceinline__ void mfma_64_ab(
    const u16* Ah, const u16* Al, const short8 bh[2], const short8 bl[2],
    int wm0, int fm, int fq, f32x4 acc[2][2])
{
  const int ka = fq * SLABB;
  short8 ah[2], al[2];
#pragma unroll
  for (int i = 0; i < 2; ++i) {
    ah[i] = *(const short8*)&Ah[ka + (wm0 + i * 16 + fm) * 8];
    al[i] = *(const short8*)&Al[ka + (wm0 + i * 16 + fm) * 8];
  }
#pragma unroll
  for (int j = 0; j < 2; ++j)
#pragma unroll
    for (int i = 0; i < 2; ++i) {
      acc[i][j] = __builtin_amdgcn_mfma_f32_16x16x32_bf16(al[i], bh[j], acc[i][j], 0, 0, 0);
      acc[i][j] = __builtin_amdgcn_mfma_f32_16x16x32_bf16(ah[i], bl[j], acc[i][j], 0, 0, 0);
      acc[i][j] = __builtin_amdgcn_mfma_f32_16x16x32_bf16(ah[i], bh[j], acc[i][j], 0, 0, 0);
    }
}

// 64-row tile, A and B both from SLABB-stride LDS, wave 32x32 (out-intra)
__device__ __forceinline__ void mfma_64_bb(
    const u16* Ah, const u16* Al, const u16* Bh, const u16* Bl,
    int wm0, int wn0, int fm, int fq, f32x4 acc[2][2])
{
  const int ka = fq * SLABB;
  short8 ah[2], al[2];
#pragma unroll
  for (int i = 0; i < 2; ++i) {
    ah[i] = *(const short8*)&Ah[ka + (wm0 + i * 16 + fm) * 8];
    al[i] = *(const short8*)&Al[ka + (wm0 + i * 16 + fm) * 8];
  }
#pragma unroll
  for (int j = 0; j < 2; ++j) {
    short8 bh = *(const short8*)&Bh[ka + (wn0 + j * 16 + fm) * 8];
    short8 bl = *(const short8*)&Bl[ka + (wn0 + j * 16 + fm) * 8];
#pragma unroll
    for (int i = 0; i < 2; ++i) {
      acc[i][j] = __builtin_amdgcn_mfma_f32_16x16x32_bf16(al[i], bh, acc[i][j], 0, 0, 0);
      acc[i][j] = __builtin_amdgcn_mfma_f32_16x16x32_bf16(ah[i], bl, acc[i][j], 0, 0, 0);
      acc[i][j] = __builtin_amdgcn_mfma_f32_16x16x32_bf16(ah[i], bh, acc[i][j], 0, 0, 0);
    }
  }
}

// load a wave's 64-row-panel B-fragments (2 col-groups, hi+lo) from global.
__device__ __forceinline__ void loadB2(short8 bh[2], short8 bl[2],
    const u16* BhP, const u16* BlP, int ks, int wn0, int fm, int fq)
{
  const int base = ks * 4096 + fq * 1024;
#pragma unroll
  for (int j = 0; j < 2; ++j) {
    int o = base + (wn0 + j * 16 + fm) * 8;
    bh[j] = *(const short8*)&BhP[o];
    bl[j] = *(const short8*)&BlP[o];
  }
}

// ---------------------------------------------------------------------------
// 0) pack W^T slabs (hi/lo) + zero rsP/lVec accumulators. grid (3, 16).
__global__ __launch_bounds__(256) void init_pack_kernel(
    const float* __restrict__ Wq, const float* __restrict__ Wk, const float* __restrict__ Wv,
    u16* __restrict__ Wth, u16* __restrict__ Wtl,
    float* __restrict__ rsP, float* __restrict__ lVec)
{
  const int which = blockIdx.x;
  const int it = blockIdx.y;
  const int t = threadIdx.x;
  if (which == 0) {
    *(float4*)&rsP[(size_t)(it * 256 + t) * 4] = (float4){0.f, 0.f, 0.f, 0.f};
  } else if (which == 1) {
    *(float4*)&lVec[(size_t)(it * 256 + t) * 4] = (float4){0.f, 0.f, 0.f, 0.f};
  }
  const float* W = which == 0 ? Wq : (which == 1 ? Wk : Wv);
  for (int pn = 0; pn < 2; ++pn) {
    int pos = it * 256 + t;
    int k8 = pos >> 7, r = pos & 127;
    u16 hs[8], ls[8];
#pragma unroll
    for (int u = 0; u < 8; ++u) {
      float x = W[(size_t)(k8 * 8 + u) * DD + pn * 128 + r];
      u16 h = f2bf(x); hs[u] = h; ls[u] = f2bf(x - bf2f(h));
    }
    size_t o = ((size_t)((which * 2 + pn) * 32 + k8)) * 1024 + (size_t)r * 8;
    *(short8*)&Wth[o] = *(short8*)hs;
    *(short8*)&Wtl[o] = *(short8*)ls;
  }
}

// ---------------------------------------------------------------------------
// 1) projections (R13): BM=64 x BN=256, pn merged. A: fp32 X (64x32/step)
//    reg-prefetched, split once into SLABB dbuf. B: W^T frags in regs per
//    wave (4 col-groups over its 64-col strip). 4 quarter-width epilogues.
__global__ __launch_bounds__(256, 3) void proj_kernel(
    const float* __restrict__ xq, const float* __restrict__ xk, const float* __restrict__ xv,
    const u16* __restrict__ Wth, const u16* __restrict__ Wtl,
    const float* __restrict__ bq, const float* __restrict__ bk_, const float* __restrict__ bv,
    u16* __restrict__ Qh, u16* __restrict__ Ql,
    u16* __restrict__ Kh, u16* __restrict__ Kl,
    u16* __restrict__ KTh, u16* __restrict__ KTl,
    u16* __restrict__ VTh, u16* __restrict__ VTl,
    float* __restrict__ lVec)
{
  const int which = blockIdx.z;
  const float* bias = which == 0 ? bq : (which == 1 ? bk_ : bv);
  const int m0 = blockIdx.x * 64;
  __shared__ u16 SM[16 * SLABB];          // A dbuf (2 x (4hi+4lo) SLABB slabs)
  __shared__ float rsc[64];
  __shared__ float wlut[64];
  __shared__ float kacc[64];
  float* fb = (float*)SM;                 // 64x65 fp32 bounce (epilogue only)
  const int tid = threadIdx.x, lane = tid & 63, wave = tid >> 6;
  const int wn0g = wave * 64;             // wave's global col strip
  const int fm = lane & 15, fq = lane >> 4;
  if (which == 1 && tid < 64) {
    int sb = (m0 & (SS - 1)) + tid;
    rsc[tid] = rsqrtf((1.0f - exp2f((float)(sb + 1) * LOG2G)) * INV1MG);
    wlut[tid] = exp2f((float)(255 - ((m0 & (LL - 1)) + tid)) * LOG2G);
    kacc[tid] = 0.f;
  }
  const float* XP = (which == 0 ? xq : (which == 1 ? xk : xv)) + (size_t)m0 * DD;
  const int pnw = wn0g >> 7, wl = wn0g & 127;
  const u16* WhP = Wth + (size_t)((which * 2 + pnw) * 32) * 1024;
  const u16* WlP = Wtl + (size_t)((which * 2 + pnw) * 32) * 1024;
  const int arow = tid >> 2, ak8 = tid & 3;  // 64 rows x 4 k8, 1 unit/thread
  f32x4 acc[4][4];
#pragma unroll
  for (int i = 0; i < 4; ++i)
#pragma unroll
    for (int j = 0; j < 4; ++j) acc[i][j] = (f32x4){0.f, 0.f, 0.f, 0.f};
  float xs[8];
  short8 bh[4], bl[4];
  // prologue: W(0) into regs, X(0) into buffer 0
  {
    const int base = fq * 1024;
#pragma unroll
    for (int j = 0; j < 4; ++j) {
      int o = base + (wl + j * 16 + fm) * 8;
      bh[j] = *(const short8*)&WhP[o];
      bl[j] = *(const short8*)&WlP[o];
    }
  }
  {
    const float* src = XP + (size_t)arow * DD + ak8 * 8;
    *(float4*)&xs[0] = *(const float4*)src;
    *(float4*)&xs[4] = *(const float4*)(src + 4);
    u16 hs[8], ls[8];
#pragma unroll
    for (int u = 0; u < 8; ++u) {
      u16 h = f2bf(xs[u]); hs[u] = h; ls[u] = f2bf(xs[u] - bf2f(h));
    }
    *(short8*)&SM[ak8 * SLABB + arow * 8] = *(short8*)hs;
    *(short8*)&SM[4 * SLABB + ak8 * SLABB + arow * 8] = *(short8*)ls;
  }
  int cur = 0;
  for (int ks = 0; ks < 8; ++ks) {
    __syncthreads();                       // buf[cur] ready
    u16* Ac = SM + cur * 8 * SLABB;
    u16* An = SM + (cur ^ 1) * 8 * SLABB;
    if (ks < 7) {
      const float* src = XP + (size_t)arow * DD + (ks + 1) * 32 + ak8 * 8;
      *(float4*)&xs[0] = *(const float4*)src;
      *(float4*)&xs[4] = *(const float4*)(src + 4);
    }
    mfma_step_regB64(Ac, Ac + 4 * SLABB, bh, bl, fm, fq, acc);
    if (ks < 7) {
      const int base = (ks + 1) * 4096 + fq * 1024;
#pragma unroll
      for (int j = 0; j < 4; ++j) {        // prefetch next W frags
        int o = base + (wl + j * 16 + fm) * 8;
        bh[j] = *(const short8*)&WhP[o];
        bl[j] = *(const short8*)&WlP[o];
      }
      u16 hs[8], ls[8];
#pragma unroll
      for (int u = 0; u < 8; ++u) {
        u16 h = f2bf(xs[u]); hs[u] = h; ls[u] = f2bf(xs[u] - bf2f(h));
      }
      *(short8*)&An[ak8 * SLABB + arow * 8] = *(short8*)hs;
      *(short8*)&An[4 * SLABB + ak8 * SLABB + arow * 8] = *(short8*)ls;
    }
    cur ^= 1;
  }
  const int b = m0 >> 12, sbb = m0 & (SS - 1);
  for (int p = 0; p < 4; ++p) {            // quarter-width column passes
    __syncthreads();
    if (wn0g == p * 64) {                  // owning wave bounces acc -> fb
#pragma unroll
      for (int i = 0; i < 4; ++i)
#pragma unroll
        for (int j = 0; j < 4; ++j)
#pragma unroll
          for (int r = 0; r < 4; ++r)
            fb[(i * 16 + fq * 4 + r) * 65 + j * 16 + fm] = acc[i][j][r];
    }
    __syncthreads();
    if (which == 0) {
#pragma unroll
      for (int it = 0; it < 2; ++it) {
        int unit = it * 256 + tid;         // 8 k8 x 64 rows
        int k8l = unit >> 6, row = unit & 63;
        int gc0 = p * 64 + k8l * 8;
        u16 hs[8], ls[8];
#pragma unroll
        for (int u = 0; u < 8; ++u) {
          float v = (fb[row * 65 + k8l * 8 + u] + bias[gc0 + u]) * (1.f / 16.f);
          u16 h = f2bf(v); hs[u] = h; ls[u] = f2bf(v - bf2f(h));
        }
        size_t o = (size_t)(m0 >> 7) * 32768 + (size_t)(p * 8 + k8l) * 1024 +
                   (size_t)((m0 & 64) + row) * 8;
        *(short8*)&Qh[o] = *(short8*)hs;
        *(short8*)&Ql[o] = *(short8*)ls;
      }
    } else if (which == 1) {
#pragma unroll
      for (int it = 0; it < 2; ++it) {     // K (row-major panel)
        int unit = it * 256 + tid;
        int k8l = unit >> 6, row = unit & 63;
        int gc0 = p * 64 + k8l * 8;
        u16 hs[8], ls[8];
#pragma unroll
        for (int u = 0; u < 8; ++u) {
          float v = (fb[row * 65 + k8l * 8 + u] + bias[gc0 + u]) * rsc[row];
          u16 h = f2bf(v); hs[u] = h; ls[u] = f2bf(v - bf2f(h));
        }
        size_t o = (size_t)(m0 >> 7) * 32768 + (size_t)(p * 8 + k8l) * 1024 +
                   (size_t)((m0 & 64) + row) * 8;
        *(short8*)&Kh[o] = *(short8*)hs;
        *(short8*)&Kl[o] = *(short8*)ls;
      }
      float kpart = 0.f;
#pragma unroll
      for (int it = 0; it < 2; ++it) {     // KT (col-major packed) + lVec
        int unit = it * 256 + tid;
        int dl = unit & 63, s8l = unit >> 6;
        int gcolg = p * 64 + dl;
        float bs = bias[gcolg];
        u16 hs[8], ls[8];
#pragma unroll
        for (int u = 0; u < 8; ++u) {
          int row = s8l * 8 + u;
          float v = (fb[row * 65 + dl] + bs) * rsc[row];
          kpart = fmaf(v, wlut[row], kpart);
          u16 h = f2bf(v); hs[u] = h; ls[u] = f2bf(v - bf2f(h));
        }
        int sb0 = sbb + s8l * 8;
        size_t o = ((size_t)(b * 2 + (gcolg >> 7)) * 512 + (sb0 >> 3)) * 1024 + (size_t)(gcolg & 127) * 8;
        *(short8*)&KTh[o] = *(short8*)hs;
        *(short8*)&KTl[o] = *(short8*)ls;
      }
      atomicAdd(&kacc[tid & 63], kpart);
      __syncthreads();
      if (tid < 64) {
        int c = sbb >> 8;
        atomicAdd(&lVec[(size_t)(b * NCH + c) * DD + p * 64 + tid], kacc[tid]);
        kacc[tid] = 0.f;
      }
    } else {  // V: split-bf16, KT-packed layout
#pragma unroll
      for (int it = 0; it < 2; ++it) {
        int unit = it * 256 + tid;
        int dl = unit & 63, s8l = unit >> 6;
        int gcolg = p * 64 + dl;
        float bs = bias[gcolg];
        u16 hs[8], ls[8];
#pragma unroll
        for (int u = 0; u < 8; ++u) {
          float v = fb[(s8l * 8 + u) * 65 + dl] + bs;
          u16 h = f2bf(v); hs[u] = h; ls[u] = f2bf(v - bf2f(h));
        }
        int sb0 = sbb + s8l * 8;
        size_t o = ((size_t)(b * 2 + (gcolg >> 7)) * 512 + (sb0 >> 3)) * 1024 + (size_t)(gcolg & 127) * 8;
        *(short8*)&VTh[o] = *(short8*)hs;
        *(short8*)&VTl[o] = *(short8*)ls;
      }
    }
  }
}

// ---------------------------------------------------------------------------
// 3) Sg = mask*(Q~.K~)*g^(il-jl); fused rowsum + Q.cVec dot -> rsP atomics.
//    R14: 64x64 tiles, causal triangle grid (64 x 10). A = Q 64-row half
//    panel via stageB64 dbuf; B = K frags global->regs. Wave tile 32x32.
__global__ __launch_bounds__(256, 4) void scores_kernel(
    const u16* __restrict__ Qh, const u16* __restrict__ Ql,
    const u16* __restrict__ Kh, const u16* __restrict__ Kl,
    const float* __restrict__ lVec, u16* __restrict__ Sgh, u16* __restrict__ Sgl,
    float* __restrict__ rsP)
{
  const int chunk = blockIdx.x, b = chunk >> 4, c = chunk & 15;
  const int y = blockIdx.y;
  const int mi = (y >= 6) ? 3 : (y >= 3) ? 2 : (y >= 1) ? 1 : 0;
  const int ji = y - mi * (mi + 1) / 2;
  const int m0 = mi * 64, jn0 = ji * 64;
  __shared__ u16 SA[2 * 8 * SLABB];
  __shared__ float cv[256], lut[256], rowAcc[64], qd4[4][64];
  float* fb = (float*)SA;  // 64x65 fp32 = 16640B = |SA| (epilogue only)
  const int tid = threadIdx.x, lane = tid & 63, wave = tid >> 6;
  const int wm0 = (wave >> 1) * 32, wn0 = (wave & 1) * 32;
  const int fm = lane & 15, fq = lane >> 4;
  if (jn0 == 0) {  // inline prefix scan: cv = sum_{cp<c} gL^(c-1-cp) lVec[cp]
    const float gL = exp2f((float)LL * LOG2G);
    float s = 0.f;
    for (int cp = 0; cp < c; ++cp)
      s = fmaf(gL, s, lVec[(size_t)(b * NCH + cp) * DD + tid]);
    cv[tid] = s;
  }
  lut[tid] = exp2f((float)tid * LOG2G);
  if (tid < 64) rowAcc[tid] = 0.f;
  const int growA = b * SS + c * LL + m0;
  const int growB = b * SS + c * LL + jn0;
  const u16* QhP = Qh + (size_t)(growA >> 7) * 32768 + (size_t)(growA & 127) * 8;
  const u16* QlP = Ql + (size_t)(growA >> 7) * 32768 + (size_t)(growA & 127) * 8;
  const u16* KhP = Kh + (size_t)(growB >> 7) * 32768 + (size_t)(growB & 127) * 8;
  const u16* KlP = Kl + (size_t)(growB >> 7) * 32768 + (size_t)(growB & 127) * 8;
  f32x4 acc[2][2];
#pragma unroll
  for (int i = 0; i < 2; ++i)
#pragma unroll
    for (int j = 0; j < 2; ++j) acc[i][j] = (f32x4){0.f, 0.f, 0.f, 0.f};
  float qdreg = 0.f;
  const int qrow = tid & 63, qk8b = tid >> 6;  // 64 rows x 4 k8
  short8 bh[2], bl[2];
  if (wave == 0) stageB64(QhP, SA, lane);
  if (wave == 1) stageB64(QlP, SA + 4 * SLABB, lane);
  loadB2(bh, bl, KhP, KlP, 0, wn0, fm, fq);
  int cur = 0;
  for (int ks = 0; ks < 8; ++ks) {
    __syncthreads();
    u16* Ac = cur ? SA + 8 * SLABB : SA;
    u16* An = cur ? SA : SA + 8 * SLABB;
    if (ks < 7) {
      if (wave == 0) stageB64(QhP + (ks + 1) * 4096, An, lane);
      if (wave == 1) stageB64(QlP + (ks + 1) * 4096, An + 4 * SLABB, lane);
    }
    mfma_64_ab(Ac, Ac + 4 * SLABB, bh, bl, wm0, fm, fq, acc);
    if (ks < 7) loadB2(bh, bl, KhP, KlP, ks + 1, wn0, fm, fq);
    if (jn0 == 0) {
      short8 hv = *(const short8*)&Ac[qk8b * SLABB + qrow * 8];
      short8 lv = *(const short8*)&Ac[4 * SLABB + qk8b * SLABB + qrow * 8];
#pragma unroll
      for (int u = 0; u < 8; ++u)
        qdreg = fmaf(bf2f((u16)hv[u]) + bf2f((u16)lv[u]),
                     cv[ks * 32 + qk8b * 8 + u], qdreg);
    }
    cur ^= 1;
  }
  qd4[qk8b][qrow] = qdreg;
  const int ps = chunk * 2 + (m0 >> 7);
  __syncthreads();                          // SA reads done; fb overlay safe
#pragma unroll
  for (int i = 0; i < 2; ++i)
#pragma unroll
    for (int j = 0; j < 2; ++j)
#pragma unroll
      for (int r = 0; r < 4; ++r)
        fb[(wm0 + i * 16 + fq * 4 + r) * 65 + wn0 + j * 16 + fm] = acc[i][j][r];
  __syncthreads();
#pragma unroll
  for (int it = 0; it < 2; ++it) {
    int unit = it * 256 + tid;              // 8 k8-cols x 64 rows
    int k8l = unit >> 6, rowl = unit & 63;
    int il = m0 + rowl;
    int jlb = jn0 + k8l * 8;
    float part = 0.f;
    u16 hs[8], ls[8];
#pragma unroll
    for (int u = 0; u < 8; ++u) {
      int jl = jlb + u;
      float v = (jl <= il) ? fb[rowl * 65 + k8l * 8 + u] * lut[il - jl] : 0.f;
      part += v;
      u16 h = f2bf(v); hs[u] = h; ls[u] = f2bf(v - bf2f(h));
    }
    atomicAdd(&rowAcc[rowl], part);
    size_t o = (size_t)(ps * 32 + (jn0 >> 3) + k8l) * 1024 +
               (size_t)((m0 & 64) + rowl) * 8;
    *(short8*)&Sgh[o] = *(short8*)hs;
    *(short8*)&Sgl[o] = *(short8*)ls;
  }
  __syncthreads();
  if (tid < 64) {
    float rs = rowAcc[tid];
    if (jn0 == 0)
      rs += exp2f((float)(m0 + tid + 1) * LOG2G) *
            (qd4[0][tid] + qd4[1][tid] + qd4[2][tid] + qd4[3][tid]);
    atomicAdd(&rsP[(size_t)b * SS + c * LL + m0 + tid], rs);
  }
}

// ---------------------------------------------------------------------------
// 5) lMatT[e][d] = sum_jl Vw[jl,e] K~[jl,d] ; R14: 64x64 tiles (grid 64x16).
//    A = V split-bf16 reg-staged (hi+lo reconstruct, wtl/denom fused) ->
//    SLABB dbuf; B = KT global->regs. Wave tile 32x32.
__global__ __launch_bounds__(256, 4) void lmat_kernel(
    const u16* __restrict__ VTh, const u16* __restrict__ VTl,
    const float* __restrict__ rsP,
    const u16* __restrict__ KTh, const u16* __restrict__ KTl,
    float* __restrict__ lMatT)
{
  const int chunk = blockIdx.x, b = chunk >> 4, c = chunk & 15;
  const int ty = blockIdx.y;
  const int m0 = (ty >> 2) * 64, n0 = (ty & 3) * 64;
  __shared__ u16 SA[2 * 8 * SLABB];
  __shared__ float swl[256];
  const int tid = threadIdx.x, lane = tid & 63, wave = tid >> 6;
  const int wm0 = (wave >> 1) * 32, wn0 = (wave & 1) * 32;
  const int fm = lane & 15, fq = lane >> 4;
  // per-jl scale = gamma^(255-jl) / max(|rsP|,1)
  swl[tid] = exp2f((float)(255 - tid) * LOG2G) /
             fmaxf(fabsf(rsP[(size_t)b * SS + c * LL + tid]), 1.0f);
  const u16* AThP = VTh + ((size_t)(b * 2 + (m0 >> 7)) * 512 + c * 32) * 1024 +
                    (size_t)(m0 & 127) * 8;
  const u16* ATlP = VTl + ((size_t)(b * 2 + (m0 >> 7)) * 512 + c * 32) * 1024 +
                    (size_t)(m0 & 127) * 8;
  const u16* BhP = KTh + ((size_t)(b * 2 + (n0 >> 7)) * 512 + c * 32) * 1024 + (size_t)(n0 & 127) * 8;
  const u16* BlP = KTl + ((size_t)(b * 2 + (n0 >> 7)) * 512 + c * 32) * 1024 + (size_t)(n0 & 127) * 8;
  const int arow = tid >> 2, ak8 = tid & 3;  // 64 rows x 4 k8, 1 unit/thread
  f32x4 acc[2][2];
#pragma unroll
  for (int i = 0; i < 2; ++i)
#pragma unroll
    for (int j = 0; j < 2; ++j) acc[i][j] = (f32x4){0.f, 0.f, 0.f, 0.f};
  short8 vh, vl;
  short8 bh[2], bl[2];
  loadB2(bh, bl, BhP, BlP, 0, wn0, fm, fq);
  {
    int off = ak8 * 1024 + arow * 8;
    vh = *(const short8*)&AThP[off];
    vl = *(const short8*)&ATlP[off];
  }
  __syncthreads();                         // swl ready
  {
    u16 hs[8], ls[8];
#pragma unroll
    for (int u = 0; u < 8; ++u) {
      float v = (bf2f((u16)vh[u]) + bf2f((u16)vl[u])) * swl[ak8 * 8 + u];
      u16 h = f2bf(v); hs[u] = h; ls[u] = f2bf(v - bf2f(h));
    }
    *(short8*)&SA[ak8 * SLABB + arow * 8] = *(short8*)hs;
    *(short8*)&SA[4 * SLABB + ak8 * SLABB + arow * 8] = *(short8*)ls;
  }
  int cur = 0;
  for (int ks = 0; ks < 8; ++ks) {
    __syncthreads();
    u16* Ac = cur ? SA + 8 * SLABB : SA;
    u16* An = cur ? SA : SA + 8 * SLABB;
    if (ks < 7) {
      int off = ((ks + 1) * 4 + ak8) * 1024 + arow * 8;
      vh = *(const short8*)&AThP[off];
      vl = *(const short8*)&ATlP[off];
    }
    mfma_64_ab(Ac, Ac + 4 * SLABB, bh, bl, wm0, fm, fq, acc);
    if (ks < 7) {
      loadB2(bh, bl, BhP, BlP, ks + 1, wn0, fm, fq);
      u16 hs[8], ls[8];
#pragma unroll
      for (int u = 0; u < 8; ++u) {
        float v = (bf2f((u16)vh[u]) + bf2f((u16)vl[u])) *
                  swl[(ks + 1) * 32 + ak8 * 8 + u];
        u16 h = f2bf(v); hs[u] = h; ls[u] = f2bf(v - bf2f(h));
      }
      *(short8*)&An[ak8 * SLABB + arow * 8] = *(short8*)hs;
      *(short8*)&An[4 * SLABB + ak8 * SLABB + arow * 8] = *(short8*)ls;
    }
    cur ^= 1;
  }
#pragma unroll
  for (int i = 0; i < 2; ++i)
#pragma unroll
    for (int j = 0; j < 2; ++j)
#pragma unroll
      for (int r = 0; r < 4; ++r) {
        int e = m0 + wm0 + i * 16 + fq * 4 + r;
        int d = n0 + wn0 + j * 16 + fm;
        lMatT[(size_t)chunk * 65536 + (size_t)e * 256 + d] = acc[i][j][r];
      }
}

// 6) carry scan -> cM packed split
__global__ __launch_bounds__(256) void combine_mat_kernel(
    const float* __restrict__ lMatT, u16* __restrict__ cMh, u16* __restrict__ cMl)
{
  const int t = blockIdx.x * 256 + threadIdx.x;
  const int b = t >> 13, rem = t & 8191;
  const int k8 = rem >> 8, e = rem & 255;
  const float gL = powf(GAMMA, (float)LL);
  float s[8] = {0.f, 0.f, 0.f, 0.f, 0.f, 0.f, 0.f, 0.f};
  for (int ch = 0; ch < 16; ++ch) {
    size_t ro = (size_t)(b * 16 + ch) * 65536 + (size_t)e * 256 + k8 * 8;
    float4 a0 = *(const float4*)&lMatT[ro];
    float4 a1 = *(const float4*)&lMatT[ro + 4];
    float vals[8] = {a0.x, a0.y, a0.z, a0.w, a1.x, a1.y, a1.z, a1.w};
    u16 hh[8], ll[8];
#pragma unroll
    for (int u = 0; u < 8; ++u) {
      u16 h = f2bf(s[u]); hh[u] = h; ll[u] = f2bf(s[u] - bf2f(h));
    }
    size_t wo = ((size_t)(((b * 16 + ch) * 2 + (e >> 7)) * 32 + k8)) * 1024 + (size_t)(e & 127) * 8;
    *(short8*)&cMh[wo] = *(short8*)hh;
    *(short8*)&cMl[wo] = *(short8*)ll;
#pragma unroll
    for (int u = 0; u < 8; ++u) s[u] = gL * s[u] + vals[u];
  }
}

// ---------------------------------------------------------------------------
// 7) out = g^(il+1) * Q~ @ cM^T + Sg @ Vd ; R15: 64x64 tiles (grid 64x16),
//    4 blocks/CU. inter: A=Q 64-row stageB64 dbuf, B=cM regs. intra: A=Sg
//    stageB64 dbuf, B=V split-bf16 reg-staged -> SLABB dbuf; nks=m0/32+2.
__global__ __launch_bounds__(256, 4) void out_kernel(
    const u16* __restrict__ Qh, const u16* __restrict__ Ql,
    const u16* __restrict__ cMh, const u16* __restrict__ cMl,
    const u16* __restrict__ Sgh, const u16* __restrict__ Sgl,
    const u16* __restrict__ VTh, const u16* __restrict__ VTl,
    const float* __restrict__ rsP,
    float* __restrict__ out)
{
  const int chunk = blockIdx.x, b = chunk >> 4, c = chunk & 15;
  const int ty = blockIdx.y;
  const int m0 = (ty >> 2) * 64, n0 = (ty & 3) * 64;
  __shared__ u16 SA[2 * 8 * SLABB];
  __shared__ u16 SB[2 * 8 * SLABB];
  __shared__ float olut[64];
  __shared__ float sdn[256];
  const int tid = threadIdx.x, lane = tid & 63, wave = tid >> 6;
  const int wm0 = (wave >> 1) * 32, wn0 = (wave & 1) * 32;
  const int fm = lane & 15, fq = lane >> 4;
  if (tid < 64) olut[tid] = exp2f((float)(m0 + tid + 1) * LOG2G);
  sdn[tid] = 1.0f / fmaxf(fabsf(rsP[(size_t)b * SS + c * LL + tid]), 1.0f);
  f32x4 acc[2][2];
#pragma unroll
  for (int i = 0; i < 2; ++i)
#pragma unroll
    for (int j = 0; j < 2; ++j) acc[i][j] = (f32x4){0.f, 0.f, 0.f, 0.f};
  int cur = 0;
  {  // inter: A = Q 64-row panel (stageB64 dbuf), B = cM rows n0.. (regs)
    const int growA = b * SS + c * LL + m0;
    const u16* AhP = Qh + (size_t)(growA >> 7) * 32768 + (size_t)(growA & 127) * 8;
    const u16* AlP = Ql + (size_t)(growA >> 7) * 32768 + (size_t)(growA & 127) * 8;
    const u16* BhP = cMh + (size_t)(chunk * 2 + (n0 >> 7)) * 32768 + (size_t)(n0 & 127) * 8;
    const u16* BlP = cMl + (size_t)(chunk * 2 + (n0 >> 7)) * 32768 + (size_t)(n0 & 127) * 8;
    short8 bh[2], bl[2];
    if (wave == 0) stageB64(AhP, SA, lane);
    if (wave == 1) stageB64(AlP, SA + 4 * SLABB, lane);
    loadB2(bh, bl, BhP, BlP, 0, wn0, fm, fq);
    for (int ks = 0; ks < 8; ++ks) {
      __syncthreads();
      u16* Ac = cur ? SA + 8 * SLABB : SA;
      u16* An = cur ? SA : SA + 8 * SLABB;
      if (ks < 7) {
        if (wave == 0) stageB64(AhP + (ks + 1) * 4096, An, lane);
        if (wave == 1) stageB64(AlP + (ks + 1) * 4096, An + 4 * SLABB, lane);
      }
      mfma_64_ab(Ac, Ac + 4 * SLABB, bh, bl, wm0, fm, fq, acc);
      if (ks < 7) loadB2(bh, bl, BhP, BlP, ks + 1, wn0, fm, fq);
      cur ^= 1;
    }
  }
  {  // intra: A = Sg 64-row panel (stageB64 dbuf), B = V split-bf16 -> SLABB
    const int growA = b * SS + c * LL + m0;  // Sg rows, same packing as Q
    const u16* AhP = Sgh + (size_t)(chunk * 2 + (m0 >> 7)) * 32768 + (size_t)(m0 & 127) * 8;
    const u16* AlP = Sgl + (size_t)(chunk * 2 + (m0 >> 7)) * 32768 + (size_t)(m0 & 127) * 8;
    const u16* BThP = VTh + ((size_t)(b * 2 + (n0 >> 7)) * 512 + c * 32) * 1024 + (size_t)(n0 & 127) * 8;
    const u16* BTlP = VTl + ((size_t)(b * 2 + (n0 >> 7)) * 512 + c * 32) * 1024 + (size_t)(n0 & 127) * 8;
    const int ber = tid >> 2, bk8 = tid & 3;  // 64 rows x 4 k8, 1 unit/thread
    const int nks = (m0 >> 5) + 2;            // causality: k <= m0+64
    short8 vh, vl;
    {  // prologue into buf[cur] (last read 2 steps ago -> safe)
      u16* Ac = cur ? SA + 8 * SLABB : SA;
      u16* Bc = cur ? SB + 8 * SLABB : SB;
      if (wave == 0) stageB64(AhP, Ac, lane);
      if (wave == 1) stageB64(AlP, Ac + 4 * SLABB, lane);
      int off = bk8 * 1024 + ber * 8;
      vh = *(const short8*)&BThP[off];
      vl = *(const short8*)&BTlP[off];
      // overlap acc scaling with the loads
#pragma unroll
      for (int i = 0; i < 2; ++i)
#pragma unroll
        for (int r = 0; r < 4; ++r) {
          int rl = wm0 + i * 16 + fq * 4 + r;
          float sc = olut[rl];
#pragma unroll
          for (int j = 0; j < 2; ++j) acc[i][j][r] *= sc;
        }
      u16 hs[8], ls[8];
#pragma unroll
      for (int u = 0; u < 8; ++u) {
        float v = (bf2f((u16)vh[u]) + bf2f((u16)vl[u])) * sdn[bk8 * 8 + u];
        u16 h = f2bf(v); hs[u] = h; ls[u] = f2bf(v - bf2f(h));
      }
      *(short8*)&Bc[bk8 * SLABB + ber * 8] = *(short8*)hs;
      *(short8*)&Bc[4 * SLABB + bk8 * SLABB + ber * 8] = *(short8*)ls;
    }
    for (int ks = 0; ks < nks; ++ks) {
      __syncthreads();
      u16* Ac = cur ? SA + 8 * SLABB : SA;
      u16* Bc = cur ? SB + 8 * SLABB : SB;
      u16* An = cur ? SA : SA + 8 * SLABB;
      u16* Bn = cur ? SB : SB + 8 * SLABB;
      if (ks + 1 < nks) {
        if (wave == 0) stageB64(AhP + (ks + 1) * 4096, An, lane);
        if (wave == 1) stageB64(AlP + (ks + 1) * 4096, An + 4 * SLABB, lane);
        int off = ((ks + 1) * 4 + bk8) * 1024 + ber * 8;
        vh = *(const short8*)&BThP[off];
        vl = *(const short8*)&BTlP[off];
      }
      mfma_64_bb(Ac, Ac + 4 * SLABB, Bc, Bc + 4 * SLABB, wm0, wn0, fm, fq, acc);
      if (ks + 1 < nks) {
        u16 hs[8], ls[8];
#pragma unroll
        for (int u = 0; u < 8; ++u) {
          float v = (bf2f((u16)vh[u]) + bf2f((u16)vl[u])) *
                    sdn[(ks + 1) * 32 + bk8 * 8 + u];
          u16 h = f2bf(v); hs[u] = h; ls[u] = f2bf(v - bf2f(h));
        }
        *(short8*)&Bn[bk8 * SLABB + ber * 8] = *(short8*)hs;
        *(short8*)&Bn[4 * SLABB + bk8 * SLABB + ber * 8] = *(short8*)ls;
      }
      cur ^= 1;
    }
  }
#pragma unroll
  for (int i = 0; i < 2; ++i)
#pragma unroll
    for (int j = 0; j < 2; ++j)
#pragma unroll
      for (int r = 0; r < 4; ++r) {
        int il = m0 + wm0 + i * 16 + fq * 4 + r;
        int e = n0 + wn0 + j * 16 + fm;
        out[(size_t)(b * SS + c * LL + il) * DD + e] = acc[i][j][r];
      }
}

// ---------------------------------------------------------------------------
extern "C" void kernel_launch(void* const* d_in, const int* in_sizes, int n_in,
                              void* d_out, int out_size, void* d_ws, size_t ws_size,
                              hipStream_t stream) {
  const float* xq = (const float*)d_in[0];
  const float* xk = (const float*)d_in[1];
  const float* xv = (const float*)d_in[2];
  const float* Wq = (const float*)d_in[3];
  const float* bq = (const float*)d_in[4];
  const float* Wk = (const float*)d_in[5];
  const float* bk = (const float*)d_in[6];
  const float* Wv = (const float*)d_in[7];
  const float* bv = (const float*)d_in[8];
  float* out = (float*)d_out;

  char* p = (char*)d_ws;
  const size_t H16 = (size_t)BB * SS * DD * 2;  // 8 MB
  u16* Qh   = (u16*)(p + 0 * H16);  u16* Ql   = (u16*)(p + 1 * H16);
  u16* Kh   = (u16*)(p + 2 * H16);  u16* Kl   = (u16*)(p + 3 * H16);
  u16* KTh  = (u16*)(p + 4 * H16);  u16* KTl  = (u16*)(p + 5 * H16);
  u16* VTh  = (u16*)(p + 6 * H16);  u16* VTl  = (u16*)(p + 7 * H16);
  u16* Sgh  = (u16*)(p + 10 * H16); u16* Sgl  = (u16*)(p + 11 * H16);
  u16* cMh  = (u16*)(p + 12 * H16); u16* cMl  = (u16*)(p + 13 * H16);
  float* lMatT = (float*)(p + 14 * H16);
  u16* Wth = (u16*)(p + 18 * H16);
  u16* Wtl = (u16*)(p + 18 * H16 + 3 * DD * DD * 2);
  float* rsP  = (float*)(p + 18 * H16 + 6 * DD * DD * 2);
  float* lVec = rsP + (size_t)BB * SS;

  init_pack_kernel<<<dim3(3, 16), 256, 0, stream>>>(Wq, Wk, Wv, Wth, Wtl, rsP, lVec);
  proj_kernel<<<dim3(BB * SS / 64, 1, 3), 256, 0, stream>>>(
      xq, xk, xv, Wth, Wtl, bq, bk, bv, Qh, Ql, Kh, Kl, KTh, KTl, VTh, VTl, lVec);
  scores_kernel<<<dim3(BB * NCH, 10), 256, 0, stream>>>(
      Qh, Ql, Kh, Kl, lVec, Sgh, Sgl, rsP);
  lmat_kernel<<<dim3(BB * NCH, 16), 256, 0, stream>>>(VTh, VTl, rsP, KTh, KTl, lMatT);
  combine_mat_kernel<<<128, 256, 0, stream>>>(lMatT, cMh, cMl);
  out_kernel<<<dim3(BB * NCH, 16), 256, 0, stream>>>(
      Qh, Ql, cMh, cMl, Sgh, Sgl, VTh, VTl, rsP, out);
}